// Round 2
// baseline (6578.671 us; speedup 1.0000x reference)
//
#include <hip/hip_runtime.h>

// All float tensors are fp32 (per reference: jnp.float32); indices int32.

// ---------------- edge scatter-add: agg[dst] += X[src] ----------------
// 16 threads per edge, 8 fp32 elems per thread (2x float4 load), 8 atomics.
__global__ __launch_bounds__(256)
void scatter_unw(const float* __restrict__ X, const int* __restrict__ src,
                 const int* __restrict__ dst, float* __restrict__ agg, int E)
{
    int tid = blockIdx.x * 256 + threadIdx.x;
    int e = tid >> 4;
    if (e >= E) return;
    int lane = tid & 15;
    int s = src[e], d = dst[e];
    const float4* xp = (const float4*)(X + (size_t)s * 128 + lane * 8);
    float4 a = xp[0], b = xp[1];
    float* out = agg + (size_t)d * 128 + lane * 8;
    atomicAdd(out + 0, a.x); atomicAdd(out + 1, a.y);
    atomicAdd(out + 2, a.z); atomicAdd(out + 3, a.w);
    atomicAdd(out + 4, b.x); atomicAdd(out + 5, b.y);
    atomicAdd(out + 6, b.z); atomicAdd(out + 7, b.w);
}

// agg[dst] += sigmoid(ew) * X[src]   (sigmoid computed inline, redundant per lane)
__global__ __launch_bounds__(256)
void scatter_w(const float* __restrict__ X, const int* __restrict__ src,
               const int* __restrict__ dst, const float* __restrict__ ew,
               float* __restrict__ agg, int E)
{
    int tid = blockIdx.x * 256 + threadIdx.x;
    int e = tid >> 4;
    if (e >= E) return;
    int lane = tid & 15;
    int s = src[e], d = dst[e];
    float x = ew[e];
    float w = 1.0f / (1.0f + __expf(-x));
    const float4* xp = (const float4*)(X + (size_t)s * 128 + lane * 8);
    float4 a = xp[0], b = xp[1];
    float* out = agg + (size_t)d * 128 + lane * 8;
    atomicAdd(out + 0, w * a.x); atomicAdd(out + 1, w * a.y);
    atomicAdd(out + 2, w * a.z); atomicAdd(out + 3, w * a.w);
    atomicAdd(out + 4, w * b.x); atomicAdd(out + 5, w * b.y);
    atomicAdd(out + 6, w * b.z); atomicAdd(out + 7, w * b.w);
}

// ---------------- fused conv: Cout = relu(A1@W1 + bias + A2@W2) ----------------
// A1,A2: [N,128] fp32; W1,W2: [128,128] fp32 row-major; bias: [128].
// 256 threads, TR=32 rows/block, thread=(cp in [0,64), g in [0,4)), RT=8 rows, 2 cols.
// Two phases re-using the same 64KB sW + 16KB sA (80KB LDS -> 2 blocks/CU).
__global__ __launch_bounds__(256)
void conv_kernel(const float* __restrict__ A1, const float* __restrict__ W1,
                 const float* __restrict__ bias,
                 const float* __restrict__ A2, const float* __restrict__ W2,
                 float* __restrict__ Cout, int N)
{
    constexpr int K = 128, OC = 128, RT = 8, TR = 32;
    __shared__ float sW[K * OC];   // 64 KB
    __shared__ float sA[TR * K];   // 16 KB

    const int tid = threadIdx.x;
    const int cp  = tid & 63;      // col pair
    const int g   = tid >> 6;      // row group
    const int row0 = blockIdx.x * TR;

    float acc[RT][2];
#pragma unroll
    for (int r = 0; r < RT; ++r) { acc[r][0] = 0.f; acc[r][1] = 0.f; }

    for (int phase = 0; phase < 2; ++phase) {
        const float* W = phase ? W2 : W1;
        const float* A = phase ? A2 : A1;
        if (phase) __syncthreads();          // protect prior-phase LDS reads
        for (int i = tid; i < K * OC / 4; i += 256)
            ((float4*)sW)[i] = ((const float4*)W)[i];
        for (int i = tid; i < TR * K / 4; i += 256) {
            int idx = i * 4;
            int r = idx >> 7, k = idx & 127;
            int gr = row0 + r;
            float4 v = make_float4(0.f, 0.f, 0.f, 0.f);
            if (gr < N) v = *(const float4*)(A + (size_t)gr * K + k);
            ((float4*)sA)[i] = v;
        }
        __syncthreads();

        const float* aBase = sA + (g * RT) * K;
#pragma unroll 2
        for (int k4 = 0; k4 < K / 4; ++k4) {
            float2 w0 = *(const float2*)(sW + (4 * k4 + 0) * OC + 2 * cp);
            float2 w1 = *(const float2*)(sW + (4 * k4 + 1) * OC + 2 * cp);
            float2 w2 = *(const float2*)(sW + (4 * k4 + 2) * OC + 2 * cp);
            float2 w3 = *(const float2*)(sW + (4 * k4 + 3) * OC + 2 * cp);
#pragma unroll
            for (int r = 0; r < RT; ++r) {
                float4 a = *(const float4*)(aBase + r * K + 4 * k4);
                acc[r][0] = fmaf(a.x, w0.x, acc[r][0]);
                acc[r][0] = fmaf(a.y, w1.x, acc[r][0]);
                acc[r][0] = fmaf(a.z, w2.x, acc[r][0]);
                acc[r][0] = fmaf(a.w, w3.x, acc[r][0]);
                acc[r][1] = fmaf(a.x, w0.y, acc[r][1]);
                acc[r][1] = fmaf(a.y, w1.y, acc[r][1]);
                acc[r][1] = fmaf(a.z, w2.y, acc[r][1]);
                acc[r][1] = fmaf(a.w, w3.y, acc[r][1]);
            }
        }
    }

#pragma unroll
    for (int r = 0; r < RT; ++r) {
        int gr = row0 + g * RT + r;
        if (gr >= N) continue;
        float v0 = fmaxf(acc[r][0] + bias[2 * cp],     0.f);
        float v1 = fmaxf(acc[r][1] + bias[2 * cp + 1], 0.f);
        float2 st; st.x = v0; st.y = v1;
        *(float2*)(Cout + (size_t)gr * OC + 2 * cp) = st;
    }
}

// ---------------- final lin: out = A@W + bias, OC=64, no relu ----------------
__global__ __launch_bounds__(256)
void lin64_kernel(const float* __restrict__ A, const float* __restrict__ W,
                  const float* __restrict__ bias, float* __restrict__ Cout, int N)
{
    constexpr int K = 128, OC = 64, RT = 8, TR = 64;
    __shared__ float sW[K * OC];   // 32 KB
    __shared__ float sA[TR * K];   // 32 KB

    const int tid = threadIdx.x;
    const int cp  = tid & 31;      // 32 col pairs
    const int g   = tid >> 5;      // 8 row groups
    const int row0 = blockIdx.x * TR;

    for (int i = tid; i < K * OC / 4; i += 256)
        ((float4*)sW)[i] = ((const float4*)W)[i];
    for (int i = tid; i < TR * K / 4; i += 256) {
        int idx = i * 4;
        int r = idx >> 7, k = idx & 127;
        int gr = row0 + r;
        float4 v = make_float4(0.f, 0.f, 0.f, 0.f);
        if (gr < N) v = *(const float4*)(A + (size_t)gr * K + k);
        ((float4*)sA)[i] = v;
    }
    __syncthreads();

    float acc[RT][2];
#pragma unroll
    for (int r = 0; r < RT; ++r) { acc[r][0] = 0.f; acc[r][1] = 0.f; }

    const float* aBase = sA + (g * RT) * K;
#pragma unroll 2
    for (int k4 = 0; k4 < K / 4; ++k4) {
        float2 w0 = *(const float2*)(sW + (4 * k4 + 0) * OC + 2 * cp);
        float2 w1 = *(const float2*)(sW + (4 * k4 + 1) * OC + 2 * cp);
        float2 w2 = *(const float2*)(sW + (4 * k4 + 2) * OC + 2 * cp);
        float2 w3 = *(const float2*)(sW + (4 * k4 + 3) * OC + 2 * cp);
#pragma unroll
        for (int r = 0; r < RT; ++r) {
            float4 a = *(const float4*)(aBase + r * K + 4 * k4);
            acc[r][0] = fmaf(a.x, w0.x, acc[r][0]);
            acc[r][0] = fmaf(a.y, w1.x, acc[r][0]);
            acc[r][0] = fmaf(a.z, w2.x, acc[r][0]);
            acc[r][0] = fmaf(a.w, w3.x, acc[r][0]);
            acc[r][1] = fmaf(a.x, w0.y, acc[r][1]);
            acc[r][1] = fmaf(a.y, w1.y, acc[r][1]);
            acc[r][1] = fmaf(a.z, w2.y, acc[r][1]);
            acc[r][1] = fmaf(a.w, w3.y, acc[r][1]);
        }
    }

#pragma unroll
    for (int r = 0; r < RT; ++r) {
        int gr = row0 + g * RT + r;
        if (gr >= N) continue;
        float2 st;
        st.x = acc[r][0] + bias[2 * cp];
        st.y = acc[r][1] + bias[2 * cp + 1];
        *(float2*)(Cout + (size_t)gr * OC + 2 * cp) = st;
    }
}

extern "C" void kernel_launch(void* const* d_in, const int* in_sizes, int n_in,
                              void* d_out, int out_size, void* d_ws, size_t ws_size,
                              hipStream_t stream)
{
    const float* x_meas  = (const float*)d_in[0];
    const float* x_dem   = (const float*)d_in[1];
    const int*   src_m   = (const int*)d_in[2];
    const int*   dst_m   = (const int*)d_in[3];
    const int*   src_b   = (const int*)d_in[4];
    const int*   dst_b   = (const int*)d_in[5];
    const float* edge_w  = (const float*)d_in[6];
    const float* W_rel1  = (const float*)d_in[7];
    const float* b_rel1  = (const float*)d_in[8];
    const float* W_root1 = (const float*)d_in[9];
    const float* W_rel2  = (const float*)d_in[10];
    const float* b_rel2  = (const float*)d_in[11];
    const float* W_root2 = (const float*)d_in[12];
    const float* W_rel3  = (const float*)d_in[13];
    const float* b_rel3  = (const float*)d_in[14];
    const float* W_root3 = (const float*)d_in[15];
    const float* W_lin   = (const float*)d_in[16];
    const float* b_lin   = (const float*)d_in[17];
    float* out = (float*)d_out;

    const int NM = 50000, ND = 20000, E = 600000;

    char* p = (char*)d_ws;
    auto alloc = [&](size_t bytes) { char* r = p; p += (bytes + 511) & ~(size_t)511; return r; };
    float* agg1  = (float*)alloc((size_t)NM * 128 * 4);   // 25.6 MB
    float* agg2  = (float*)alloc((size_t)ND * 128 * 4);   // 10.24 MB
    float* movie = (float*)alloc((size_t)NM * 128 * 4);   // 25.6 MB
    float* t2    = (float*)alloc((size_t)ND * 128 * 4);   // 10.24 MB
    float* agg3 = agg1;   // agg1 dead after conv1
    float* t3   = agg2;   // agg2 dead after conv2

    hipMemsetAsync(agg1, 0, (size_t)NM * 128 * 4, stream);
    hipMemsetAsync(agg2, 0, (size_t)ND * 128 * 4, stream);

    const int sblocks = (E * 16) / 256;   // 37500
    scatter_unw<<<sblocks, 256, 0, stream>>>(x_meas, src_m, dst_m, agg1, E);
    scatter_w  <<<sblocks, 256, 0, stream>>>(x_meas, src_b, dst_b, edge_w, agg2, E);

    // conv1: movie = relu(agg1@W_rel1 + b1 + x_meas@W_root1)
    conv_kernel<<<(NM + 31) / 32, 256, 0, stream>>>(agg1, W_rel1, b_rel1, x_meas, W_root1, movie, NM);
    // conv2: t2 = relu(agg2@W_rel2 + b2 + x_dem@W_root2)
    conv_kernel<<<(ND + 31) / 32, 256, 0, stream>>>(agg2, W_rel2, b_rel2, x_dem, W_root2, t2, ND);

    // scatter3: agg3 = sum_e sigmoid(ew) * movie[src_b] -> dst_b
    hipMemsetAsync(agg3, 0, (size_t)ND * 128 * 4, stream);
    scatter_w<<<sblocks, 256, 0, stream>>>(movie, src_b, dst_b, edge_w, agg3, E);

    // conv3: t3 = relu(agg3@W_rel3 + b3 + t2@W_root3)
    conv_kernel<<<(ND + 31) / 32, 256, 0, stream>>>(agg3, W_rel3, b_rel3, t2, W_root3, t3, ND);

    // final: out = t3@W_lin + b_lin
    lin64_kernel<<<(ND + 63) / 64, 256, 0, stream>>>(t3, W_lin, b_lin, out, ND);
}

// Round 3
// 622.374 us; speedup vs baseline: 10.5703x; 10.5703x over previous
//
#include <hip/hip_runtime.h>

// All float tensors fp32 (verified round 2); indices int32.
// Strategy: device-built CSR (by dst) -> wave-per-node gather aggregation.
// Kills the 2.4 GB/dispatch atomic write-through seen in round 2 rocprof.

// ---------------- fused degree histogram for both graphs ----------------
__global__ __launch_bounds__(256)
void hist_kernel(const int* __restrict__ dst_m, const int* __restrict__ dst_b,
                 int* __restrict__ deg_m, int* __restrict__ deg_b, int E)
{
    int t = blockIdx.x * 256 + threadIdx.x;
    if (t < E) {
        atomicAdd(&deg_m[dst_m[t]], 1);
    } else if (t < 2 * E) {
        atomicAdd(&deg_b[dst_b[t - E]], 1);
    }
}

// ---------------- single-block exclusive scan (2 blocks: one per graph) ----
__device__ __forceinline__ int wave_incl_scan(int v, int lane) {
#pragma unroll
    for (int off = 1; off < 64; off <<= 1) {
        int t = __shfl_up(v, off, 64);
        if (lane >= off) v += t;
    }
    return v;
}

__global__ __launch_bounds__(1024)
void scan2_kernel(const int* __restrict__ degA, int* __restrict__ rpA, int nA,
                  const int* __restrict__ degB, int* __restrict__ rpB, int nB)
{
    const int* deg = blockIdx.x ? degB : degA;
    int* rp = blockIdx.x ? rpB : rpA;
    int n = blockIdx.x ? nB : nA;

    __shared__ int wsum[16];
    __shared__ int carry;
    const int tid = threadIdx.x, lane = tid & 63, wid = tid >> 6;
    if (tid == 0) carry = 0;
    __syncthreads();

    for (int base = 0; base < n; base += 1024) {
        int idx = base + tid;
        int v = (idx < n) ? deg[idx] : 0;
        int incl = wave_incl_scan(v, lane);
        if (lane == 63) wsum[wid] = incl;
        __syncthreads();
        if (wid == 0) {
            int s = (lane < 16) ? wsum[lane] : 0;
            int si = wave_incl_scan(s, lane);
            if (lane < 16) wsum[lane] = si - s;   // exclusive wave offsets
        }
        __syncthreads();
        if (idx < n) rp[idx] = carry + wsum[wid] + incl - v;  // exclusive scan
        __syncthreads();                           // everyone read carry/wsum
        if (tid == 1023) carry += wsum[15] + incl; // chunk total
        __syncthreads();
    }
}

// ---------------- fill: permute src (and sigmoid(w)) into CSR order --------
// Mutates rp_* in place: exclusive scan -> inclusive scan (start of node i+1).
__global__ __launch_bounds__(256)
void fill_kernel(const int* __restrict__ src_m, const int* __restrict__ dst_m,
                 const int* __restrict__ src_b, const int* __restrict__ dst_b,
                 const float* __restrict__ edge_w,
                 int* __restrict__ rp_m, int* __restrict__ rp_b,
                 int* __restrict__ srcs_m, int* __restrict__ srcs_b,
                 float* __restrict__ wsrt_b, int E)
{
    int t = blockIdx.x * 256 + threadIdx.x;
    if (t < E) {
        int pos = atomicAdd(&rp_m[dst_m[t]], 1);
        srcs_m[pos] = src_m[t];
    } else if (t < 2 * E) {
        int e = t - E;
        int pos = atomicAdd(&rp_b[dst_b[e]], 1);
        srcs_b[pos] = src_b[e];
        float x = edge_w[e];
        wsrt_b[pos] = 1.0f / (1.0f + __expf(-x));
    }
}

// ---------------- wave-per-node CSR gather aggregation ----------------------
// rp is the post-fill (inclusive) array: end = rp[node], beg = rp[node-1] (0 for node 0).
// 64 lanes x float2 = one 512B coalesced row gather per edge; plain store per node.
template<bool WEIGHTED>
__global__ __launch_bounds__(256)
void gather_agg(const float* __restrict__ X, const int* __restrict__ srcs,
                const float* __restrict__ wts, const int* __restrict__ rp,
                float* __restrict__ out, int N)
{
    int node = blockIdx.x * 4 + (threadIdx.x >> 6);
    if (node >= N) return;
    int lane = threadIdx.x & 63;
    int end = rp[node];
    int beg = node ? rp[node - 1] : 0;

    float2 acc = make_float2(0.f, 0.f);
    int i = beg;
    for (; i + 2 <= end; i += 2) {          // unroll-2: two independent gathers in flight
        int s0 = srcs[i], s1 = srcs[i + 1];
        float w0 = WEIGHTED ? wts[i] : 1.0f;
        float w1 = WEIGHTED ? wts[i + 1] : 1.0f;
        float2 v0 = *(const float2*)(X + (size_t)s0 * 128 + lane * 2);
        float2 v1 = *(const float2*)(X + (size_t)s1 * 128 + lane * 2);
        acc.x = fmaf(w0, v0.x, acc.x); acc.y = fmaf(w0, v0.y, acc.y);
        acc.x = fmaf(w1, v1.x, acc.x); acc.y = fmaf(w1, v1.y, acc.y);
    }
    if (i < end) {
        int s = srcs[i];
        float w = WEIGHTED ? wts[i] : 1.0f;
        float2 v = *(const float2*)(X + (size_t)s * 128 + lane * 2);
        acc.x = fmaf(w, v.x, acc.x); acc.y = fmaf(w, v.y, acc.y);
    }
    *(float2*)(out + (size_t)node * 128 + lane * 2) = acc;
}

// ---------------- fused conv: Cout = relu(A1@W1 + bias + A2@W2) ----------------
__global__ __launch_bounds__(256)
void conv_kernel(const float* __restrict__ A1, const float* __restrict__ W1,
                 const float* __restrict__ bias,
                 const float* __restrict__ A2, const float* __restrict__ W2,
                 float* __restrict__ Cout, int N)
{
    constexpr int K = 128, OC = 128, RT = 8, TR = 32;
    __shared__ float sW[K * OC];   // 64 KB
    __shared__ float sA[TR * K];   // 16 KB

    const int tid = threadIdx.x;
    const int cp  = tid & 63;
    const int g   = tid >> 6;
    const int row0 = blockIdx.x * TR;

    float acc[RT][2];
#pragma unroll
    for (int r = 0; r < RT; ++r) { acc[r][0] = 0.f; acc[r][1] = 0.f; }

    for (int phase = 0; phase < 2; ++phase) {
        const float* W = phase ? W2 : W1;
        const float* A = phase ? A2 : A1;
        if (phase) __syncthreads();
        for (int i = tid; i < K * OC / 4; i += 256)
            ((float4*)sW)[i] = ((const float4*)W)[i];
        for (int i = tid; i < TR * K / 4; i += 256) {
            int idx = i * 4;
            int r = idx >> 7, k = idx & 127;
            int gr = row0 + r;
            float4 v = make_float4(0.f, 0.f, 0.f, 0.f);
            if (gr < N) v = *(const float4*)(A + (size_t)gr * K + k);
            ((float4*)sA)[i] = v;
        }
        __syncthreads();

        const float* aBase = sA + (g * RT) * K;
#pragma unroll 2
        for (int k4 = 0; k4 < K / 4; ++k4) {
            float2 w0 = *(const float2*)(sW + (4 * k4 + 0) * OC + 2 * cp);
            float2 w1 = *(const float2*)(sW + (4 * k4 + 1) * OC + 2 * cp);
            float2 w2 = *(const float2*)(sW + (4 * k4 + 2) * OC + 2 * cp);
            float2 w3 = *(const float2*)(sW + (4 * k4 + 3) * OC + 2 * cp);
#pragma unroll
            for (int r = 0; r < RT; ++r) {
                float4 a = *(const float4*)(aBase + r * K + 4 * k4);
                acc[r][0] = fmaf(a.x, w0.x, acc[r][0]);
                acc[r][0] = fmaf(a.y, w1.x, acc[r][0]);
                acc[r][0] = fmaf(a.z, w2.x, acc[r][0]);
                acc[r][0] = fmaf(a.w, w3.x, acc[r][0]);
                acc[r][1] = fmaf(a.x, w0.y, acc[r][1]);
                acc[r][1] = fmaf(a.y, w1.y, acc[r][1]);
                acc[r][1] = fmaf(a.z, w2.y, acc[r][1]);
                acc[r][1] = fmaf(a.w, w3.y, acc[r][1]);
            }
        }
    }

#pragma unroll
    for (int r = 0; r < RT; ++r) {
        int gr = row0 + g * RT + r;
        if (gr >= N) continue;
        float2 st;
        st.x = fmaxf(acc[r][0] + bias[2 * cp],     0.f);
        st.y = fmaxf(acc[r][1] + bias[2 * cp + 1], 0.f);
        *(float2*)(Cout + (size_t)gr * OC + 2 * cp) = st;
    }
}

// ---------------- final lin: out = A@W + bias, OC=64, no relu ----------------
__global__ __launch_bounds__(256)
void lin64_kernel(const float* __restrict__ A, const float* __restrict__ W,
                  const float* __restrict__ bias, float* __restrict__ Cout, int N)
{
    constexpr int K = 128, OC = 64, RT = 8, TR = 64;
    __shared__ float sW[K * OC];   // 32 KB
    __shared__ float sA[TR * K];   // 32 KB

    const int tid = threadIdx.x;
    const int cp  = tid & 31;
    const int g   = tid >> 5;
    const int row0 = blockIdx.x * TR;

    for (int i = tid; i < K * OC / 4; i += 256)
        ((float4*)sW)[i] = ((const float4*)W)[i];
    for (int i = tid; i < TR * K / 4; i += 256) {
        int idx = i * 4;
        int r = idx >> 7, k = idx & 127;
        int gr = row0 + r;
        float4 v = make_float4(0.f, 0.f, 0.f, 0.f);
        if (gr < N) v = *(const float4*)(A + (size_t)gr * K + k);
        ((float4*)sA)[i] = v;
    }
    __syncthreads();

    float acc[RT][2];
#pragma unroll
    for (int r = 0; r < RT; ++r) { acc[r][0] = 0.f; acc[r][1] = 0.f; }

    const float* aBase = sA + (g * RT) * K;
#pragma unroll 2
    for (int k4 = 0; k4 < K / 4; ++k4) {
        float2 w0 = *(const float2*)(sW + (4 * k4 + 0) * OC + 2 * cp);
        float2 w1 = *(const float2*)(sW + (4 * k4 + 1) * OC + 2 * cp);
        float2 w2 = *(const float2*)(sW + (4 * k4 + 2) * OC + 2 * cp);
        float2 w3 = *(const float2*)(sW + (4 * k4 + 3) * OC + 2 * cp);
#pragma unroll
        for (int r = 0; r < RT; ++r) {
            float4 a = *(const float4*)(aBase + r * K + 4 * k4);
            acc[r][0] = fmaf(a.x, w0.x, acc[r][0]);
            acc[r][0] = fmaf(a.y, w1.x, acc[r][0]);
            acc[r][0] = fmaf(a.z, w2.x, acc[r][0]);
            acc[r][0] = fmaf(a.w, w3.x, acc[r][0]);
            acc[r][1] = fmaf(a.x, w0.y, acc[r][1]);
            acc[r][1] = fmaf(a.y, w1.y, acc[r][1]);
            acc[r][1] = fmaf(a.z, w2.y, acc[r][1]);
            acc[r][1] = fmaf(a.w, w3.y, acc[r][1]);
        }
    }

#pragma unroll
    for (int r = 0; r < RT; ++r) {
        int gr = row0 + g * RT + r;
        if (gr >= N) continue;
        float2 st;
        st.x = acc[r][0] + bias[2 * cp];
        st.y = acc[r][1] + bias[2 * cp + 1];
        *(float2*)(Cout + (size_t)gr * OC + 2 * cp) = st;
    }
}

extern "C" void kernel_launch(void* const* d_in, const int* in_sizes, int n_in,
                              void* d_out, int out_size, void* d_ws, size_t ws_size,
                              hipStream_t stream)
{
    const float* x_meas  = (const float*)d_in[0];
    const float* x_dem   = (const float*)d_in[1];
    const int*   src_m   = (const int*)d_in[2];
    const int*   dst_m   = (const int*)d_in[3];
    const int*   src_b   = (const int*)d_in[4];
    const int*   dst_b   = (const int*)d_in[5];
    const float* edge_w  = (const float*)d_in[6];
    const float* W_rel1  = (const float*)d_in[7];
    const float* b_rel1  = (const float*)d_in[8];
    const float* W_root1 = (const float*)d_in[9];
    const float* W_rel2  = (const float*)d_in[10];
    const float* b_rel2  = (const float*)d_in[11];
    const float* W_root2 = (const float*)d_in[12];
    const float* W_rel3  = (const float*)d_in[13];
    const float* b_rel3  = (const float*)d_in[14];
    const float* W_root3 = (const float*)d_in[15];
    const float* W_lin   = (const float*)d_in[16];
    const float* b_lin   = (const float*)d_in[17];
    float* out = (float*)d_out;

    const int NM = 50000, ND = 20000, E = 600000;

    char* p = (char*)d_ws;
    auto alloc = [&](size_t bytes) { char* r = p; p += (bytes + 511) & ~(size_t)511; return r; };
    int*   deg_m  = (int*)  alloc((size_t)NM * 4);
    int*   rp_m   = (int*)  alloc((size_t)NM * 4);
    int*   deg_b  = (int*)  alloc((size_t)ND * 4);
    int*   rp_b   = (int*)  alloc((size_t)ND * 4);
    int*   srcs_m = (int*)  alloc((size_t)E * 4);
    int*   srcs_b = (int*)  alloc((size_t)E * 4);
    float* wsrt_b = (float*)alloc((size_t)E * 4);
    float* agg1   = (float*)alloc((size_t)NM * 128 * 4);   // 25.6 MB
    float* agg2   = (float*)alloc((size_t)ND * 128 * 4);   // 10.24 MB
    float* movie  = (float*)alloc((size_t)NM * 128 * 4);   // 25.6 MB
    float* t2     = (float*)alloc((size_t)ND * 128 * 4);   // 10.24 MB
    float* agg3 = agg1;   // agg1 dead after conv1 (ND rows fit in NM buffer)
    float* t3   = agg2;   // agg2 dead after conv2

    hipMemsetAsync(deg_m, 0, (size_t)NM * 4, stream);
    hipMemsetAsync(deg_b, 0, (size_t)ND * 4, stream);

    // CSR build (both graphs)
    const int eb2 = (2 * E + 255) / 256;
    hist_kernel<<<eb2, 256, 0, stream>>>(dst_m, dst_b, deg_m, deg_b, E);
    scan2_kernel<<<2, 1024, 0, stream>>>(deg_m, rp_m, NM, deg_b, rp_b, ND);
    fill_kernel<<<eb2, 256, 0, stream>>>(src_m, dst_m, src_b, dst_b, edge_w,
                                         rp_m, rp_b, srcs_m, srcs_b, wsrt_b, E);

    // aggregations (atomic-free, one write per node)
    gather_agg<false><<<(NM + 3) / 4, 256, 0, stream>>>(x_meas, srcs_m, nullptr, rp_m, agg1, NM);
    gather_agg<true ><<<(ND + 3) / 4, 256, 0, stream>>>(x_meas, srcs_b, wsrt_b, rp_b, agg2, ND);

    // conv1: movie = relu(agg1@W_rel1 + b1 + x_meas@W_root1)
    conv_kernel<<<(NM + 31) / 32, 256, 0, stream>>>(agg1, W_rel1, b_rel1, x_meas, W_root1, movie, NM);
    // conv2: t2 = relu(agg2@W_rel2 + b2 + x_dem@W_root2)
    conv_kernel<<<(ND + 31) / 32, 256, 0, stream>>>(agg2, W_rel2, b_rel2, x_dem, W_root2, t2, ND);

    // agg3 = sum_e w * movie[src_b]  (CSR_b reused)
    gather_agg<true><<<(ND + 3) / 4, 256, 0, stream>>>(movie, srcs_b, wsrt_b, rp_b, agg3, ND);

    // conv3: t3 = relu(agg3@W_rel3 + b3 + t2@W_root3)
    conv_kernel<<<(ND + 31) / 32, 256, 0, stream>>>(agg3, W_rel3, b_rel3, t2, W_root3, t3, ND);

    // final: out = t3@W_lin + b_lin
    lin64_kernel<<<(ND + 63) / 64, 256, 0, stream>>>(t3, W_lin, b_lin, out, ND);
}

// Round 5
// 566.753 us; speedup vs baseline: 11.6077x; 1.0981x over previous
//
#include <hip/hip_runtime.h>

// Round 5: MFMA split-bf16 GEMMs with IN-REGISTER hi/lo split.
// Data path (CSR build, fp32 gathers, fp32 activations) identical to the
// round-3 kernel that passed at absmax 0.25; ws usage back to ~80 MB
// (round 4's 116 MB likely overflowed ws -> OOB corruption, absmax 8.19).

typedef unsigned short u16;
typedef unsigned int u32;
typedef __attribute__((ext_vector_type(8))) short bf16x8;
typedef __attribute__((ext_vector_type(4))) float f32x4;

__device__ __forceinline__ float bf2f(u16 h) {
    union { u32 u; float f; } v; v.u = ((u32)h) << 16; return v.f;
}
__device__ __forceinline__ u16 f2bf(float f) {
    union { float f; u32 u; } v; v.f = f;
    u32 lsb = (v.u >> 16) & 1u;
    v.u += 0x7fffu + lsb;           // RNE
    return (u16)(v.u >> 16);
}
__device__ __forceinline__ void split2(float v, u16& h, u16& l) {
    u16 hb = f2bf(v);
    h = hb; l = f2bf(v - bf2f(hb));
}
// split 8 consecutive fp32 into hi/lo bf16x8 A-fragments (in-register)
__device__ __forceinline__ void split8(const float* __restrict__ p, bf16x8& h, bf16x8& l) {
    float4 u = *(const float4*)p;
    float4 w = *(const float4*)(p + 4);
    float a[8] = {u.x, u.y, u.z, u.w, w.x, w.y, w.z, w.w};
#pragma unroll
    for (int j = 0; j < 8; ++j) {
        u16 hh, ll; split2(a[j], hh, ll);
        h[j] = (short)hh; l[j] = (short)ll;
    }
}

// ---------------- CSR build (round-3 proven, unchanged) ----------------
__global__ __launch_bounds__(256)
void hist_kernel(const int* __restrict__ dst_m, const int* __restrict__ dst_b,
                 int* __restrict__ deg_m, int* __restrict__ deg_b, int E)
{
    int t = blockIdx.x * 256 + threadIdx.x;
    if (t < E) {
        atomicAdd(&deg_m[dst_m[t]], 1);
    } else if (t < 2 * E) {
        atomicAdd(&deg_b[dst_b[t - E]], 1);
    }
}

__device__ __forceinline__ int wave_incl_scan(int v, int lane) {
#pragma unroll
    for (int off = 1; off < 64; off <<= 1) {
        int t = __shfl_up(v, off, 64);
        if (lane >= off) v += t;
    }
    return v;
}

__global__ __launch_bounds__(1024)
void scan2_kernel(const int* __restrict__ degA, int* __restrict__ rpA, int nA,
                  const int* __restrict__ degB, int* __restrict__ rpB, int nB)
{
    const int* deg = blockIdx.x ? degB : degA;
    int* rp = blockIdx.x ? rpB : rpA;
    int n = blockIdx.x ? nB : nA;

    __shared__ int wsum[16];
    __shared__ int carry;
    const int tid = threadIdx.x, lane = tid & 63, wid = tid >> 6;
    if (tid == 0) carry = 0;
    __syncthreads();

    for (int base = 0; base < n; base += 1024) {
        int idx = base + tid;
        int v = (idx < n) ? deg[idx] : 0;
        int incl = wave_incl_scan(v, lane);
        if (lane == 63) wsum[wid] = incl;
        __syncthreads();
        if (wid == 0) {
            int s = (lane < 16) ? wsum[lane] : 0;
            int si = wave_incl_scan(s, lane);
            if (lane < 16) wsum[lane] = si - s;
        }
        __syncthreads();
        if (idx < n) rp[idx] = carry + wsum[wid] + incl - v;
        __syncthreads();
        if (tid == 1023) carry += wsum[15] + incl;
        __syncthreads();
    }
}

__global__ __launch_bounds__(256)
void fill_kernel(const int* __restrict__ src_m, const int* __restrict__ dst_m,
                 const int* __restrict__ src_b, const int* __restrict__ dst_b,
                 const float* __restrict__ edge_w,
                 int* __restrict__ rp_m, int* __restrict__ rp_b,
                 int* __restrict__ srcs_m, int* __restrict__ srcs_b,
                 float* __restrict__ wsrt_b, int E)
{
    int t = blockIdx.x * 256 + threadIdx.x;
    if (t < E) {
        int pos = atomicAdd(&rp_m[dst_m[t]], 1);
        srcs_m[pos] = src_m[t];
    } else if (t < 2 * E) {
        int e = t - E;
        int pos = atomicAdd(&rp_b[dst_b[e]], 1);
        srcs_b[pos] = src_b[e];
        float x = edge_w[e];
        wsrt_b[pos] = 1.0f / (1.0f + __expf(-x));
    }
}

// ---------------- wave-per-node CSR gather (round-3 proven, fp32) ----------
template<bool WEIGHTED>
__global__ __launch_bounds__(256)
void gather_agg(const float* __restrict__ X, const int* __restrict__ srcs,
                const float* __restrict__ wts, const int* __restrict__ rp,
                float* __restrict__ out, int N)
{
    int node = blockIdx.x * 4 + (threadIdx.x >> 6);
    if (node >= N) return;
    int lane = threadIdx.x & 63;
    int end = rp[node];
    int beg = node ? rp[node - 1] : 0;

    float2 acc = make_float2(0.f, 0.f);
    int i = beg;
    for (; i + 2 <= end; i += 2) {
        int s0 = srcs[i], s1 = srcs[i + 1];
        float w0 = WEIGHTED ? wts[i] : 1.0f;
        float w1 = WEIGHTED ? wts[i + 1] : 1.0f;
        float2 v0 = *(const float2*)(X + (size_t)s0 * 128 + lane * 2);
        float2 v1 = *(const float2*)(X + (size_t)s1 * 128 + lane * 2);
        acc.x = fmaf(w0, v0.x, acc.x); acc.y = fmaf(w0, v0.y, acc.y);
        acc.x = fmaf(w1, v1.x, acc.x); acc.y = fmaf(w1, v1.y, acc.y);
    }
    if (i < end) {
        int s = srcs[i];
        float w = WEIGHTED ? wts[i] : 1.0f;
        float2 v = *(const float2*)(X + (size_t)s * 128 + lane * 2);
        acc.x = fmaf(w, v.x, acc.x); acc.y = fmaf(w, v.y, acc.y);
    }
    *(float2*)(out + (size_t)node * 128 + lane * 2) = acc;
}

// ---------------- transpose + split weights: W[K][OC] fp32 -> Wt_h/l [OC][K] --
__global__ __launch_bounds__(256)
void wsplit_kernel(const float* __restrict__ W, u16* __restrict__ th,
                   u16* __restrict__ tl, int K, int OC)
{
    int i = blockIdx.x * 256 + threadIdx.x;
    if (i >= K * OC) return;
    int k = i / OC, n = i % OC;
    u16 h, l;
    split2(W[i], h, l);
    th[n * K + k] = h;
    tl[n * K + k] = l;
}

// ---------------- MFMA conv: C = relu(A1@W1 + bias + A2@W2) ----------------
// A1,A2: [N,128] fp32 (split hi/lo in-register). W*: transposed [OC][K] hi/lo bf16.
// Wave = 32 rows x 128 cols. Split-3 MFMA: Ah*Bh + Al*Bh + Ah*Bl.
// Layouts (m89/m91/m120-verified): A[m=lane&15][k=quad*8+j]; B from W^T rows
// identically; C/D col=lane&15, row=quad*4+reg.
__global__ __launch_bounds__(256)
void conv_mfma(const float* __restrict__ A1,
               const u16* __restrict__ W1h, const u16* __restrict__ W1l,
               const float* __restrict__ bias,
               const float* __restrict__ A2,
               const u16* __restrict__ W2h, const u16* __restrict__ W2l,
               float* __restrict__ Cout, int N)
{
    const int wid  = (blockIdx.x * 256 + threadIdx.x) >> 6;
    const int lane = threadIdx.x & 63;
    const int m0   = wid * 32;
    if (m0 >= N) return;
    const int lr   = lane & 15;
    const int quad = lane >> 4;

    f32x4 acc[2][8];
#pragma unroll
    for (int mt = 0; mt < 2; ++mt)
#pragma unroll
        for (int n = 0; n < 8; ++n) acc[mt][n] = (f32x4){0.f, 0.f, 0.f, 0.f};

    int r0 = m0 + lr;      if (r0 >= N) r0 = N - 1;
    int r1 = m0 + 16 + lr; if (r1 >= N) r1 = N - 1;

#pragma unroll
    for (int phase = 0; phase < 2; ++phase) {
        const float* A  = phase ? A2  : A1;
        const u16*   Wh = phase ? W2h : W1h;
        const u16*   Wl = phase ? W2l : W1l;
#pragma unroll
        for (int c = 0; c < 4; ++c) {
            const int kb = c * 32 + quad * 8;
            bf16x8 a0h, a0l, a1h, a1l;
            split8(A + (size_t)r0 * 128 + kb, a0h, a0l);
            split8(A + (size_t)r1 * 128 + kb, a1h, a1l);
#pragma unroll
            for (int n = 0; n < 8; ++n) {
                bf16x8 bh = *(const bf16x8*)(Wh + (size_t)(n * 16 + lr) * 128 + kb);
                bf16x8 bl = *(const bf16x8*)(Wl + (size_t)(n * 16 + lr) * 128 + kb);
                acc[0][n] = __builtin_amdgcn_mfma_f32_16x16x32_bf16(a0h, bh, acc[0][n], 0, 0, 0);
                acc[0][n] = __builtin_amdgcn_mfma_f32_16x16x32_bf16(a0l, bh, acc[0][n], 0, 0, 0);
                acc[0][n] = __builtin_amdgcn_mfma_f32_16x16x32_bf16(a0h, bl, acc[0][n], 0, 0, 0);
                acc[1][n] = __builtin_amdgcn_mfma_f32_16x16x32_bf16(a1h, bh, acc[1][n], 0, 0, 0);
                acc[1][n] = __builtin_amdgcn_mfma_f32_16x16x32_bf16(a1l, bh, acc[1][n], 0, 0, 0);
                acc[1][n] = __builtin_amdgcn_mfma_f32_16x16x32_bf16(a1h, bl, acc[1][n], 0, 0, 0);
            }
        }
    }

#pragma unroll
    for (int mt = 0; mt < 2; ++mt) {
#pragma unroll
        for (int n = 0; n < 8; ++n) {
            const int col = n * 16 + lr;
            const float b = bias[col];
#pragma unroll
            for (int r = 0; r < 4; ++r) {
                int row = m0 + mt * 16 + quad * 4 + r;
                if (row >= N) continue;
                Cout[(size_t)row * 128 + col] = fmaxf(acc[mt][n][r] + b, 0.f);
            }
        }
    }
}

// ---------------- MFMA final lin: out = A@W + bias, OC=64, fp32 out ----------
__global__ __launch_bounds__(256)
void lin_mfma(const float* __restrict__ A,
              const u16* __restrict__ Wh, const u16* __restrict__ Wl,
              const float* __restrict__ bias, float* __restrict__ out, int N)
{
    const int wid  = (blockIdx.x * 256 + threadIdx.x) >> 6;
    const int lane = threadIdx.x & 63;
    const int m0   = wid * 32;
    if (m0 >= N) return;
    const int lr   = lane & 15;
    const int quad = lane >> 4;

    f32x4 acc[2][4];
#pragma unroll
    for (int mt = 0; mt < 2; ++mt)
#pragma unroll
        for (int n = 0; n < 4; ++n) acc[mt][n] = (f32x4){0.f, 0.f, 0.f, 0.f};

    int r0 = m0 + lr;      if (r0 >= N) r0 = N - 1;
    int r1 = m0 + 16 + lr; if (r1 >= N) r1 = N - 1;

#pragma unroll
    for (int c = 0; c < 4; ++c) {
        const int kb = c * 32 + quad * 8;
        bf16x8 a0h, a0l, a1h, a1l;
        split8(A + (size_t)r0 * 128 + kb, a0h, a0l);
        split8(A + (size_t)r1 * 128 + kb, a1h, a1l);
#pragma unroll
        for (int n = 0; n < 4; ++n) {
            bf16x8 bh = *(const bf16x8*)(Wh + (size_t)(n * 16 + lr) * 128 + kb);
            bf16x8 bl = *(const bf16x8*)(Wl + (size_t)(n * 16 + lr) * 128 + kb);
            acc[0][n] = __builtin_amdgcn_mfma_f32_16x16x32_bf16(a0h, bh, acc[0][n], 0, 0, 0);
            acc[0][n] = __builtin_amdgcn_mfma_f32_16x16x32_bf16(a0l, bh, acc[0][n], 0, 0, 0);
            acc[0][n] = __builtin_amdgcn_mfma_f32_16x16x32_bf16(a0h, bl, acc[0][n], 0, 0, 0);
            acc[1][n] = __builtin_amdgcn_mfma_f32_16x16x32_bf16(a1h, bh, acc[1][n], 0, 0, 0);
            acc[1][n] = __builtin_amdgcn_mfma_f32_16x16x32_bf16(a1l, bh, acc[1][n], 0, 0, 0);
            acc[1][n] = __builtin_amdgcn_mfma_f32_16x16x32_bf16(a1h, bl, acc[1][n], 0, 0, 0);
        }
    }

#pragma unroll
    for (int mt = 0; mt < 2; ++mt) {
#pragma unroll
        for (int n = 0; n < 4; ++n) {
            const int col = n * 16 + lr;
            const float b = bias[col];
#pragma unroll
            for (int r = 0; r < 4; ++r) {
                int row = m0 + mt * 16 + quad * 4 + r;
                if (row >= N) continue;
                out[(size_t)row * 64 + col] = acc[mt][n][r] + b;
            }
        }
    }
}

extern "C" void kernel_launch(void* const* d_in, const int* in_sizes, int n_in,
                              void* d_out, int out_size, void* d_ws, size_t ws_size,
                              hipStream_t stream)
{
    const float* x_meas  = (const float*)d_in[0];
    const float* x_dem   = (const float*)d_in[1];
    const int*   src_m   = (const int*)d_in[2];
    const int*   dst_m   = (const int*)d_in[3];
    const int*   src_b   = (const int*)d_in[4];
    const int*   dst_b   = (const int*)d_in[5];
    const float* edge_w  = (const float*)d_in[6];
    const float* W_rel1  = (const float*)d_in[7];
    const float* b_rel1  = (const float*)d_in[8];
    const float* W_root1 = (const float*)d_in[9];
    const float* W_rel2  = (const float*)d_in[10];
    const float* b_rel2  = (const float*)d_in[11];
    const float* W_root2 = (const float*)d_in[12];
    const float* W_rel3  = (const float*)d_in[13];
    const float* b_rel3  = (const float*)d_in[14];
    const float* W_root3 = (const float*)d_in[15];
    const float* W_lin   = (const float*)d_in[16];
    const float* b_lin   = (const float*)d_in[17];
    float* out = (float*)d_out;

    const int NM = 50000, ND = 20000, E = 600000;

    char* p = (char*)d_ws;
    auto alloc = [&](size_t bytes) { char* r = p; p += (bytes + 511) & ~(size_t)511; return r; };
    int*   deg_m  = (int*)alloc((size_t)NM * 4);
    int*   rp_m   = (int*)alloc((size_t)NM * 4);
    int*   deg_b  = (int*)alloc((size_t)ND * 4);
    int*   rp_b   = (int*)alloc((size_t)ND * 4);
    int*   srcs_m = (int*)alloc((size_t)E * 4);
    int*   srcs_b = (int*)alloc((size_t)E * 4);
    float* wsrt_b = (float*)alloc((size_t)E * 4);
    float* agg1   = (float*)alloc((size_t)NM * 128 * 4);   // 25.6 MB
    float* agg2   = (float*)alloc((size_t)ND * 128 * 4);   // 10.24 MB
    float* movie  = (float*)alloc((size_t)NM * 128 * 4);   // 25.6 MB
    float* t2     = (float*)alloc((size_t)ND * 128 * 4);   // 10.24 MB
    u16* w1r_h = (u16*)alloc(128 * 128 * 2); u16* w1r_l = (u16*)alloc(128 * 128 * 2);
    u16* w1o_h = (u16*)alloc(128 * 128 * 2); u16* w1o_l = (u16*)alloc(128 * 128 * 2);
    u16* w2r_h = (u16*)alloc(128 * 128 * 2); u16* w2r_l = (u16*)alloc(128 * 128 * 2);
    u16* w2o_h = (u16*)alloc(128 * 128 * 2); u16* w2o_l = (u16*)alloc(128 * 128 * 2);
    u16* w3r_h = (u16*)alloc(128 * 128 * 2); u16* w3r_l = (u16*)alloc(128 * 128 * 2);
    u16* w3o_h = (u16*)alloc(128 * 128 * 2); u16* w3o_l = (u16*)alloc(128 * 128 * 2);
    u16* wl_h  = (u16*)alloc(128 * 64 * 2);  u16* wl_l  = (u16*)alloc(128 * 64 * 2);
    float* agg3 = agg1;   // agg1 dead after conv1
    float* t3   = agg2;   // agg2 dead after conv2

    hipMemsetAsync(deg_m, 0, (size_t)NM * 4, stream);
    hipMemsetAsync(deg_b, 0, (size_t)ND * 4, stream);

    const int eb2 = (2 * E + 255) / 256;
    hist_kernel<<<eb2, 256, 0, stream>>>(dst_m, dst_b, deg_m, deg_b, E);
    scan2_kernel<<<2, 1024, 0, stream>>>(deg_m, rp_m, NM, deg_b, rp_b, ND);
    fill_kernel<<<eb2, 256, 0, stream>>>(src_m, dst_m, src_b, dst_b, edge_w,
                                         rp_m, rp_b, srcs_m, srcs_b, wsrt_b, E);

    // weight transpose+split (tiny)
    wsplit_kernel<<<64, 256, 0, stream>>>(W_rel1,  w1r_h, w1r_l, 128, 128);
    wsplit_kernel<<<64, 256, 0, stream>>>(W_root1, w1o_h, w1o_l, 128, 128);
    wsplit_kernel<<<64, 256, 0, stream>>>(W_rel2,  w2r_h, w2r_l, 128, 128);
    wsplit_kernel<<<64, 256, 0, stream>>>(W_root2, w2o_h, w2o_l, 128, 128);
    wsplit_kernel<<<64, 256, 0, stream>>>(W_rel3,  w3r_h, w3r_l, 128, 128);
    wsplit_kernel<<<64, 256, 0, stream>>>(W_root3, w3o_h, w3o_l, 128, 128);
    wsplit_kernel<<<32, 256, 0, stream>>>(W_lin,   wl_h,  wl_l,  128, 64);

    // aggregations (fp32, round-3 proven)
    gather_agg<false><<<(NM + 3) / 4, 256, 0, stream>>>(x_meas, srcs_m, nullptr, rp_m, agg1, NM);
    gather_agg<true ><<<(ND + 3) / 4, 256, 0, stream>>>(x_meas, srcs_b, wsrt_b, rp_b, agg2, ND);

    // conv1: movie = relu(agg1@W_rel1 + b1 + x_meas@W_root1)
    const int cb1 = (((NM + 31) / 32) + 3) / 4;
    conv_mfma<<<cb1, 256, 0, stream>>>(agg1, w1r_h, w1r_l, b_rel1,
                                       x_meas, w1o_h, w1o_l, movie, NM);
    // conv2: t2 = relu(agg2@W_rel2 + b2 + x_dem@W_root2)
    const int cb2 = (((ND + 31) / 32) + 3) / 4;
    conv_mfma<<<cb2, 256, 0, stream>>>(agg2, w2r_h, w2r_l, b_rel2,
                                       x_dem, w2o_h, w2o_l, t2, ND);

    // agg3 = sum_e w * movie[src_b]
    gather_agg<true><<<(ND + 3) / 4, 256, 0, stream>>>(movie, srcs_b, wsrt_b, rp_b, agg3, ND);

    // conv3: t3 = relu(agg3@W_rel3 + b3 + t2@W_root3)
    conv_mfma<<<cb2, 256, 0, stream>>>(agg3, w3r_h, w3r_l, b_rel3,
                                       t2, w3o_h, w3o_l, t3, ND);

    // out = t3@W_lin + b_lin
    lin_mfma<<<cb2, 256, 0, stream>>>(t3, wl_h, wl_l, b_lin, out, ND);
}

// Round 6
// 545.586 us; speedup vs baseline: 12.0580x; 1.0388x over previous
//
#include <hip/hip_runtime.h>

// Round 6: packed (src,w) edges for graph b (one 8B scattered store),
// half-wave float4 gather (2 edges per load instr, unroll-2), fused wsplit.
// MFMA conv/lin kernels proven in round 5 (absmax 0.25). ws ~= 79.9 MB.

typedef unsigned short u16;
typedef unsigned int u32;
typedef __attribute__((ext_vector_type(8))) short bf16x8;
typedef __attribute__((ext_vector_type(4))) float f32x4;

__device__ __forceinline__ float bf2f(u16 h) {
    union { u32 u; float f; } v; v.u = ((u32)h) << 16; return v.f;
}
__device__ __forceinline__ u16 f2bf(float f) {
    union { float f; u32 u; } v; v.f = f;
    u32 lsb = (v.u >> 16) & 1u;
    v.u += 0x7fffu + lsb;           // RNE
    return (u16)(v.u >> 16);
}
__device__ __forceinline__ void split2(float v, u16& h, u16& l) {
    u16 hb = f2bf(v);
    h = hb; l = f2bf(v - bf2f(hb));
}
__device__ __forceinline__ void split8(const float* __restrict__ p, bf16x8& h, bf16x8& l) {
    float4 u = *(const float4*)p;
    float4 w = *(const float4*)(p + 4);
    float a[8] = {u.x, u.y, u.z, u.w, w.x, w.y, w.z, w.w};
#pragma unroll
    for (int j = 0; j < 8; ++j) {
        u16 hh, ll; split2(a[j], hh, ll);
        h[j] = (short)hh; l[j] = (short)ll;
    }
}

// ---------------- CSR build ----------------
__global__ __launch_bounds__(256)
void hist_kernel(const int* __restrict__ dst_m, const int* __restrict__ dst_b,
                 int* __restrict__ deg_m, int* __restrict__ deg_b, int E)
{
    int t = blockIdx.x * 256 + threadIdx.x;
    if (t < E) {
        atomicAdd(&deg_m[dst_m[t]], 1);
    } else if (t < 2 * E) {
        atomicAdd(&deg_b[dst_b[t - E]], 1);
    }
}

__device__ __forceinline__ int wave_incl_scan(int v, int lane) {
#pragma unroll
    for (int off = 1; off < 64; off <<= 1) {
        int t = __shfl_up(v, off, 64);
        if (lane >= off) v += t;
    }
    return v;
}

__global__ __launch_bounds__(1024)
void scan2_kernel(const int* __restrict__ degA, int* __restrict__ rpA, int nA,
                  const int* __restrict__ degB, int* __restrict__ rpB, int nB)
{
    const int* deg = blockIdx.x ? degB : degA;
    int* rp = blockIdx.x ? rpB : rpA;
    int n = blockIdx.x ? nB : nA;

    __shared__ int wsum[16];
    __shared__ int carry;
    const int tid = threadIdx.x, lane = tid & 63, wid = tid >> 6;
    if (tid == 0) carry = 0;
    __syncthreads();

    for (int base = 0; base < n; base += 1024) {
        int idx = base + tid;
        int v = (idx < n) ? deg[idx] : 0;
        int incl = wave_incl_scan(v, lane);
        if (lane == 63) wsum[wid] = incl;
        __syncthreads();
        if (wid == 0) {
            int s = (lane < 16) ? wsum[lane] : 0;
            int si = wave_incl_scan(s, lane);
            if (lane < 16) wsum[lane] = si - s;
        }
        __syncthreads();
        if (idx < n) rp[idx] = carry + wsum[wid] + incl - v;
        __syncthreads();
        if (tid == 1023) carry += wsum[15] + incl;
        __syncthreads();
    }
}

// fill: graph m -> srcs_m[pos]=src; graph b -> edges_b[pos]={src, bits(sigmoid(w))}
__global__ __launch_bounds__(256)
void fill_kernel(const int* __restrict__ src_m, const int* __restrict__ dst_m,
                 const int* __restrict__ src_b, const int* __restrict__ dst_b,
                 const float* __restrict__ edge_w,
                 int* __restrict__ rp_m, int* __restrict__ rp_b,
                 int* __restrict__ srcs_m, int2* __restrict__ edges_b, int E)
{
    int t = blockIdx.x * 256 + threadIdx.x;
    if (t < E) {
        int pos = atomicAdd(&rp_m[dst_m[t]], 1);
        srcs_m[pos] = src_m[t];
    } else if (t < 2 * E) {
        int e = t - E;
        int pos = atomicAdd(&rp_b[dst_b[e]], 1);
        float x = edge_w[e];
        int2 pk;
        pk.x = src_b[e];
        pk.y = __float_as_int(1.0f / (1.0f + __expf(-x)));
        edges_b[pos] = pk;
    }
}

// ---------------- half-wave float4 CSR gather ----------------
// Wave = 1 node; each 32-lane half handles alternate edges; lane covers 4 cols.
template<bool WEIGHTED>
__global__ __launch_bounds__(256)
void gather_agg(const float* __restrict__ X, const int* __restrict__ srcs,
                const int2* __restrict__ edges, const int* __restrict__ rp,
                float* __restrict__ out, int N)
{
    int node = blockIdx.x * 4 + (threadIdx.x >> 6);
    if (node >= N) return;
    const int lane = threadIdx.x & 63;
    const int half = lane >> 5;
    const int cl   = lane & 31;
    int end = rp[node];
    int i   = node ? rp[node - 1] : 0;

    float4 acc = make_float4(0.f, 0.f, 0.f, 0.f);
    for (; i + 4 <= end; i += 4) {      // 4 edges in flight (2 per half)
        int e0 = i + half, e1 = i + 2 + half;
        int s0, s1; float w0 = 1.f, w1 = 1.f;
        if (WEIGHTED) {
            int2 p0 = edges[e0], p1 = edges[e1];
            s0 = p0.x; w0 = __int_as_float(p0.y);
            s1 = p1.x; w1 = __int_as_float(p1.y);
        } else { s0 = srcs[e0]; s1 = srcs[e1]; }
        float4 v0 = *(const float4*)(X + (size_t)s0 * 128 + cl * 4);
        float4 v1 = *(const float4*)(X + (size_t)s1 * 128 + cl * 4);
        acc.x = fmaf(w0, v0.x, acc.x); acc.y = fmaf(w0, v0.y, acc.y);
        acc.z = fmaf(w0, v0.z, acc.z); acc.w = fmaf(w0, v0.w, acc.w);
        acc.x = fmaf(w1, v1.x, acc.x); acc.y = fmaf(w1, v1.y, acc.y);
        acc.z = fmaf(w1, v1.z, acc.z); acc.w = fmaf(w1, v1.w, acc.w);
    }
    for (; i + 2 <= end; i += 2) {      // 2 edges (1 per half)
        int e = i + half;
        int s; float w = 1.f;
        if (WEIGHTED) { int2 pk = edges[e]; s = pk.x; w = __int_as_float(pk.y); }
        else s = srcs[e];
        float4 v = *(const float4*)(X + (size_t)s * 128 + cl * 4);
        acc.x = fmaf(w, v.x, acc.x); acc.y = fmaf(w, v.y, acc.y);
        acc.z = fmaf(w, v.z, acc.z); acc.w = fmaf(w, v.w, acc.w);
    }
    if (i < end && half == 0) {         // odd tail: half 0 only
        int s; float w = 1.f;
        if (WEIGHTED) { int2 pk = edges[i]; s = pk.x; w = __int_as_float(pk.y); }
        else s = srcs[i];
        float4 v = *(const float4*)(X + (size_t)s * 128 + cl * 4);
        acc.x = fmaf(w, v.x, acc.x); acc.y = fmaf(w, v.y, acc.y);
        acc.z = fmaf(w, v.z, acc.z); acc.w = fmaf(w, v.w, acc.w);
    }
    // combine halves (xor-partner shuffle), half 0 stores
    float4 o;
    o.x = __shfl(acc.x, lane ^ 32);
    o.y = __shfl(acc.y, lane ^ 32);
    o.z = __shfl(acc.z, lane ^ 32);
    o.w = __shfl(acc.w, lane ^ 32);
    if (half == 0) {
        float4 r;
        r.x = acc.x + o.x; r.y = acc.y + o.y;
        r.z = acc.z + o.z; r.w = acc.w + o.w;
        *(float4*)(out + (size_t)node * 128 + cl * 4) = r;
    }
}

// ---------------- fused weight transpose+split: 7 weights, 1 launch ----------
// Slot widx occupies wbuf[widx*32768 .. ]: h at +0, l at +16384 (u16 units).
__global__ __launch_bounds__(256)
void wsplit_all(const float* __restrict__ w0, const float* __restrict__ w1,
                const float* __restrict__ w2, const float* __restrict__ w3,
                const float* __restrict__ w4, const float* __restrict__ w5,
                const float* __restrict__ w6, u16* __restrict__ wbuf)
{
    const int widx = blockIdx.x >> 6;                       // 64 blocks per slot
    const int off  = ((blockIdx.x & 63) << 8) + threadIdx.x;
    const int OC   = (widx == 6) ? 64 : 128;
    if (off >= OC * 128) return;
    const float* W;
    switch (widx) {
        case 0: W = w0; break; case 1: W = w1; break; case 2: W = w2; break;
        case 3: W = w3; break; case 4: W = w4; break; case 5: W = w5; break;
        default: W = w6;
    }
    int k = off / OC, n = off % OC;                         // src index == off
    u16 h, l;
    split2(W[off], h, l);
    u16* slot = wbuf + widx * 32768;
    slot[n * 128 + k]         = h;
    slot[16384 + n * 128 + k] = l;
}

// ---------------- MFMA conv: C = relu(A1@W1 + bias + A2@W2) (round-5 proven) --
__global__ __launch_bounds__(256)
void conv_mfma(const float* __restrict__ A1,
               const u16* __restrict__ W1h, const u16* __restrict__ W1l,
               const float* __restrict__ bias,
               const float* __restrict__ A2,
               const u16* __restrict__ W2h, const u16* __restrict__ W2l,
               float* __restrict__ Cout, int N)
{
    const int wid  = (blockIdx.x * 256 + threadIdx.x) >> 6;
    const int lane = threadIdx.x & 63;
    const int m0   = wid * 32;
    if (m0 >= N) return;
    const int lr   = lane & 15;
    const int quad = lane >> 4;

    f32x4 acc[2][8];
#pragma unroll
    for (int mt = 0; mt < 2; ++mt)
#pragma unroll
        for (int n = 0; n < 8; ++n) acc[mt][n] = (f32x4){0.f, 0.f, 0.f, 0.f};

    int r0 = m0 + lr;      if (r0 >= N) r0 = N - 1;
    int r1 = m0 + 16 + lr; if (r1 >= N) r1 = N - 1;

#pragma unroll
    for (int phase = 0; phase < 2; ++phase) {
        const float* A  = phase ? A2  : A1;
        const u16*   Wh = phase ? W2h : W1h;
        const u16*   Wl = phase ? W2l : W1l;
#pragma unroll
        for (int c = 0; c < 4; ++c) {
            const int kb = c * 32 + quad * 8;
            bf16x8 a0h, a0l, a1h, a1l;
            split8(A + (size_t)r0 * 128 + kb, a0h, a0l);
            split8(A + (size_t)r1 * 128 + kb, a1h, a1l);
#pragma unroll
            for (int n = 0; n < 8; ++n) {
                bf16x8 bh = *(const bf16x8*)(Wh + (size_t)(n * 16 + lr) * 128 + kb);
                bf16x8 bl = *(const bf16x8*)(Wl + (size_t)(n * 16 + lr) * 128 + kb);
                acc[0][n] = __builtin_amdgcn_mfma_f32_16x16x32_bf16(a0h, bh, acc[0][n], 0, 0, 0);
                acc[0][n] = __builtin_amdgcn_mfma_f32_16x16x32_bf16(a0l, bh, acc[0][n], 0, 0, 0);
                acc[0][n] = __builtin_amdgcn_mfma_f32_16x16x32_bf16(a0h, bl, acc[0][n], 0, 0, 0);
                acc[1][n] = __builtin_amdgcn_mfma_f32_16x16x32_bf16(a1h, bh, acc[1][n], 0, 0, 0);
                acc[1][n] = __builtin_amdgcn_mfma_f32_16x16x32_bf16(a1l, bh, acc[1][n], 0, 0, 0);
                acc[1][n] = __builtin_amdgcn_mfma_f32_16x16x32_bf16(a1h, bl, acc[1][n], 0, 0, 0);
            }
        }
    }

#pragma unroll
    for (int mt = 0; mt < 2; ++mt) {
#pragma unroll
        for (int n = 0; n < 8; ++n) {
            const int col = n * 16 + lr;
            const float b = bias[col];
#pragma unroll
            for (int r = 0; r < 4; ++r) {
                int row = m0 + mt * 16 + quad * 4 + r;
                if (row >= N) continue;
                Cout[(size_t)row * 128 + col] = fmaxf(acc[mt][n][r] + b, 0.f);
            }
        }
    }
}

// ---------------- MFMA final lin: out = A@W + bias, OC=64 (round-5 proven) ----
__global__ __launch_bounds__(256)
void lin_mfma(const float* __restrict__ A,
              const u16* __restrict__ Wh, const u16* __restrict__ Wl,
              const float* __restrict__ bias, float* __restrict__ out, int N)
{
    const int wid  = (blockIdx.x * 256 + threadIdx.x) >> 6;
    const int lane = threadIdx.x & 63;
    const int m0   = wid * 32;
    if (m0 >= N) return;
    const int lr   = lane & 15;
    const int quad = lane >> 4;

    f32x4 acc[2][4];
#pragma unroll
    for (int mt = 0; mt < 2; ++mt)
#pragma unroll
        for (int n = 0; n < 4; ++n) acc[mt][n] = (f32x4){0.f, 0.f, 0.f, 0.f};

    int r0 = m0 + lr;      if (r0 >= N) r0 = N - 1;
    int r1 = m0 + 16 + lr; if (r1 >= N) r1 = N - 1;

#pragma unroll
    for (int c = 0; c < 4; ++c) {
        const int kb = c * 32 + quad * 8;
        bf16x8 a0h, a0l, a1h, a1l;
        split8(A + (size_t)r0 * 128 + kb, a0h, a0l);
        split8(A + (size_t)r1 * 128 + kb, a1h, a1l);
#pragma unroll
        for (int n = 0; n < 4; ++n) {
            bf16x8 bh = *(const bf16x8*)(Wh + (size_t)(n * 16 + lr) * 128 + kb);
            bf16x8 bl = *(const bf16x8*)(Wl + (size_t)(n * 16 + lr) * 128 + kb);
            acc[0][n] = __builtin_amdgcn_mfma_f32_16x16x32_bf16(a0h, bh, acc[0][n], 0, 0, 0);
            acc[0][n] = __builtin_amdgcn_mfma_f32_16x16x32_bf16(a0l, bh, acc[0][n], 0, 0, 0);
            acc[0][n] = __builtin_amdgcn_mfma_f32_16x16x32_bf16(a0h, bl, acc[0][n], 0, 0, 0);
            acc[1][n] = __builtin_amdgcn_mfma_f32_16x16x32_bf16(a1h, bh, acc[1][n], 0, 0, 0);
            acc[1][n] = __builtin_amdgcn_mfma_f32_16x16x32_bf16(a1l, bh, acc[1][n], 0, 0, 0);
            acc[1][n] = __builtin_amdgcn_mfma_f32_16x16x32_bf16(a1h, bl, acc[1][n], 0, 0, 0);
        }
    }

#pragma unroll
    for (int mt = 0; mt < 2; ++mt) {
#pragma unroll
        for (int n = 0; n < 4; ++n) {
            const int col = n * 16 + lr;
            const float b = bias[col];
#pragma unroll
            for (int r = 0; r < 4; ++r) {
                int row = m0 + mt * 16 + quad * 4 + r;
                if (row >= N) continue;
                out[(size_t)row * 64 + col] = acc[mt][n][r] + b;
            }
        }
    }
}

extern "C" void kernel_launch(void* const* d_in, const int* in_sizes, int n_in,
                              void* d_out, int out_size, void* d_ws, size_t ws_size,
                              hipStream_t stream)
{
    const float* x_meas  = (const float*)d_in[0];
    const float* x_dem   = (const float*)d_in[1];
    const int*   src_m   = (const int*)d_in[2];
    const int*   dst_m   = (const int*)d_in[3];
    const int*   src_b   = (const int*)d_in[4];
    const int*   dst_b   = (const int*)d_in[5];
    const float* edge_w  = (const float*)d_in[6];
    const float* W_rel1  = (const float*)d_in[7];
    const float* b_rel1  = (const float*)d_in[8];
    const float* W_root1 = (const float*)d_in[9];
    const float* W_rel2  = (const float*)d_in[10];
    const float* b_rel2  = (const float*)d_in[11];
    const float* W_root2 = (const float*)d_in[12];
    const float* W_rel3  = (const float*)d_in[13];
    const float* b_rel3  = (const float*)d_in[14];
    const float* W_root3 = (const float*)d_in[15];
    const float* W_lin   = (const float*)d_in[16];
    const float* b_lin   = (const float*)d_in[17];
    float* out = (float*)d_out;

    const int NM = 50000, ND = 20000, E = 600000;

    char* p = (char*)d_ws;
    auto alloc = [&](size_t bytes) { char* r = p; p += (bytes + 511) & ~(size_t)511; return r; };
    int*   deg_m   = (int*)alloc((size_t)NM * 4);          // deg_m, deg_b adjacent
    int*   deg_b   = (int*)alloc((size_t)ND * 4);          //   -> single memset
    int*   rp_m    = (int*)alloc((size_t)NM * 4);
    int*   rp_b    = (int*)alloc((size_t)ND * 4);
    int*   srcs_m  = (int*)alloc((size_t)E * 4);
    int2*  edges_b = (int2*)alloc((size_t)E * 8);
    float* agg1    = (float*)alloc((size_t)NM * 128 * 4);  // 25.6 MB
    float* agg2    = (float*)alloc((size_t)ND * 128 * 4);  // 10.24 MB
    float* movie   = (float*)alloc((size_t)NM * 128 * 4);  // 25.6 MB
    float* t2      = (float*)alloc((size_t)ND * 128 * 4);  // 10.24 MB
    u16*   wbuf    = (u16*)alloc(7 * 32768 * 2);           // 0.44 MB
    float* agg3 = agg1;   // agg1 dead after conv1
    float* t3   = agg2;   // agg2 dead after conv2

    // split-weight slot pointers
    u16* w1r_h = wbuf + 0 * 32768; u16* w1r_l = w1r_h + 16384;
    u16* w1o_h = wbuf + 1 * 32768; u16* w1o_l = w1o_h + 16384;
    u16* w2r_h = wbuf + 2 * 32768; u16* w2r_l = w2r_h + 16384;
    u16* w2o_h = wbuf + 3 * 32768; u16* w2o_l = w2o_h + 16384;
    u16* w3r_h = wbuf + 4 * 32768; u16* w3r_l = w3r_h + 16384;
    u16* w3o_h = wbuf + 5 * 32768; u16* w3o_l = w3o_h + 16384;
    u16* wl_h  = wbuf + 6 * 32768; u16* wl_l  = wl_h  + 16384;

    size_t deg_span = (size_t)((char*)deg_b - (char*)deg_m) + (size_t)ND * 4;
    hipMemsetAsync(deg_m, 0, deg_span, stream);

    const int eb2 = (2 * E + 255) / 256;
    hist_kernel<<<eb2, 256, 0, stream>>>(dst_m, dst_b, deg_m, deg_b, E);
    scan2_kernel<<<2, 1024, 0, stream>>>(deg_m, rp_m, NM, deg_b, rp_b, ND);
    fill_kernel<<<eb2, 256, 0, stream>>>(src_m, dst_m, src_b, dst_b, edge_w,
                                         rp_m, rp_b, srcs_m, edges_b, E);

    wsplit_all<<<448, 256, 0, stream>>>(W_rel1, W_root1, W_rel2, W_root2,
                                        W_rel3, W_root3, W_lin, wbuf);

    // aggregations
    gather_agg<false><<<(NM + 3) / 4, 256, 0, stream>>>(x_meas, srcs_m, nullptr, rp_m, agg1, NM);
    gather_agg<true ><<<(ND + 3) / 4, 256, 0, stream>>>(x_meas, nullptr, edges_b, rp_b, agg2, ND);

    // conv1: movie = relu(agg1@W_rel1 + b1 + x_meas@W_root1)
    const int cb1 = (((NM + 31) / 32) + 3) / 4;
    conv_mfma<<<cb1, 256, 0, stream>>>(agg1, w1r_h, w1r_l, b_rel1,
                                       x_meas, w1o_h, w1o_l, movie, NM);
    // conv2: t2 = relu(agg2@W_rel2 + b2 + x_dem@W_root2)
    const int cb2 = (((ND + 31) / 32) + 3) / 4;
    conv_mfma<<<cb2, 256, 0, stream>>>(agg2, w2r_h, w2r_l, b_rel2,
                                       x_dem, w2o_h, w2o_l, t2, ND);

    // agg3 = sum_e w * movie[src_b]
    gather_agg<true><<<(ND + 3) / 4, 256, 0, stream>>>(movie, nullptr, edges_b, rp_b, agg3, ND);

    // conv3: t3 = relu(agg3@W_rel3 + b3 + t2@W_root3)
    conv_mfma<<<cb2, 256, 0, stream>>>(agg3, w3r_h, w3r_l, b_rel3,
                                       t2, w3o_h, w3o_l, t3, ND);

    // out = t3@W_lin + b_lin
    lin_mfma<<<cb2, 256, 0, stream>>>(t3, wl_h, wl_l, b_lin, out, ND);
}

// Round 7
// 526.734 us; speedup vs baseline: 12.4896x; 1.0358x over previous
//
#include <hip/hip_runtime.h>

// Round 7: packed pf32 intermediates (u32 = bf16hi | bf16lo<<16, byte-equal to
// fp32), cheap unpack in MFMA convs; half-wave-per-node unroll-4 gathers;
// merged gather1+2 and conv1+2 launches. fill/hist/scan CSR build unchanged.

typedef unsigned short u16;
typedef unsigned int u32;
typedef __attribute__((ext_vector_type(8))) short bf16x8;
typedef __attribute__((ext_vector_type(4))) float f32x4;

__device__ __forceinline__ float bf2f(u16 h) {
    union { u32 u; float f; } v; v.u = ((u32)h) << 16; return v.f;
}
__device__ __forceinline__ u16 f2bf(float f) {
    union { float f; u32 u; } v; v.f = f;
    u32 lsb = (v.u >> 16) & 1u;
    v.u += 0x7fffu + lsb;           // RNE
    return (u16)(v.u >> 16);
}
__device__ __forceinline__ void split2(float v, u16& h, u16& l) {
    u16 hb = f2bf(v);
    h = hb; l = f2bf(v - bf2f(hb));
}
// fp32 -> packed (hi | lo<<16), trunc-hi split (error ~2^-24 rel)
__device__ __forceinline__ u32 packf(float v) {
    u32 b = __float_as_uint(v);
    float hf = __uint_as_float(b & 0xffff0000u);
    u16 l = f2bf(v - hf);
    return (b >> 16) | ((u32)l << 16);
}
// packed -> fp32 (h + l)
__device__ __forceinline__ float unpackf(u32 w) {
    return __uint_as_float(w << 16) + __uint_as_float(w & 0xffff0000u);
}
// 8 consecutive fp32 -> hi/lo bf16x8 fragments (RNE split, proven r5)
__device__ __forceinline__ void split8(const float* __restrict__ p, bf16x8& h, bf16x8& l) {
    float4 u = *(const float4*)p;
    float4 w = *(const float4*)(p + 4);
    float a[8] = {u.x, u.y, u.z, u.w, w.x, w.y, w.z, w.w};
#pragma unroll
    for (int j = 0; j < 8; ++j) {
        u16 hh, ll; split2(a[j], hh, ll);
        h[j] = (short)hh; l[j] = (short)ll;
    }
}
// 8 packed u32 -> hi/lo bf16x8 fragments (cheap: extract 16-bit halves)
__device__ __forceinline__ void unpack8(const u32* __restrict__ p, bf16x8& h, bf16x8& l) {
    uint4 a = *(const uint4*)p;
    uint4 b = *(const uint4*)(p + 4);
    h[0] = (short)a.x; l[0] = (short)(a.x >> 16);
    h[1] = (short)a.y; l[1] = (short)(a.y >> 16);
    h[2] = (short)a.z; l[2] = (short)(a.z >> 16);
    h[3] = (short)a.w; l[3] = (short)(a.w >> 16);
    h[4] = (short)b.x; l[4] = (short)(b.x >> 16);
    h[5] = (short)b.y; l[5] = (short)(b.y >> 16);
    h[6] = (short)b.z; l[6] = (short)(b.z >> 16);
    h[7] = (short)b.w; l[7] = (short)(b.w >> 16);
}

// ---------------- CSR build (r3-proven) ----------------
__global__ __launch_bounds__(256)
void hist_kernel(const int* __restrict__ dst_m, const int* __restrict__ dst_b,
                 int* __restrict__ deg_m, int* __restrict__ deg_b, int E)
{
    int t = blockIdx.x * 256 + threadIdx.x;
    if (t < E) {
        atomicAdd(&deg_m[dst_m[t]], 1);
    } else if (t < 2 * E) {
        atomicAdd(&deg_b[dst_b[t - E]], 1);
    }
}

__device__ __forceinline__ int wave_incl_scan(int v, int lane) {
#pragma unroll
    for (int off = 1; off < 64; off <<= 1) {
        int t = __shfl_up(v, off, 64);
        if (lane >= off) v += t;
    }
    return v;
}

__global__ __launch_bounds__(1024)
void scan2_kernel(const int* __restrict__ degA, int* __restrict__ rpA, int nA,
                  const int* __restrict__ degB, int* __restrict__ rpB, int nB)
{
    const int* deg = blockIdx.x ? degB : degA;
    int* rp = blockIdx.x ? rpB : rpA;
    int n = blockIdx.x ? nB : nA;

    __shared__ int wsum[16];
    __shared__ int carry;
    const int tid = threadIdx.x, lane = tid & 63, wid = tid >> 6;
    if (tid == 0) carry = 0;
    __syncthreads();

    for (int base = 0; base < n; base += 1024) {
        int idx = base + tid;
        int v = (idx < n) ? deg[idx] : 0;
        int incl = wave_incl_scan(v, lane);
        if (lane == 63) wsum[wid] = incl;
        __syncthreads();
        if (wid == 0) {
            int s = (lane < 16) ? wsum[lane] : 0;
            int si = wave_incl_scan(s, lane);
            if (lane < 16) wsum[lane] = si - s;
        }
        __syncthreads();
        if (idx < n) rp[idx] = carry + wsum[wid] + incl - v;
        __syncthreads();
        if (tid == 1023) carry += wsum[15] + incl;
        __syncthreads();
    }
}

__global__ __launch_bounds__(256)
void fill_kernel(const int* __restrict__ src_m, const int* __restrict__ dst_m,
                 const int* __restrict__ src_b, const int* __restrict__ dst_b,
                 const float* __restrict__ edge_w,
                 int* __restrict__ rp_m, int* __restrict__ rp_b,
                 int* __restrict__ srcs_m, int2* __restrict__ edges_b, int E)
{
    int t = blockIdx.x * 256 + threadIdx.x;
    if (t < E) {
        int pos = atomicAdd(&rp_m[dst_m[t]], 1);
        srcs_m[pos] = src_m[t];
    } else if (t < 2 * E) {
        int e = t - E;
        int pos = atomicAdd(&rp_b[dst_b[e]], 1);
        float x = edge_w[e];
        int2 pk;
        pk.x = src_b[e];
        pk.y = __float_as_int(1.0f / (1.0f + __expf(-x)));
        edges_b[pos] = pk;
    }
}

// ---------------- merged gather1+2: fp32 X -> packed agg ----------------
// One node per 32-lane half; lane covers 4 cols (float4); unroll-4.
__global__ __launch_bounds__(256)
void gather12(const float* __restrict__ X, const float* __restrict__ Xd_unused,
              const int* __restrict__ srcs_m, const int2* __restrict__ edges_b,
              const int* __restrict__ rp_m, const int* __restrict__ rp_b,
              u32* __restrict__ agg1, u32* __restrict__ agg2, int NM, int ND)
{
    const int h  = blockIdx.x * 8 + (threadIdx.x >> 5);
    const int cl = threadIdx.x & 31;
    float4 acc = make_float4(0.f, 0.f, 0.f, 0.f);

    if (h < NM) {
        int end = rp_m[h];
        int i   = h ? rp_m[h - 1] : 0;
        for (; i + 4 <= end; i += 4) {
            int s0 = srcs_m[i], s1 = srcs_m[i + 1], s2 = srcs_m[i + 2], s3 = srcs_m[i + 3];
            float4 v0 = *(const float4*)(X + (size_t)s0 * 128 + cl * 4);
            float4 v1 = *(const float4*)(X + (size_t)s1 * 128 + cl * 4);
            float4 v2 = *(const float4*)(X + (size_t)s2 * 128 + cl * 4);
            float4 v3 = *(const float4*)(X + (size_t)s3 * 128 + cl * 4);
            acc.x += v0.x + v1.x + v2.x + v3.x;
            acc.y += v0.y + v1.y + v2.y + v3.y;
            acc.z += v0.z + v1.z + v2.z + v3.z;
            acc.w += v0.w + v1.w + v2.w + v3.w;
        }
        for (; i < end; ++i) {
            int s = srcs_m[i];
            float4 v = *(const float4*)(X + (size_t)s * 128 + cl * 4);
            acc.x += v.x; acc.y += v.y; acc.z += v.z; acc.w += v.w;
        }
        uint4 st;
        st.x = packf(acc.x); st.y = packf(acc.y);
        st.z = packf(acc.z); st.w = packf(acc.w);
        *(uint4*)(agg1 + (size_t)h * 128 + cl * 4) = st;
    } else if (h < NM + ND) {
        int node = h - NM;
        int end = rp_b[node];
        int i   = node ? rp_b[node - 1] : 0;
        for (; i + 4 <= end; i += 4) {
            int2 p0 = edges_b[i],     p1 = edges_b[i + 1];
            int2 p2 = edges_b[i + 2], p3 = edges_b[i + 3];
            float w0 = __int_as_float(p0.y), w1 = __int_as_float(p1.y);
            float w2 = __int_as_float(p2.y), w3 = __int_as_float(p3.y);
            float4 v0 = *(const float4*)(X + (size_t)p0.x * 128 + cl * 4);
            float4 v1 = *(const float4*)(X + (size_t)p1.x * 128 + cl * 4);
            float4 v2 = *(const float4*)(X + (size_t)p2.x * 128 + cl * 4);
            float4 v3 = *(const float4*)(X + (size_t)p3.x * 128 + cl * 4);
            acc.x = fmaf(w0, v0.x, acc.x); acc.y = fmaf(w0, v0.y, acc.y);
            acc.z = fmaf(w0, v0.z, acc.z); acc.w = fmaf(w0, v0.w, acc.w);
            acc.x = fmaf(w1, v1.x, acc.x); acc.y = fmaf(w1, v1.y, acc.y);
            acc.z = fmaf(w1, v1.z, acc.z); acc.w = fmaf(w1, v1.w, acc.w);
            acc.x = fmaf(w2, v2.x, acc.x); acc.y = fmaf(w2, v2.y, acc.y);
            acc.z = fmaf(w2, v2.z, acc.z); acc.w = fmaf(w2, v2.w, acc.w);
            acc.x = fmaf(w3, v3.x, acc.x); acc.y = fmaf(w3, v3.y, acc.y);
            acc.z = fmaf(w3, v3.z, acc.z); acc.w = fmaf(w3, v3.w, acc.w);
        }
        for (; i < end; ++i) {
            int2 pk = edges_b[i];
            float w = __int_as_float(pk.y);
            float4 v = *(const float4*)(X + (size_t)pk.x * 128 + cl * 4);
            acc.x = fmaf(w, v.x, acc.x); acc.y = fmaf(w, v.y, acc.y);
            acc.z = fmaf(w, v.z, acc.z); acc.w = fmaf(w, v.w, acc.w);
        }
        uint4 st;
        st.x = packf(acc.x); st.y = packf(acc.y);
        st.z = packf(acc.z); st.w = packf(acc.w);
        *(uint4*)(agg2 + (size_t)node * 128 + cl * 4) = st;
    }
}

// ---------------- gather3: packed movie -> packed agg3, weighted ----------
__global__ __launch_bounds__(256)
void gather3_kernel(const u32* __restrict__ Mv, const int2* __restrict__ edges_b,
                    const int* __restrict__ rp_b, u32* __restrict__ agg3, int ND)
{
    const int node = blockIdx.x * 8 + (threadIdx.x >> 5);
    if (node >= ND) return;
    const int cl = threadIdx.x & 31;
    int end = rp_b[node];
    int i   = node ? rp_b[node - 1] : 0;

    float4 acc = make_float4(0.f, 0.f, 0.f, 0.f);
    for (; i + 4 <= end; i += 4) {
        int2 p0 = edges_b[i],     p1 = edges_b[i + 1];
        int2 p2 = edges_b[i + 2], p3 = edges_b[i + 3];
        float w0 = __int_as_float(p0.y), w1 = __int_as_float(p1.y);
        float w2 = __int_as_float(p2.y), w3 = __int_as_float(p3.y);
        uint4 a0 = *(const uint4*)(Mv + (size_t)p0.x * 128 + cl * 4);
        uint4 a1 = *(const uint4*)(Mv + (size_t)p1.x * 128 + cl * 4);
        uint4 a2 = *(const uint4*)(Mv + (size_t)p2.x * 128 + cl * 4);
        uint4 a3 = *(const uint4*)(Mv + (size_t)p3.x * 128 + cl * 4);
        acc.x = fmaf(w0, unpackf(a0.x), acc.x); acc.y = fmaf(w0, unpackf(a0.y), acc.y);
        acc.z = fmaf(w0, unpackf(a0.z), acc.z); acc.w = fmaf(w0, unpackf(a0.w), acc.w);
        acc.x = fmaf(w1, unpackf(a1.x), acc.x); acc.y = fmaf(w1, unpackf(a1.y), acc.y);
        acc.z = fmaf(w1, unpackf(a1.z), acc.z); acc.w = fmaf(w1, unpackf(a1.w), acc.w);
        acc.x = fmaf(w2, unpackf(a2.x), acc.x); acc.y = fmaf(w2, unpackf(a2.y), acc.y);
        acc.z = fmaf(w2, unpackf(a2.z), acc.z); acc.w = fmaf(w2, unpackf(a2.w), acc.w);
        acc.x = fmaf(w3, unpackf(a3.x), acc.x); acc.y = fmaf(w3, unpackf(a3.y), acc.y);
        acc.z = fmaf(w3, unpackf(a3.z), acc.z); acc.w = fmaf(w3, unpackf(a3.w), acc.w);
    }
    for (; i < end; ++i) {
        int2 pk = edges_b[i];
        float w = __int_as_float(pk.y);
        uint4 a = *(const uint4*)(Mv + (size_t)pk.x * 128 + cl * 4);
        acc.x = fmaf(w, unpackf(a.x), acc.x); acc.y = fmaf(w, unpackf(a.y), acc.y);
        acc.z = fmaf(w, unpackf(a.z), acc.z); acc.w = fmaf(w, unpackf(a.w), acc.w);
    }
    uint4 st;
    st.x = packf(acc.x); st.y = packf(acc.y);
    st.z = packf(acc.z); st.w = packf(acc.w);
    *(uint4*)(agg3 + (size_t)node * 128 + cl * 4) = st;
}

// ---------------- fused weight transpose+split ----------------
__global__ __launch_bounds__(256)
void wsplit_all(const float* __restrict__ w0, const float* __restrict__ w1,
                const float* __restrict__ w2, const float* __restrict__ w3,
                const float* __restrict__ w4, const float* __restrict__ w5,
                const float* __restrict__ w6, u16* __restrict__ wbuf)
{
    const int widx = blockIdx.x >> 6;
    const int off  = ((blockIdx.x & 63) << 8) + threadIdx.x;
    const int OC   = (widx == 6) ? 64 : 128;
    if (off >= OC * 128) return;
    const float* W;
    switch (widx) {
        case 0: W = w0; break; case 1: W = w1; break; case 2: W = w2; break;
        case 3: W = w3; break; case 4: W = w4; break; case 5: W = w5; break;
        default: W = w6;
    }
    int k = off / OC, n = off % OC;
    u16 h, l;
    split2(W[off], h, l);
    u16* slot = wbuf + widx * 32768;
    slot[n * 128 + k]         = h;
    slot[16384 + n * 128 + k] = l;
}

// ---------------- merged MFMA conv1+conv2 ----------------
// Phase 0: packed agg (unpack8). Phase 1: fp32 root X (split8).
// Output packed. Tile per wave: 32 rows x 128 cols. Split-3 MFMA.
__global__ __launch_bounds__(256)
void conv12_mfma(const u32* __restrict__ agg1, const u16* __restrict__ w1r,
                 const float* __restrict__ b1, const float* __restrict__ x1,
                 const u16* __restrict__ w1o, u32* __restrict__ C1, int N1, int cb1,
                 const u32* __restrict__ agg2, const u16* __restrict__ w2r,
                 const float* __restrict__ b2, const float* __restrict__ x2,
                 const u16* __restrict__ w2o, u32* __restrict__ C2, int N2)
{
    const u32* Ap; const u16 *Wr, *Wo; const float *bias, *Xf; u32* C; int N, base;
    if ((int)blockIdx.x < cb1) {
        Ap = agg1; Wr = w1r; Wo = w1o; bias = b1; Xf = x1; C = C1; N = N1; base = blockIdx.x;
    } else {
        Ap = agg2; Wr = w2r; Wo = w2o; bias = b2; Xf = x2; C = C2; N = N2; base = blockIdx.x - cb1;
    }
    const int lane = threadIdx.x & 63;
    const int m0   = (base * 4 + (threadIdx.x >> 6)) * 32;
    if (m0 >= N) return;
    const int lr   = lane & 15;
    const int quad = lane >> 4;

    f32x4 acc[2][8];
#pragma unroll
    for (int mt = 0; mt < 2; ++mt)
#pragma unroll
        for (int n = 0; n < 8; ++n) acc[mt][n] = (f32x4){0.f, 0.f, 0.f, 0.f};

    int r0 = m0 + lr;      if (r0 >= N) r0 = N - 1;
    int r1 = m0 + 16 + lr; if (r1 >= N) r1 = N - 1;

#pragma unroll
    for (int phase = 0; phase < 2; ++phase) {
        const u16* Wh = phase ? Wo : Wr;
        const u16* Wl = Wh + 16384;
#pragma unroll
        for (int c = 0; c < 4; ++c) {
            const int kb = c * 32 + quad * 8;
            bf16x8 a0h, a0l, a1h, a1l;
            if (phase == 0) {
                unpack8(Ap + (size_t)r0 * 128 + kb, a0h, a0l);
                unpack8(Ap + (size_t)r1 * 128 + kb, a1h, a1l);
            } else {
                split8(Xf + (size_t)r0 * 128 + kb, a0h, a0l);
                split8(Xf + (size_t)r1 * 128 + kb, a1h, a1l);
            }
#pragma unroll
            for (int n = 0; n < 8; ++n) {
                bf16x8 bh = *(const bf16x8*)(Wh + (size_t)(n * 16 + lr) * 128 + kb);
                bf16x8 bl = *(const bf16x8*)(Wl + (size_t)(n * 16 + lr) * 128 + kb);
                acc[0][n] = __builtin_amdgcn_mfma_f32_16x16x32_bf16(a0h, bh, acc[0][n], 0, 0, 0);
                acc[0][n] = __builtin_amdgcn_mfma_f32_16x16x32_bf16(a0l, bh, acc[0][n], 0, 0, 0);
                acc[0][n] = __builtin_amdgcn_mfma_f32_16x16x32_bf16(a0h, bl, acc[0][n], 0, 0, 0);
                acc[1][n] = __builtin_amdgcn_mfma_f32_16x16x32_bf16(a1h, bh, acc[1][n], 0, 0, 0);
                acc[1][n] = __builtin_amdgcn_mfma_f32_16x16x32_bf16(a1l, bh, acc[1][n], 0, 0, 0);
                acc[1][n] = __builtin_amdgcn_mfma_f32_16x16x32_bf16(a1h, bl, acc[1][n], 0, 0, 0);
            }
        }
    }

#pragma unroll
    for (int mt = 0; mt < 2; ++mt) {
#pragma unroll
        for (int n = 0; n < 8; ++n) {
            const int col = n * 16 + lr;
            const float b = bias[col];
#pragma unroll
            for (int r = 0; r < 4; ++r) {
                int row = m0 + mt * 16 + quad * 4 + r;
                if (row >= N) continue;
                C[(size_t)row * 128 + col] = packf(fmaxf(acc[mt][n][r] + b, 0.f));
            }
        }
    }
}

// ---------------- conv3: both phases packed ----------------
__global__ __launch_bounds__(256)
void conv3_mfma(const u32* __restrict__ A1, const u16* __restrict__ Wr,
                const float* __restrict__ bias,
                const u32* __restrict__ A2, const u16* __restrict__ Wo,
                u32* __restrict__ Cout, int N)
{
    const int lane = threadIdx.x & 63;
    const int m0   = (blockIdx.x * 4 + (threadIdx.x >> 6)) * 32;
    if (m0 >= N) return;
    const int lr   = lane & 15;
    const int quad = lane >> 4;

    f32x4 acc[2][8];
#pragma unroll
    for (int mt = 0; mt < 2; ++mt)
#pragma unroll
        for (int n = 0; n < 8; ++n) acc[mt][n] = (f32x4){0.f, 0.f, 0.f, 0.f};

    int r0 = m0 + lr;      if (r0 >= N) r0 = N - 1;
    int r1 = m0 + 16 + lr; if (r1 >= N) r1 = N - 1;

#pragma unroll
    for (int phase = 0; phase < 2; ++phase) {
        const u32* Ap = phase ? A2 : A1;
        const u16* Wh = phase ? Wo : Wr;
        const u16* Wl = Wh + 16384;
#pragma unroll
        for (int c = 0; c < 4; ++c) {
            const int kb = c * 32 + quad * 8;
            bf16x8 a0h, a0l, a1h, a1l;
            unpack8(Ap + (size_t)r0 * 128 + kb, a0h, a0l);
            unpack8(Ap + (size_t)r1 * 128 + kb, a1h, a1l);
#pragma unroll
            for (int n = 0; n < 8; ++n) {
                bf16x8 bh = *(const bf16x8*)(Wh + (size_t)(n * 16 + lr) * 128 + kb);
                bf16x8 bl = *(const bf16x8*)(Wl + (size_t)(n * 16 + lr) * 128 + kb);
                acc[0][n] = __builtin_amdgcn_mfma_f32_16x16x32_bf16(a0h, bh, acc[0][n], 0, 0, 0);
                acc[0][n] = __builtin_amdgcn_mfma_f32_16x16x32_bf16(a0l, bh, acc[0][n], 0, 0, 0);
                acc[0][n] = __builtin_amdgcn_mfma_f32_16x16x32_bf16(a0h, bl, acc[0][n], 0, 0, 0);
                acc[1][n] = __builtin_amdgcn_mfma_f32_16x16x32_bf16(a1h, bh, acc[1][n], 0, 0, 0);
                acc[1][n] = __builtin_amdgcn_mfma_f32_16x16x32_bf16(a1l, bh, acc[1][n], 0, 0, 0);
                acc[1][n] = __builtin_amdgcn_mfma_f32_16x16x32_bf16(a1h, bl, acc[1][n], 0, 0, 0);
            }
        }
    }

#pragma unroll
    for (int mt = 0; mt < 2; ++mt) {
#pragma unroll
        for (int n = 0; n < 8; ++n) {
            const int col = n * 16 + lr;
            const float b = bias[col];
#pragma unroll
            for (int r = 0; r < 4; ++r) {
                int row = m0 + mt * 16 + quad * 4 + r;
                if (row >= N) continue;
                Cout[(size_t)row * 128 + col] = packf(fmaxf(acc[mt][n][r] + b, 0.f));
            }
        }
    }
}

// ---------------- MFMA final lin: packed A, OC=64, fp32 out ----------------
__global__ __launch_bounds__(256)
void lin_mfma(const u32* __restrict__ A,
              const u16* __restrict__ Wh2, const float* __restrict__ bias,
              float* __restrict__ out, int N)
{
    const int lane = threadIdx.x & 63;
    const int m0   = (blockIdx.x * 4 + (threadIdx.x >> 6)) * 32;
    if (m0 >= N) return;
    const int lr   = lane & 15;
    const int quad = lane >> 4;
    const u16* Wh = Wh2;
    const u16* Wl = Wh + 16384;

    f32x4 acc[2][4];
#pragma unroll
    for (int mt = 0; mt < 2; ++mt)
#pragma unroll
        for (int n = 0; n < 4; ++n) acc[mt][n] = (f32x4){0.f, 0.f, 0.f, 0.f};

    int r0 = m0 + lr;      if (r0 >= N) r0 = N - 1;
    int r1 = m0 + 16 + lr; if (r1 >= N) r1 = N - 1;

#pragma unroll
    for (int c = 0; c < 4; ++c) {
        const int kb = c * 32 + quad * 8;
        bf16x8 a0h, a0l, a1h, a1l;
        unpack8(A + (size_t)r0 * 128 + kb, a0h, a0l);
        unpack8(A + (size_t)r1 * 128 + kb, a1h, a1l);
#pragma unroll
        for (int n = 0; n < 4; ++n) {
            bf16x8 bh = *(const bf16x8*)(Wh + (size_t)(n * 16 + lr) * 128 + kb);
            bf16x8 bl = *(const bf16x8*)(Wl + (size_t)(n * 16 + lr) * 128 + kb);
            acc[0][n] = __builtin_amdgcn_mfma_f32_16x16x32_bf16(a0h, bh, acc[0][n], 0, 0, 0);
            acc[0][n] = __builtin_amdgcn_mfma_f32_16x16x32_bf16(a0l, bh, acc[0][n], 0, 0, 0);
            acc[0][n] = __builtin_amdgcn_mfma_f32_16x16x32_bf16(a0h, bl, acc[0][n], 0, 0, 0);
            acc[1][n] = __builtin_amdgcn_mfma_f32_16x16x32_bf16(a1h, bh, acc[1][n], 0, 0, 0);
            acc[1][n] = __builtin_amdgcn_mfma_f32_16x16x32_bf16(a1l, bh, acc[1][n], 0, 0, 0);
            acc[1][n] = __builtin_amdgcn_mfma_f32_16x16x32_bf16(a1h, bl, acc[1][n], 0, 0, 0);
        }
    }

#pragma unroll
    for (int mt = 0; mt < 2; ++mt) {
#pragma unroll
        for (int n = 0; n < 4; ++n) {
            const int col = n * 16 + lr;
            const float b = bias[col];
#pragma unroll
            for (int r = 0; r < 4; ++r) {
                int row = m0 + mt * 16 + quad * 4 + r;
                if (row >= N) continue;
                out[(size_t)row * 64 + col] = acc[mt][n][r] + b;
            }
        }
    }
}

extern "C" void kernel_launch(void* const* d_in, const int* in_sizes, int n_in,
                              void* d_out, int out_size, void* d_ws, size_t ws_size,
                              hipStream_t stream)
{
    const float* x_meas  = (const float*)d_in[0];
    const float* x_dem   = (const float*)d_in[1];
    const int*   src_m   = (const int*)d_in[2];
    const int*   dst_m   = (const int*)d_in[3];
    const int*   src_b   = (const int*)d_in[4];
    const int*   dst_b   = (const int*)d_in[5];
    const float* edge_w  = (const float*)d_in[6];
    const float* W_rel1  = (const float*)d_in[7];
    const float* b_rel1  = (const float*)d_in[8];
    const float* W_root1 = (const float*)d_in[9];
    const float* W_rel2  = (const float*)d_in[10];
    const float* b_rel2  = (const float*)d_in[11];
    const float* W_root2 = (const float*)d_in[12];
    const float* W_rel3  = (const float*)d_in[13];
    const float* b_rel3  = (const float*)d_in[14];
    const float* W_root3 = (const float*)d_in[15];
    const float* W_lin   = (const float*)d_in[16];
    const float* b_lin   = (const float*)d_in[17];
    float* out = (float*)d_out;

    const int NM = 50000, ND = 20000, E = 600000;

    char* p = (char*)d_ws;
    auto alloc = [&](size_t bytes) { char* r = p; p += (bytes + 511) & ~(size_t)511; return r; };
    int*   deg_m   = (int*)alloc((size_t)NM * 4);
    int*   deg_b   = (int*)alloc((size_t)ND * 4);
    int*   rp_m    = (int*)alloc((size_t)NM * 4);
    int*   rp_b    = (int*)alloc((size_t)ND * 4);
    int*   srcs_m  = (int*)alloc((size_t)E * 4);
    int2*  edges_b = (int2*)alloc((size_t)E * 8);
    u32*   agg1    = (u32*)alloc((size_t)NM * 128 * 4);
    u32*   agg2    = (u32*)alloc((size_t)ND * 128 * 4);
    u32*   movie   = (u32*)alloc((size_t)NM * 128 * 4);
    u32*   t2      = (u32*)alloc((size_t)ND * 128 * 4);
    u16*   wbuf    = (u16*)alloc(7 * 32768 * 2);
    u32* agg3 = agg1;   // agg1 dead after conv1
    u32* t3   = agg2;   // agg2 dead after conv2

    u16* w1r = wbuf + 0 * 32768;
    u16* w1o = wbuf + 1 * 32768;
    u16* w2r = wbuf + 2 * 32768;
    u16* w2o = wbuf + 3 * 32768;
    u16* w3r = wbuf + 4 * 32768;
    u16* w3o = wbuf + 5 * 32768;
    u16* wl  = wbuf + 6 * 32768;

    size_t deg_span = (size_t)((char*)deg_b - (char*)deg_m) + (size_t)ND * 4;
    hipMemsetAsync(deg_m, 0, deg_span, stream);

    const int eb2 = (2 * E + 255) / 256;
    hist_kernel<<<eb2, 256, 0, stream>>>(dst_m, dst_b, deg_m, deg_b, E);
    scan2_kernel<<<2, 1024, 0, stream>>>(deg_m, rp_m, NM, deg_b, rp_b, ND);
    fill_kernel<<<eb2, 256, 0, stream>>>(src_m, dst_m, src_b, dst_b, edge_w,
                                         rp_m, rp_b, srcs_m, edges_b, E);

    wsplit_all<<<448, 256, 0, stream>>>(W_rel1, W_root1, W_rel2, W_root2,
                                        W_rel3, W_root3, W_lin, wbuf);

    // merged gather1 (m-graph, unweighted) + gather2 (b-graph, weighted)
    gather12<<<(NM + ND + 7) / 8, 256, 0, stream>>>(x_meas, nullptr, srcs_m, edges_b,
                                                    rp_m, rp_b, agg1, agg2, NM, ND);

    // merged conv1+conv2
    const int cb1 = (NM + 127) / 128;   // 391
    const int cb2 = (ND + 127) / 128;   // 157
    conv12_mfma<<<cb1 + cb2, 256, 0, stream>>>(agg1, w1r, b_rel1, x_meas, w1o, movie, NM, cb1,
                                               agg2, w2r, b_rel2, x_dem,  w2o, t2,    ND);

    // agg3 = sum_e w * movie[src_b]
    gather3_kernel<<<(ND + 7) / 8, 256, 0, stream>>>(movie, edges_b, rp_b, agg3, ND);

    // conv3: t3 = relu(agg3@W_rel3 + b3 + t2@W_root3)
    conv3_mfma<<<cb2, 256, 0, stream>>>(agg3, w3r, b_rel3, t2, w3o, t3, ND);

    // out = t3@W_lin + b_lin
    lin_mfma<<<cb2, 256, 0, stream>>>(t3, wl, b_lin, out, ND);
}

// Round 8
// 433.678 us; speedup vs baseline: 15.1695x; 1.2146x over previous
//
#include <hip/hip_runtime.h>

// Round 8: (a) bf16 gather source for gather12 (halves gathered bytes; root
// terms stay fp32), (b) atomic-free fill via hist-returned ranks (kills 1.2M
// cursor atomic write-throughs), exclusive rowptr + sentinel. ws still 79.9 MB
// via aliasing (rank->agg1, xm_bf->movie).

typedef unsigned short u16;
typedef unsigned int u32;
typedef __attribute__((ext_vector_type(8))) short bf16x8;
typedef __attribute__((ext_vector_type(4))) float f32x4;

__device__ __forceinline__ float bf2f(u16 h) {
    union { u32 u; float f; } v; v.u = ((u32)h) << 16; return v.f;
}
__device__ __forceinline__ u16 f2bf(float f) {
    union { float f; u32 u; } v; v.f = f;
    u32 lsb = (v.u >> 16) & 1u;
    v.u += 0x7fffu + lsb;           // RNE
    return (u16)(v.u >> 16);
}
__device__ __forceinline__ void split2(float v, u16& h, u16& l) {
    u16 hb = f2bf(v);
    h = hb; l = f2bf(v - bf2f(hb));
}
__device__ __forceinline__ u32 packf(float v) {
    u32 b = __float_as_uint(v);
    float hf = __uint_as_float(b & 0xffff0000u);
    u16 l = f2bf(v - hf);
    return (b >> 16) | ((u32)l << 16);
}
__device__ __forceinline__ float unpackf(u32 w) {
    return __uint_as_float(w << 16) + __uint_as_float(w & 0xffff0000u);
}
__device__ __forceinline__ void split8(const float* __restrict__ p, bf16x8& h, bf16x8& l) {
    float4 u = *(const float4*)p;
    float4 w = *(const float4*)(p + 4);
    float a[8] = {u.x, u.y, u.z, u.w, w.x, w.y, w.z, w.w};
#pragma unroll
    for (int j = 0; j < 8; ++j) {
        u16 hh, ll; split2(a[j], hh, ll);
        h[j] = (short)hh; l[j] = (short)ll;
    }
}
__device__ __forceinline__ void unpack8(const u32* __restrict__ p, bf16x8& h, bf16x8& l) {
    uint4 a = *(const uint4*)p;
    uint4 b = *(const uint4*)(p + 4);
    h[0] = (short)a.x; l[0] = (short)(a.x >> 16);
    h[1] = (short)a.y; l[1] = (short)(a.y >> 16);
    h[2] = (short)a.z; l[2] = (short)(a.z >> 16);
    h[3] = (short)a.w; l[3] = (short)(a.w >> 16);
    h[4] = (short)b.x; l[4] = (short)(b.x >> 16);
    h[5] = (short)b.y; l[5] = (short)(b.y >> 16);
    h[6] = (short)b.z; l[6] = (short)(b.z >> 16);
    h[7] = (short)b.w; l[7] = (short)(b.w >> 16);
}

// ---------------- x_meas -> bf16 copy (gather source) ----------------
__global__ __launch_bounds__(256)
void tobf16_kernel(const float* __restrict__ in, u16* __restrict__ out, int n8)
{
    int i = blockIdx.x * 256 + threadIdx.x;
    if (i >= n8) return;
    float4 a = ((const float4*)in)[2 * i];
    float4 b = ((const float4*)in)[2 * i + 1];
    ushort4 h0; h0.x = f2bf(a.x); h0.y = f2bf(a.y); h0.z = f2bf(a.z); h0.w = f2bf(a.w);
    ushort4 h1; h1.x = f2bf(b.x); h1.y = f2bf(b.y); h1.z = f2bf(b.z); h1.w = f2bf(b.w);
    ((ushort4*)out)[2 * i]     = h0;
    ((ushort4*)out)[2 * i + 1] = h1;
}

// ---------------- hist: degree count + per-edge rank ----------------
__global__ __launch_bounds__(256)
void hist_kernel(const int* __restrict__ dst_m, const int* __restrict__ dst_b,
                 int* __restrict__ deg_m, int* __restrict__ deg_b,
                 int* __restrict__ rank_m, int* __restrict__ rank_b, int E)
{
    int t = blockIdx.x * 256 + threadIdx.x;
    if (t < E) {
        rank_m[t] = atomicAdd(&deg_m[dst_m[t]], 1);
    } else if (t < 2 * E) {
        int e = t - E;
        rank_b[e] = atomicAdd(&deg_b[dst_b[e]], 1);
    }
}

__device__ __forceinline__ int wave_incl_scan(int v, int lane) {
#pragma unroll
    for (int off = 1; off < 64; off <<= 1) {
        int t = __shfl_up(v, off, 64);
        if (lane >= off) v += t;
    }
    return v;
}

// exclusive scan + sentinel rp[n] = total
__global__ __launch_bounds__(1024)
void scan2_kernel(const int* __restrict__ degA, int* __restrict__ rpA, int nA,
                  const int* __restrict__ degB, int* __restrict__ rpB, int nB)
{
    const int* deg = blockIdx.x ? degB : degA;
    int* rp = blockIdx.x ? rpB : rpA;
    int n = blockIdx.x ? nB : nA;

    __shared__ int wsum[16];
    __shared__ int carry;
    const int tid = threadIdx.x, lane = tid & 63, wid = tid >> 6;
    if (tid == 0) carry = 0;
    __syncthreads();

    for (int base = 0; base < n; base += 1024) {
        int idx = base + tid;
        int v = (idx < n) ? deg[idx] : 0;
        int incl = wave_incl_scan(v, lane);
        if (lane == 63) wsum[wid] = incl;
        __syncthreads();
        if (wid == 0) {
            int s = (lane < 16) ? wsum[lane] : 0;
            int si = wave_incl_scan(s, lane);
            if (lane < 16) wsum[lane] = si - s;
        }
        __syncthreads();
        if (idx < n) rp[idx] = carry + wsum[wid] + incl - v;
        __syncthreads();
        if (tid == 1023) carry += wsum[15] + incl;
        __syncthreads();
    }
    if (tid == 0) rp[n] = carry;   // sentinel: total edge count
}

// ---------------- atomic-free fill (pos = rp[dst] + rank) ----------------
__global__ __launch_bounds__(256)
void fill_kernel(const int* __restrict__ src_m, const int* __restrict__ dst_m,
                 const int* __restrict__ src_b, const int* __restrict__ dst_b,
                 const float* __restrict__ edge_w,
                 const int* __restrict__ rp_m, const int* __restrict__ rp_b,
                 const int* __restrict__ rank_m, const int* __restrict__ rank_b,
                 int* __restrict__ srcs_m, int2* __restrict__ edges_b, int E)
{
    int t = blockIdx.x * 256 + threadIdx.x;
    if (t < E) {
        int pos = rp_m[dst_m[t]] + rank_m[t];
        srcs_m[pos] = src_m[t];
    } else if (t < 2 * E) {
        int e = t - E;
        int pos = rp_b[dst_b[e]] + rank_b[e];
        float x = edge_w[e];
        int2 pk;
        pk.x = src_b[e];
        pk.y = __float_as_int(1.0f / (1.0f + __expf(-x)));
        edges_b[pos] = pk;
    }
}

// ---------------- merged gather1+2 from bf16 rows -> packed agg ----------------
// One node per 32-lane half; lane covers 4 cols (ushort4 = 8B); unroll-4.
__global__ __launch_bounds__(256)
void gather12(const u16* __restrict__ Xb,
              const int* __restrict__ srcs_m, const int2* __restrict__ edges_b,
              const int* __restrict__ rp_m, const int* __restrict__ rp_b,
              u32* __restrict__ agg1, u32* __restrict__ agg2, int NM, int ND)
{
    const int h  = blockIdx.x * 8 + (threadIdx.x >> 5);
    const int cl = threadIdx.x & 31;
    float4 acc = make_float4(0.f, 0.f, 0.f, 0.f);

    if (h < NM) {
        int i   = rp_m[h];
        int end = rp_m[h + 1];
        for (; i + 4 <= end; i += 4) {
            int s0 = srcs_m[i], s1 = srcs_m[i + 1], s2 = srcs_m[i + 2], s3 = srcs_m[i + 3];
            ushort4 v0 = *(const ushort4*)(Xb + (size_t)s0 * 128 + cl * 4);
            ushort4 v1 = *(const ushort4*)(Xb + (size_t)s1 * 128 + cl * 4);
            ushort4 v2 = *(const ushort4*)(Xb + (size_t)s2 * 128 + cl * 4);
            ushort4 v3 = *(const ushort4*)(Xb + (size_t)s3 * 128 + cl * 4);
            acc.x += (bf2f(v0.x) + bf2f(v1.x)) + (bf2f(v2.x) + bf2f(v3.x));
            acc.y += (bf2f(v0.y) + bf2f(v1.y)) + (bf2f(v2.y) + bf2f(v3.y));
            acc.z += (bf2f(v0.z) + bf2f(v1.z)) + (bf2f(v2.z) + bf2f(v3.z));
            acc.w += (bf2f(v0.w) + bf2f(v1.w)) + (bf2f(v2.w) + bf2f(v3.w));
        }
        for (; i < end; ++i) {
            int s = srcs_m[i];
            ushort4 v = *(const ushort4*)(Xb + (size_t)s * 128 + cl * 4);
            acc.x += bf2f(v.x); acc.y += bf2f(v.y);
            acc.z += bf2f(v.z); acc.w += bf2f(v.w);
        }
        uint4 st;
        st.x = packf(acc.x); st.y = packf(acc.y);
        st.z = packf(acc.z); st.w = packf(acc.w);
        *(uint4*)(agg1 + (size_t)h * 128 + cl * 4) = st;
    } else if (h < NM + ND) {
        int node = h - NM;
        int i   = rp_b[node];
        int end = rp_b[node + 1];
        for (; i + 4 <= end; i += 4) {
            int2 p0 = edges_b[i],     p1 = edges_b[i + 1];
            int2 p2 = edges_b[i + 2], p3 = edges_b[i + 3];
            float w0 = __int_as_float(p0.y), w1 = __int_as_float(p1.y);
            float w2 = __int_as_float(p2.y), w3 = __int_as_float(p3.y);
            ushort4 v0 = *(const ushort4*)(Xb + (size_t)p0.x * 128 + cl * 4);
            ushort4 v1 = *(const ushort4*)(Xb + (size_t)p1.x * 128 + cl * 4);
            ushort4 v2 = *(const ushort4*)(Xb + (size_t)p2.x * 128 + cl * 4);
            ushort4 v3 = *(const ushort4*)(Xb + (size_t)p3.x * 128 + cl * 4);
            acc.x = fmaf(w0, bf2f(v0.x), acc.x); acc.y = fmaf(w0, bf2f(v0.y), acc.y);
            acc.z = fmaf(w0, bf2f(v0.z), acc.z); acc.w = fmaf(w0, bf2f(v0.w), acc.w);
            acc.x = fmaf(w1, bf2f(v1.x), acc.x); acc.y = fmaf(w1, bf2f(v1.y), acc.y);
            acc.z = fmaf(w1, bf2f(v1.z), acc.z); acc.w = fmaf(w1, bf2f(v1.w), acc.w);
            acc.x = fmaf(w2, bf2f(v2.x), acc.x); acc.y = fmaf(w2, bf2f(v2.y), acc.y);
            acc.z = fmaf(w2, bf2f(v2.z), acc.z); acc.w = fmaf(w2, bf2f(v2.w), acc.w);
            acc.x = fmaf(w3, bf2f(v3.x), acc.x); acc.y = fmaf(w3, bf2f(v3.y), acc.y);
            acc.z = fmaf(w3, bf2f(v3.z), acc.z); acc.w = fmaf(w3, bf2f(v3.w), acc.w);
        }
        for (; i < end; ++i) {
            int2 pk = edges_b[i];
            float w = __int_as_float(pk.y);
            ushort4 v = *(const ushort4*)(Xb + (size_t)pk.x * 128 + cl * 4);
            acc.x = fmaf(w, bf2f(v.x), acc.x); acc.y = fmaf(w, bf2f(v.y), acc.y);
            acc.z = fmaf(w, bf2f(v.z), acc.z); acc.w = fmaf(w, bf2f(v.w), acc.w);
        }
        uint4 st;
        st.x = packf(acc.x); st.y = packf(acc.y);
        st.z = packf(acc.z); st.w = packf(acc.w);
        *(uint4*)(agg2 + (size_t)node * 128 + cl * 4) = st;
    }
}

// ---------------- gather3: packed movie -> packed agg3, weighted ----------
__global__ __launch_bounds__(256)
void gather3_kernel(const u32* __restrict__ Mv, const int2* __restrict__ edges_b,
                    const int* __restrict__ rp_b, u32* __restrict__ agg3, int ND)
{
    const int node = blockIdx.x * 8 + (threadIdx.x >> 5);
    if (node >= ND) return;
    const int cl = threadIdx.x & 31;
    int i   = rp_b[node];
    int end = rp_b[node + 1];

    float4 acc = make_float4(0.f, 0.f, 0.f, 0.f);
    for (; i + 4 <= end; i += 4) {
        int2 p0 = edges_b[i],     p1 = edges_b[i + 1];
        int2 p2 = edges_b[i + 2], p3 = edges_b[i + 3];
        float w0 = __int_as_float(p0.y), w1 = __int_as_float(p1.y);
        float w2 = __int_as_float(p2.y), w3 = __int_as_float(p3.y);
        uint4 a0 = *(const uint4*)(Mv + (size_t)p0.x * 128 + cl * 4);
        uint4 a1 = *(const uint4*)(Mv + (size_t)p1.x * 128 + cl * 4);
        uint4 a2 = *(const uint4*)(Mv + (size_t)p2.x * 128 + cl * 4);
        uint4 a3 = *(const uint4*)(Mv + (size_t)p3.x * 128 + cl * 4);
        acc.x = fmaf(w0, unpackf(a0.x), acc.x); acc.y = fmaf(w0, unpackf(a0.y), acc.y);
        acc.z = fmaf(w0, unpackf(a0.z), acc.z); acc.w = fmaf(w0, unpackf(a0.w), acc.w);
        acc.x = fmaf(w1, unpackf(a1.x), acc.x); acc.y = fmaf(w1, unpackf(a1.y), acc.y);
        acc.z = fmaf(w1, unpackf(a1.z), acc.z); acc.w = fmaf(w1, unpackf(a1.w), acc.w);
        acc.x = fmaf(w2, unpackf(a2.x), acc.x); acc.y = fmaf(w2, unpackf(a2.y), acc.y);
        acc.z = fmaf(w2, unpackf(a2.z), acc.z); acc.w = fmaf(w2, unpackf(a2.w), acc.w);
        acc.x = fmaf(w3, unpackf(a3.x), acc.x); acc.y = fmaf(w3, unpackf(a3.y), acc.y);
        acc.z = fmaf(w3, unpackf(a3.z), acc.z); acc.w = fmaf(w3, unpackf(a3.w), acc.w);
    }
    for (; i < end; ++i) {
        int2 pk = edges_b[i];
        float w = __int_as_float(pk.y);
        uint4 a = *(const uint4*)(Mv + (size_t)pk.x * 128 + cl * 4);
        acc.x = fmaf(w, unpackf(a.x), acc.x); acc.y = fmaf(w, unpackf(a.y), acc.y);
        acc.z = fmaf(w, unpackf(a.z), acc.z); acc.w = fmaf(w, unpackf(a.w), acc.w);
    }
    uint4 st;
    st.x = packf(acc.x); st.y = packf(acc.y);
    st.z = packf(acc.z); st.w = packf(acc.w);
    *(uint4*)(agg3 + (size_t)node * 128 + cl * 4) = st;
}

// ---------------- fused weight transpose+split ----------------
__global__ __launch_bounds__(256)
void wsplit_all(const float* __restrict__ w0, const float* __restrict__ w1,
                const float* __restrict__ w2, const float* __restrict__ w3,
                const float* __restrict__ w4, const float* __restrict__ w5,
                const float* __restrict__ w6, u16* __restrict__ wbuf)
{
    const int widx = blockIdx.x >> 6;
    const int off  = ((blockIdx.x & 63) << 8) + threadIdx.x;
    const int OC   = (widx == 6) ? 64 : 128;
    if (off >= OC * 128) return;
    const float* W;
    switch (widx) {
        case 0: W = w0; break; case 1: W = w1; break; case 2: W = w2; break;
        case 3: W = w3; break; case 4: W = w4; break; case 5: W = w5; break;
        default: W = w6;
    }
    int k = off / OC, n = off % OC;
    u16 h, l;
    split2(W[off], h, l);
    u16* slot = wbuf + widx * 32768;
    slot[n * 128 + k]         = h;
    slot[16384 + n * 128 + k] = l;
}

// ---------------- merged MFMA conv1+conv2 (r7-proven) ----------------
__global__ __launch_bounds__(256)
void conv12_mfma(const u32* __restrict__ agg1, const u16* __restrict__ w1r,
                 const float* __restrict__ b1, const float* __restrict__ x1,
                 const u16* __restrict__ w1o, u32* __restrict__ C1, int N1, int cb1,
                 const u32* __restrict__ agg2, const u16* __restrict__ w2r,
                 const float* __restrict__ b2, const float* __restrict__ x2,
                 const u16* __restrict__ w2o, u32* __restrict__ C2, int N2)
{
    const u32* Ap; const u16 *Wr, *Wo; const float *bias, *Xf; u32* C; int N, base;
    if ((int)blockIdx.x < cb1) {
        Ap = agg1; Wr = w1r; Wo = w1o; bias = b1; Xf = x1; C = C1; N = N1; base = blockIdx.x;
    } else {
        Ap = agg2; Wr = w2r; Wo = w2o; bias = b2; Xf = x2; C = C2; N = N2; base = blockIdx.x - cb1;
    }
    const int lane = threadIdx.x & 63;
    const int m0   = (base * 4 + (threadIdx.x >> 6)) * 32;
    if (m0 >= N) return;
    const int lr   = lane & 15;
    const int quad = lane >> 4;

    f32x4 acc[2][8];
#pragma unroll
    for (int mt = 0; mt < 2; ++mt)
#pragma unroll
        for (int n = 0; n < 8; ++n) acc[mt][n] = (f32x4){0.f, 0.f, 0.f, 0.f};

    int r0 = m0 + lr;      if (r0 >= N) r0 = N - 1;
    int r1 = m0 + 16 + lr; if (r1 >= N) r1 = N - 1;

#pragma unroll
    for (int phase = 0; phase < 2; ++phase) {
        const u16* Wh = phase ? Wo : Wr;
        const u16* Wl = Wh + 16384;
#pragma unroll
        for (int c = 0; c < 4; ++c) {
            const int kb = c * 32 + quad * 8;
            bf16x8 a0h, a0l, a1h, a1l;
            if (phase == 0) {
                unpack8(Ap + (size_t)r0 * 128 + kb, a0h, a0l);
                unpack8(Ap + (size_t)r1 * 128 + kb, a1h, a1l);
            } else {
                split8(Xf + (size_t)r0 * 128 + kb, a0h, a0l);
                split8(Xf + (size_t)r1 * 128 + kb, a1h, a1l);
            }
#pragma unroll
            for (int n = 0; n < 8; ++n) {
                bf16x8 bh = *(const bf16x8*)(Wh + (size_t)(n * 16 + lr) * 128 + kb);
                bf16x8 bl = *(const bf16x8*)(Wl + (size_t)(n * 16 + lr) * 128 + kb);
                acc[0][n] = __builtin_amdgcn_mfma_f32_16x16x32_bf16(a0h, bh, acc[0][n], 0, 0, 0);
                acc[0][n] = __builtin_amdgcn_mfma_f32_16x16x32_bf16(a0l, bh, acc[0][n], 0, 0, 0);
                acc[0][n] = __builtin_amdgcn_mfma_f32_16x16x32_bf16(a0h, bl, acc[0][n], 0, 0, 0);
                acc[1][n] = __builtin_amdgcn_mfma_f32_16x16x32_bf16(a1h, bh, acc[1][n], 0, 0, 0);
                acc[1][n] = __builtin_amdgcn_mfma_f32_16x16x32_bf16(a1l, bh, acc[1][n], 0, 0, 0);
                acc[1][n] = __builtin_amdgcn_mfma_f32_16x16x32_bf16(a1h, bl, acc[1][n], 0, 0, 0);
            }
        }
    }

#pragma unroll
    for (int mt = 0; mt < 2; ++mt) {
#pragma unroll
        for (int n = 0; n < 8; ++n) {
            const int col = n * 16 + lr;
            const float b = bias[col];
#pragma unroll
            for (int r = 0; r < 4; ++r) {
                int row = m0 + mt * 16 + quad * 4 + r;
                if (row >= N) continue;
                C[(size_t)row * 128 + col] = packf(fmaxf(acc[mt][n][r] + b, 0.f));
            }
        }
    }
}

// ---------------- conv3: both phases packed (r7-proven) ----------------
__global__ __launch_bounds__(256)
void conv3_mfma(const u32* __restrict__ A1, const u16* __restrict__ Wr,
                const float* __restrict__ bias,
                const u32* __restrict__ A2, const u16* __restrict__ Wo,
                u32* __restrict__ Cout, int N)
{
    const int lane = threadIdx.x & 63;
    const int m0   = (blockIdx.x * 4 + (threadIdx.x >> 6)) * 32;
    if (m0 >= N) return;
    const int lr   = lane & 15;
    const int quad = lane >> 4;

    f32x4 acc[2][8];
#pragma unroll
    for (int mt = 0; mt < 2; ++mt)
#pragma unroll
        for (int n = 0; n < 8; ++n) acc[mt][n] = (f32x4){0.f, 0.f, 0.f, 0.f};

    int r0 = m0 + lr;      if (r0 >= N) r0 = N - 1;
    int r1 = m0 + 16 + lr; if (r1 >= N) r1 = N - 1;

#pragma unroll
    for (int phase = 0; phase < 2; ++phase) {
        const u32* Ap = phase ? A2 : A1;
        const u16* Wh = phase ? Wo : Wr;
        const u16* Wl = Wh + 16384;
#pragma unroll
        for (int c = 0; c < 4; ++c) {
            const int kb = c * 32 + quad * 8;
            bf16x8 a0h, a0l, a1h, a1l;
            unpack8(Ap + (size_t)r0 * 128 + kb, a0h, a0l);
            unpack8(Ap + (size_t)r1 * 128 + kb, a1h, a1l);
#pragma unroll
            for (int n = 0; n < 8; ++n) {
                bf16x8 bh = *(const bf16x8*)(Wh + (size_t)(n * 16 + lr) * 128 + kb);
                bf16x8 bl = *(const bf16x8*)(Wl + (size_t)(n * 16 + lr) * 128 + kb);
                acc[0][n] = __builtin_amdgcn_mfma_f32_16x16x32_bf16(a0h, bh, acc[0][n], 0, 0, 0);
                acc[0][n] = __builtin_amdgcn_mfma_f32_16x16x32_bf16(a0l, bh, acc[0][n], 0, 0, 0);
                acc[0][n] = __builtin_amdgcn_mfma_f32_16x16x32_bf16(a0h, bl, acc[0][n], 0, 0, 0);
                acc[1][n] = __builtin_amdgcn_mfma_f32_16x16x32_bf16(a1h, bh, acc[1][n], 0, 0, 0);
                acc[1][n] = __builtin_amdgcn_mfma_f32_16x16x32_bf16(a1l, bh, acc[1][n], 0, 0, 0);
                acc[1][n] = __builtin_amdgcn_mfma_f32_16x16x32_bf16(a1h, bl, acc[1][n], 0, 0, 0);
            }
        }
    }

#pragma unroll
    for (int mt = 0; mt < 2; ++mt) {
#pragma unroll
        for (int n = 0; n < 8; ++n) {
            const int col = n * 16 + lr;
            const float b = bias[col];
#pragma unroll
            for (int r = 0; r < 4; ++r) {
                int row = m0 + mt * 16 + quad * 4 + r;
                if (row >= N) continue;
                Cout[(size_t)row * 128 + col] = packf(fmaxf(acc[mt][n][r] + b, 0.f));
            }
        }
    }
}

// ---------------- MFMA final lin (r7-proven) ----------------
__global__ __launch_bounds__(256)
void lin_mfma(const u32* __restrict__ A,
              const u16* __restrict__ Wh2, const float* __restrict__ bias,
              float* __restrict__ out, int N)
{
    const int lane = threadIdx.x & 63;
    const int m0   = (blockIdx.x * 4 + (threadIdx.x >> 6)) * 32;
    if (m0 >= N) return;
    const int lr   = lane & 15;
    const int quad = lane >> 4;
    const u16* Wh = Wh2;
    const u16* Wl = Wh + 16384;

    f32x4 acc[2][4];
#pragma unroll
    for (int mt = 0; mt < 2; ++mt)
#pragma unroll
        for (int n = 0; n < 4; ++n) acc[mt][n] = (f32x4){0.f, 0.f, 0.f, 0.f};

    int r0 = m0 + lr;      if (r0 >= N) r0 = N - 1;
    int r1 = m0 + 16 + lr; if (r1 >= N) r1 = N - 1;

#pragma unroll
    for (int c = 0; c < 4; ++c) {
        const int kb = c * 32 + quad * 8;
        bf16x8 a0h, a0l, a1h, a1l;
        unpack8(A + (size_t)r0 * 128 + kb, a0h, a0l);
        unpack8(A + (size_t)r1 * 128 + kb, a1h, a1l);
#pragma unroll
        for (int n = 0; n < 4; ++n) {
            bf16x8 bh = *(const bf16x8*)(Wh + (size_t)(n * 16 + lr) * 128 + kb);
            bf16x8 bl = *(const bf16x8*)(Wl + (size_t)(n * 16 + lr) * 128 + kb);
            acc[0][n] = __builtin_amdgcn_mfma_f32_16x16x32_bf16(a0h, bh, acc[0][n], 0, 0, 0);
            acc[0][n] = __builtin_amdgcn_mfma_f32_16x16x32_bf16(a0l, bh, acc[0][n], 0, 0, 0);
            acc[0][n] = __builtin_amdgcn_mfma_f32_16x16x32_bf16(a0h, bl, acc[0][n], 0, 0, 0);
            acc[1][n] = __builtin_amdgcn_mfma_f32_16x16x32_bf16(a1h, bh, acc[1][n], 0, 0, 0);
            acc[1][n] = __builtin_amdgcn_mfma_f32_16x16x32_bf16(a1l, bh, acc[1][n], 0, 0, 0);
            acc[1][n] = __builtin_amdgcn_mfma_f32_16x16x32_bf16(a1h, bl, acc[1][n], 0, 0, 0);
        }
    }

#pragma unroll
    for (int mt = 0; mt < 2; ++mt) {
#pragma unroll
        for (int n = 0; n < 4; ++n) {
            const int col = n * 16 + lr;
            const float b = bias[col];
#pragma unroll
            for (int r = 0; r < 4; ++r) {
                int row = m0 + mt * 16 + quad * 4 + r;
                if (row >= N) continue;
                out[(size_t)row * 64 + col] = acc[mt][n][r] + b;
            }
        }
    }
}

extern "C" void kernel_launch(void* const* d_in, const int* in_sizes, int n_in,
                              void* d_out, int out_size, void* d_ws, size_t ws_size,
                              hipStream_t stream)
{
    const float* x_meas  = (const float*)d_in[0];
    const float* x_dem   = (const float*)d_in[1];
    const int*   src_m   = (const int*)d_in[2];
    const int*   dst_m   = (const int*)d_in[3];
    const int*   src_b   = (const int*)d_in[4];
    const int*   dst_b   = (const int*)d_in[5];
    const float* edge_w  = (const float*)d_in[6];
    const float* W_rel1  = (const float*)d_in[7];
    const float* b_rel1  = (const float*)d_in[8];
    const float* W_root1 = (const float*)d_in[9];
    const float* W_rel2  = (const float*)d_in[10];
    const float* b_rel2  = (const float*)d_in[11];
    const float* W_root2 = (const float*)d_in[12];
    const float* W_rel3  = (const float*)d_in[13];
    const float* b_rel3  = (const float*)d_in[14];
    const float* W_root3 = (const float*)d_in[15];
    const float* W_lin   = (const float*)d_in[16];
    const float* b_lin   = (const float*)d_in[17];
    float* out = (float*)d_out;

    const int NM = 50000, ND = 20000, E = 600000;

    char* p = (char*)d_ws;
    auto alloc = [&](size_t bytes) { char* r = p; p += (bytes + 511) & ~(size_t)511; return r; };
    int*   deg_m   = (int*)alloc((size_t)NM * 4);
    int*   deg_b   = (int*)alloc((size_t)ND * 4);
    int*   rp_m    = (int*)alloc((size_t)(NM + 1) * 4);
    int*   rp_b    = (int*)alloc((size_t)(ND + 1) * 4);
    int*   srcs_m  = (int*)alloc((size_t)E * 4);
    int2*  edges_b = (int2*)alloc((size_t)E * 8);
    u32*   agg1    = (u32*)alloc((size_t)NM * 128 * 4);   // 25.6 MB
    u32*   agg2    = (u32*)alloc((size_t)ND * 128 * 4);   // 10.24 MB
    u32*   movie   = (u32*)alloc((size_t)NM * 128 * 4);   // 25.6 MB
    u32*   t2      = (u32*)alloc((size_t)ND * 128 * 4);   // 10.24 MB
    u16*   wbuf    = (u16*)alloc(7 * 32768 * 2);          // 0.44 MB
    // aliases (lifetime-checked): ranks die before gather12 writes agg1;
    // xm_bf dies before conv12 writes movie.
    int* rank_m = (int*)agg1;
    int* rank_b = rank_m + E;
    u16* xm_bf  = (u16*)movie;
    u32* agg3 = agg1;   // agg1 dead after conv12
    u32* t3   = agg2;   // agg2 dead after conv3's read? no — after conv3 consumes agg3/t2; t3 written by conv3
    u16* w1r = wbuf + 0 * 32768;
    u16* w1o = wbuf + 1 * 32768;
    u16* w2r = wbuf + 2 * 32768;
    u16* w2o = wbuf + 3 * 32768;
    u16* w3r = wbuf + 4 * 32768;
    u16* w3o = wbuf + 5 * 32768;
    u16* wl  = wbuf + 6 * 32768;

    size_t deg_span = (size_t)((char*)deg_b - (char*)deg_m) + (size_t)ND * 4;
    hipMemsetAsync(deg_m, 0, deg_span, stream);

    // bf16 gather source (independent of CSR build)
    tobf16_kernel<<<(NM * 16 + 255) / 256, 256, 0, stream>>>(x_meas, xm_bf, NM * 16);

    const int eb2 = (2 * E + 255) / 256;
    hist_kernel<<<eb2, 256, 0, stream>>>(dst_m, dst_b, deg_m, deg_b, rank_m, rank_b, E);
    scan2_kernel<<<2, 1024, 0, stream>>>(deg_m, rp_m, NM, deg_b, rp_b, ND);
    fill_kernel<<<eb2, 256, 0, stream>>>(src_m, dst_m, src_b, dst_b, edge_w,
                                         rp_m, rp_b, rank_m, rank_b, srcs_m, edges_b, E);

    wsplit_all<<<448, 256, 0, stream>>>(W_rel1, W_root1, W_rel2, W_root2,
                                        W_rel3, W_root3, W_lin, wbuf);

    // merged gather1 (m-graph) + gather2 (b-graph) from bf16 rows
    gather12<<<(NM + ND + 7) / 8, 256, 0, stream>>>(xm_bf, srcs_m, edges_b,
                                                    rp_m, rp_b, agg1, agg2, NM, ND);

    // merged conv1+conv2 (roots x_meas/x_dem read fp32)
    const int cb1 = (NM + 127) / 128;
    const int cb2 = (ND + 127) / 128;
    conv12_mfma<<<cb1 + cb2, 256, 0, stream>>>(agg1, w1r, b_rel1, x_meas, w1o, movie, NM, cb1,
                                               agg2, w2r, b_rel2, x_dem,  w2o, t2,    ND);

    // agg3 = sum_e w * movie[src_b]  (full pf32 precision)
    gather3_kernel<<<(ND + 7) / 8, 256, 0, stream>>>(movie, edges_b, rp_b, agg3, ND);

    // conv3: t3 = relu(agg3@W_rel3 + b3 + t2@W_root3)
    conv3_mfma<<<cb2, 256, 0, stream>>>(agg3, w3r, b_rel3, t2, w3o, t3, ND);

    // out = t3@W_lin + b_lin
    lin_mfma<<<cb2, 256, 0, stream>>>(t3, wl, b_lin, out, ND);
}

// Round 10
// 380.026 us; speedup vs baseline: 17.3111x; 1.1412x over previous
//
#include <hip/hip_runtime.h>

// Round 10: round-9 structure with the lin_mfma LDS staging bug fixed
// (copied 512 uint4 = half of W_lin's 1024-uint4 fragment slot; k=64..127
// read 0xAA poison -> absmax 118.75). Conv kernels' bounds were correct.

typedef unsigned short u16;
typedef unsigned int u32;
typedef __attribute__((ext_vector_type(8))) short bf16x8;
typedef __attribute__((ext_vector_type(4))) float f32x4;

__device__ __forceinline__ float bf2f(u16 h) {
    union { u32 u; float f; } v; v.u = ((u32)h) << 16; return v.f;
}
__device__ __forceinline__ u16 f2bf(float f) {
    union { float f; u32 u; } v; v.f = f;
    u32 lsb = (v.u >> 16) & 1u;
    v.u += 0x7fffu + lsb;           // RNE
    return (u16)(v.u >> 16);
}
__device__ __forceinline__ u32 packf(float v) {
    u32 b = __float_as_uint(v);
    float hf = __uint_as_float(b & 0xffff0000u);
    u16 l = f2bf(v - hf);
    return (b >> 16) | ((u32)l << 16);
}
__device__ __forceinline__ float unpackf(u32 w) {
    return __uint_as_float(w << 16) + __uint_as_float(w & 0xffff0000u);
}
__device__ __forceinline__ void split2(float v, u16& h, u16& l) {
    u16 hb = f2bf(v);
    h = hb; l = f2bf(v - bf2f(hb));
}
__device__ __forceinline__ void split8(const float* __restrict__ p, bf16x8& h, bf16x8& l) {
    float4 u = *(const float4*)p;
    float4 w = *(const float4*)(p + 4);
    float a[8] = {u.x, u.y, u.z, u.w, w.x, w.y, w.z, w.w};
#pragma unroll
    for (int j = 0; j < 8; ++j) {
        u16 hh, ll; split2(a[j], hh, ll);
        h[j] = (short)hh; l[j] = (short)ll;
    }
}
__device__ __forceinline__ void unpack8(const u32* __restrict__ p, bf16x8& h, bf16x8& l) {
    uint4 a = *(const uint4*)p;
    uint4 b = *(const uint4*)(p + 4);
    h[0] = (short)a.x; l[0] = (short)(a.x >> 16);
    h[1] = (short)a.y; l[1] = (short)(a.y >> 16);
    h[2] = (short)a.z; l[2] = (short)(a.z >> 16);
    h[3] = (short)a.w; l[3] = (short)(a.w >> 16);
    h[4] = (short)b.x; l[4] = (short)(b.x >> 16);
    h[5] = (short)b.y; l[5] = (short)(b.y >> 16);
    h[6] = (short)b.z; l[6] = (short)(b.z >> 16);
    h[7] = (short)b.w; l[7] = (short)(b.w >> 16);
}

// ---------------- x_meas -> bf16 copy (gather source) ----------------
__global__ __launch_bounds__(256)
void tobf16_kernel(const float* __restrict__ in, u16* __restrict__ out, int n8)
{
    int i = blockIdx.x * 256 + threadIdx.x;
    if (i >= n8) return;
    float4 a = ((const float4*)in)[2 * i];
    float4 b = ((const float4*)in)[2 * i + 1];
    ushort4 h0; h0.x = f2bf(a.x); h0.y = f2bf(a.y); h0.z = f2bf(a.z); h0.w = f2bf(a.w);
    ushort4 h1; h1.x = f2bf(b.x); h1.y = f2bf(b.y); h1.z = f2bf(b.z); h1.w = f2bf(b.w);
    ((ushort4*)out)[2 * i]     = h0;
    ((ushort4*)out)[2 * i + 1] = h1;
}

// ---------------- hist: degree count + per-edge rank ----------------
__global__ __launch_bounds__(256)
void hist_kernel(const int* __restrict__ dst_m, const int* __restrict__ dst_b,
                 int* __restrict__ deg_m, int* __restrict__ deg_b,
                 int* __restrict__ rank_m, int* __restrict__ rank_b, int E)
{
    int t = blockIdx.x * 256 + threadIdx.x;
    if (t < E) {
        rank_m[t] = atomicAdd(&deg_m[dst_m[t]], 1);
    } else if (t < 2 * E) {
        int e = t - E;
        rank_b[e] = atomicAdd(&deg_b[dst_b[e]], 1);
    }
}

__device__ __forceinline__ int wave_incl_scan(int v, int lane) {
#pragma unroll
    for (int off = 1; off < 64; off <<= 1) {
        int t = __shfl_up(v, off, 64);
        if (lane >= off) v += t;
    }
    return v;
}

// exclusive scan + sentinel rp[n] = total
__global__ __launch_bounds__(1024)
void scan2_kernel(const int* __restrict__ degA, int* __restrict__ rpA, int nA,
                  const int* __restrict__ degB, int* __restrict__ rpB, int nB)
{
    const int* deg = blockIdx.x ? degB : degA;
    int* rp = blockIdx.x ? rpB : rpA;
    int n = blockIdx.x ? nB : nA;

    __shared__ int wsum[16];
    __shared__ int carry;
    const int tid = threadIdx.x, lane = tid & 63, wid = tid >> 6;
    if (tid == 0) carry = 0;
    __syncthreads();

    for (int base = 0; base < n; base += 1024) {
        int idx = base + tid;
        int v = (idx < n) ? deg[idx] : 0;
        int incl = wave_incl_scan(v, lane);
        if (lane == 63) wsum[wid] = incl;
        __syncthreads();
        if (wid == 0) {
            int s = (lane < 16) ? wsum[lane] : 0;
            int si = wave_incl_scan(s, lane);
            if (lane < 16) wsum[lane] = si - s;
        }
        __syncthreads();
        if (idx < n) rp[idx] = carry + wsum[wid] + incl - v;
        __syncthreads();
        if (tid == 1023) carry += wsum[15] + incl;
        __syncthreads();
    }
    if (tid == 0) rp[n] = carry;
}

// ---------------- atomic-free fill (pos = rp[dst] + rank) ----------------
__global__ __launch_bounds__(256)
void fill_kernel(const int* __restrict__ src_m, const int* __restrict__ dst_m,
                 const int* __restrict__ src_b, const int* __restrict__ dst_b,
                 const float* __restrict__ edge_w,
                 const int* __restrict__ rp_m, const int* __restrict__ rp_b,
                 const int* __restrict__ rank_m, const int* __restrict__ rank_b,
                 int* __restrict__ srcs_m, int2* __restrict__ edges_b, int E)
{
    int t = blockIdx.x * 256 + threadIdx.x;
    if (t < E) {
        int pos = rp_m[dst_m[t]] + rank_m[t];
        srcs_m[pos] = src_m[t];
    } else if (t < 2 * E) {
        int e = t - E;
        int pos = rp_b[dst_b[e]] + rank_b[e];
        float x = edge_w[e];
        int2 pk;
        pk.x = src_b[e];
        pk.y = __float_as_int(1.0f / (1.0f + __expf(-x)));
        edges_b[pos] = pk;
    }
}

// ---------------- merged gather1+2 from bf16 rows -> packed agg ----------------
__global__ __launch_bounds__(256)
void gather12(const u16* __restrict__ Xb,
              const int* __restrict__ srcs_m, const int2* __restrict__ edges_b,
              const int* __restrict__ rp_m, const int* __restrict__ rp_b,
              u32* __restrict__ agg1, u32* __restrict__ agg2, int NM, int ND)
{
    const int h  = blockIdx.x * 8 + (threadIdx.x >> 5);
    const int cl = threadIdx.x & 31;
    float4 acc = make_float4(0.f, 0.f, 0.f, 0.f);

    if (h < NM) {
        int i   = rp_m[h];
        int end = rp_m[h + 1];
        for (; i + 4 <= end; i += 4) {
            int s0 = srcs_m[i], s1 = srcs_m[i + 1], s2 = srcs_m[i + 2], s3 = srcs_m[i + 3];
            ushort4 v0 = *(const ushort4*)(Xb + (size_t)s0 * 128 + cl * 4);
            ushort4 v1 = *(const ushort4*)(Xb + (size_t)s1 * 128 + cl * 4);
            ushort4 v2 = *(const ushort4*)(Xb + (size_t)s2 * 128 + cl * 4);
            ushort4 v3 = *(const ushort4*)(Xb + (size_t)s3 * 128 + cl * 4);
            acc.x += (bf2f(v0.x) + bf2f(v1.x)) + (bf2f(v2.x) + bf2f(v3.x));
            acc.y += (bf2f(v0.y) + bf2f(v1.y)) + (bf2f(v2.y) + bf2f(v3.y));
            acc.z += (bf2f(v0.z) + bf2f(v1.z)) + (bf2f(v2.z) + bf2f(v3.z));
            acc.w += (bf2f(v0.w) + bf2f(v1.w)) + (bf2f(v2.w) + bf2f(v3.w));
        }
        for (; i < end; ++i) {
            int s = srcs_m[i];
            ushort4 v = *(const ushort4*)(Xb + (size_t)s * 128 + cl * 4);
            acc.x += bf2f(v.x); acc.y += bf2f(v.y);
            acc.z += bf2f(v.z); acc.w += bf2f(v.w);
        }
        uint4 st;
        st.x = packf(acc.x); st.y = packf(acc.y);
        st.z = packf(acc.z); st.w = packf(acc.w);
        *(uint4*)(agg1 + (size_t)h * 128 + cl * 4) = st;
    } else if (h < NM + ND) {
        int node = h - NM;
        int i   = rp_b[node];
        int end = rp_b[node + 1];
        for (; i + 4 <= end; i += 4) {
            int2 p0 = edges_b[i],     p1 = edges_b[i + 1];
            int2 p2 = edges_b[i + 2], p3 = edges_b[i + 3];
            float w0 = __int_as_float(p0.y), w1 = __int_as_float(p1.y);
            float w2 = __int_as_float(p2.y), w3 = __int_as_float(p3.y);
            ushort4 v0 = *(const ushort4*)(Xb + (size_t)p0.x * 128 + cl * 4);
            ushort4 v1 = *(const ushort4*)(Xb + (size_t)p1.x * 128 + cl * 4);
            ushort4 v2 = *(const ushort4*)(Xb + (size_t)p2.x * 128 + cl * 4);
            ushort4 v3 = *(const ushort4*)(Xb + (size_t)p3.x * 128 + cl * 4);
            acc.x = fmaf(w0, bf2f(v0.x), acc.x); acc.y = fmaf(w0, bf2f(v0.y), acc.y);
            acc.z = fmaf(w0, bf2f(v0.z), acc.z); acc.w = fmaf(w0, bf2f(v0.w), acc.w);
            acc.x = fmaf(w1, bf2f(v1.x), acc.x); acc.y = fmaf(w1, bf2f(v1.y), acc.y);
            acc.z = fmaf(w1, bf2f(v1.z), acc.z); acc.w = fmaf(w1, bf2f(v1.w), acc.w);
            acc.x = fmaf(w2, bf2f(v2.x), acc.x); acc.y = fmaf(w2, bf2f(v2.y), acc.y);
            acc.z = fmaf(w2, bf2f(v2.z), acc.z); acc.w = fmaf(w2, bf2f(v2.w), acc.w);
            acc.x = fmaf(w3, bf2f(v3.x), acc.x); acc.y = fmaf(w3, bf2f(v3.y), acc.y);
            acc.z = fmaf(w3, bf2f(v3.z), acc.z); acc.w = fmaf(w3, bf2f(v3.w), acc.w);
        }
        for (; i < end; ++i) {
            int2 pk = edges_b[i];
            float w = __int_as_float(pk.y);
            ushort4 v = *(const ushort4*)(Xb + (size_t)pk.x * 128 + cl * 4);
            acc.x = fmaf(w, bf2f(v.x), acc.x); acc.y = fmaf(w, bf2f(v.y), acc.y);
            acc.z = fmaf(w, bf2f(v.z), acc.z); acc.w = fmaf(w, bf2f(v.w), acc.w);
        }
        uint4 st;
        st.x = packf(acc.x); st.y = packf(acc.y);
        st.z = packf(acc.z); st.w = packf(acc.w);
        *(uint4*)(agg2 + (size_t)node * 128 + cl * 4) = st;
    }
}

// ---------------- gather3: packed movie -> packed agg3, weighted ----------
__global__ __launch_bounds__(256)
void gather3_kernel(const u32* __restrict__ Mv, const int2* __restrict__ edges_b,
                    const int* __restrict__ rp_b, u32* __restrict__ agg3, int ND)
{
    const int node = blockIdx.x * 8 + (threadIdx.x >> 5);
    if (node >= ND) return;
    const int cl = threadIdx.x & 31;
    int i   = rp_b[node];
    int end = rp_b[node + 1];

    float4 acc = make_float4(0.f, 0.f, 0.f, 0.f);
    for (; i + 4 <= end; i += 4) {
        int2 p0 = edges_b[i],     p1 = edges_b[i + 1];
        int2 p2 = edges_b[i + 2], p3 = edges_b[i + 3];
        float w0 = __int_as_float(p0.y), w1 = __int_as_float(p1.y);
        float w2 = __int_as_float(p2.y), w3 = __int_as_float(p3.y);
        uint4 a0 = *(const uint4*)(Mv + (size_t)p0.x * 128 + cl * 4);
        uint4 a1 = *(const uint4*)(Mv + (size_t)p1.x * 128 + cl * 4);
        uint4 a2 = *(const uint4*)(Mv + (size_t)p2.x * 128 + cl * 4);
        uint4 a3 = *(const uint4*)(Mv + (size_t)p3.x * 128 + cl * 4);
        acc.x = fmaf(w0, unpackf(a0.x), acc.x); acc.y = fmaf(w0, unpackf(a0.y), acc.y);
        acc.z = fmaf(w0, unpackf(a0.z), acc.z); acc.w = fmaf(w0, unpackf(a0.w), acc.w);
        acc.x = fmaf(w1, unpackf(a1.x), acc.x); acc.y = fmaf(w1, unpackf(a1.y), acc.y);
        acc.z = fmaf(w1, unpackf(a1.z), acc.z); acc.w = fmaf(w1, unpackf(a1.w), acc.w);
        acc.x = fmaf(w2, unpackf(a2.x), acc.x); acc.y = fmaf(w2, unpackf(a2.y), acc.y);
        acc.z = fmaf(w2, unpackf(a2.z), acc.z); acc.w = fmaf(w2, unpackf(a2.w), acc.w);
        acc.x = fmaf(w3, unpackf(a3.x), acc.x); acc.y = fmaf(w3, unpackf(a3.y), acc.y);
        acc.z = fmaf(w3, unpackf(a3.z), acc.z); acc.w = fmaf(w3, unpackf(a3.w), acc.w);
    }
    for (; i < end; ++i) {
        int2 pk = edges_b[i];
        float w = __int_as_float(pk.y);
        uint4 a = *(const uint4*)(Mv + (size_t)pk.x * 128 + cl * 4);
        acc.x = fmaf(w, unpackf(a.x), acc.x); acc.y = fmaf(w, unpackf(a.y), acc.y);
        acc.z = fmaf(w, unpackf(a.z), acc.z); acc.w = fmaf(w, unpackf(a.w), acc.w);
    }
    uint4 st;
    st.x = packf(acc.x); st.y = packf(acc.y);
    st.z = packf(acc.z); st.w = packf(acc.w);
    *(uint4*)(agg3 + (size_t)node * 128 + cl * 4) = st;
}

// ---------------- weight prep: fp32 W[K][OC] -> bf16 MFMA-B-fragment order --
__global__ __launch_bounds__(256)
void wfrag_all(const float* __restrict__ w0, const float* __restrict__ w1,
               const float* __restrict__ w2, const float* __restrict__ w3,
               const float* __restrict__ w4, const float* __restrict__ w5,
               const float* __restrict__ w6, u16* __restrict__ wbuf)
{
    const int widx = blockIdx.x >> 6;
    const int o    = ((blockIdx.x & 63) << 8) + threadIdx.x;
    const int OC   = (widx == 6) ? 64 : 128;
    if (o >= OC * 128) return;
    const float* W;
    switch (widx) {
        case 0: W = w0; break; case 1: W = w1; break; case 2: W = w2; break;
        case 3: W = w3; break; case 4: W = w4; break; case 5: W = w5; break;
        default: W = w6;
    }
    int j = o & 7;
    int lane = (o >> 3) & 63;
    int n, c;
    if (OC == 128) { n = (o >> 9) & 7; c = o >> 12; }
    else           { n = (o >> 9) & 3; c = o >> 11; }
    int col = n * 16 + (lane & 15);
    int k   = c * 32 + (lane >> 4) * 8 + j;
    wbuf[widx * 16384 + o] = f2bf(W[k * OC + col]);
}

// ---------------- merged MFMA conv1+conv2, LDS-staged frag weights ----------
__global__ __launch_bounds__(256)
void conv12_mfma(const u32* __restrict__ agg1, const u16* __restrict__ w1r,
                 const float* __restrict__ b1, const float* __restrict__ x1,
                 const u16* __restrict__ w1o, u32* __restrict__ C1, int N1, int cb1,
                 const u32* __restrict__ agg2, const u16* __restrict__ w2r,
                 const float* __restrict__ b2, const float* __restrict__ x2,
                 const u16* __restrict__ w2o, u32* __restrict__ C2, int N2)
{
    __shared__ u16 sW[32768];   // 64 KB: [phase*16384 + c*4096 + n*512 + lane*8]

    const u32* Ap; const u16 *Wr, *Wo; const float *bias, *Xf; u32* C; int N, base;
    if ((int)blockIdx.x < cb1) {
        Ap = agg1; Wr = w1r; Wo = w1o; bias = b1; Xf = x1; C = C1; N = N1; base = blockIdx.x;
    } else {
        Ap = agg2; Wr = w2r; Wo = w2o; bias = b2; Xf = x2; C = C2; N = N2; base = blockIdx.x - cb1;
    }
    const int tid = threadIdx.x;
    for (int i = tid; i < 2048; i += 256) {        // 2048 uint4 = 32 KB per phase
        ((uint4*)sW)[i]        = ((const uint4*)Wr)[i];
        ((uint4*)sW)[2048 + i] = ((const uint4*)Wo)[i];
    }
    __syncthreads();

    const int lane = tid & 63;
    const int m0   = (base * 4 + (tid >> 6)) * 32;
    if (m0 >= N) return;
    const int lr   = lane & 15;
    const int quad = lane >> 4;

    f32x4 acc[2][8];
#pragma unroll
    for (int mt = 0; mt < 2; ++mt)
#pragma unroll
        for (int n = 0; n < 8; ++n) acc[mt][n] = (f32x4){0.f, 0.f, 0.f, 0.f};

    int r0 = m0 + lr;      if (r0 >= N) r0 = N - 1;
    int r1 = m0 + 16 + lr; if (r1 >= N) r1 = N - 1;

#pragma unroll
    for (int phase = 0; phase < 2; ++phase) {
#pragma unroll
        for (int c = 0; c < 4; ++c) {
            const int kb = c * 32 + quad * 8;
            bf16x8 a0h, a0l, a1h, a1l;
            if (phase == 0) {
                unpack8(Ap + (size_t)r0 * 128 + kb, a0h, a0l);
                unpack8(Ap + (size_t)r1 * 128 + kb, a1h, a1l);
            } else {
                split8(Xf + (size_t)r0 * 128 + kb, a0h, a0l);
                split8(Xf + (size_t)r1 * 128 + kb, a1h, a1l);
            }
            const u16* wp = sW + phase * 16384 + c * 4096 + lane * 8;
#pragma unroll
            for (int n = 0; n < 8; ++n) {
                bf16x8 b = *(const bf16x8*)(wp + n * 512);
                acc[0][n] = __builtin_amdgcn_mfma_f32_16x16x32_bf16(a0h, b, acc[0][n], 0, 0, 0);
                acc[0][n] = __builtin_amdgcn_mfma_f32_16x16x32_bf16(a0l, b, acc[0][n], 0, 0, 0);
                acc[1][n] = __builtin_amdgcn_mfma_f32_16x16x32_bf16(a1h, b, acc[1][n], 0, 0, 0);
                acc[1][n] = __builtin_amdgcn_mfma_f32_16x16x32_bf16(a1l, b, acc[1][n], 0, 0, 0);
            }
        }
    }

#pragma unroll
    for (int mt = 0; mt < 2; ++mt) {
#pragma unroll
        for (int n = 0; n < 8; ++n) {
            const int col = n * 16 + lr;
            const float b = bias[col];
#pragma unroll
            for (int r = 0; r < 4; ++r) {
                int row = m0 + mt * 16 + quad * 4 + r;
                if (row >= N) continue;
                C[(size_t)row * 128 + col] = packf(fmaxf(acc[mt][n][r] + b, 0.f));
            }
        }
    }
}

// ---------------- conv3: both phases packed, LDS frag weights ----------------
__global__ __launch_bounds__(256)
void conv3_mfma(const u32* __restrict__ A1, const u16* __restrict__ Wr,
                const float* __restrict__ bias,
                const u32* __restrict__ A2, const u16* __restrict__ Wo,
                u32* __restrict__ Cout, int N)
{
    __shared__ u16 sW[32768];
    const int tid = threadIdx.x;
    for (int i = tid; i < 2048; i += 256) {
        ((uint4*)sW)[i]        = ((const uint4*)Wr)[i];
        ((uint4*)sW)[2048 + i] = ((const uint4*)Wo)[i];
    }
    __syncthreads();

    const int lane = tid & 63;
    const int m0   = (blockIdx.x * 4 + (tid >> 6)) * 32;
    if (m0 >= N) return;
    const int lr   = lane & 15;
    const int quad = lane >> 4;

    f32x4 acc[2][8];
#pragma unroll
    for (int mt = 0; mt < 2; ++mt)
#pragma unroll
        for (int n = 0; n < 8; ++n) acc[mt][n] = (f32x4){0.f, 0.f, 0.f, 0.f};

    int r0 = m0 + lr;      if (r0 >= N) r0 = N - 1;
    int r1 = m0 + 16 + lr; if (r1 >= N) r1 = N - 1;

#pragma unroll
    for (int phase = 0; phase < 2; ++phase) {
        const u32* Ap = phase ? A2 : A1;
#pragma unroll
        for (int c = 0; c < 4; ++c) {
            const int kb = c * 32 + quad * 8;
            bf16x8 a0h, a0l, a1h, a1l;
            unpack8(Ap + (size_t)r0 * 128 + kb, a0h, a0l);
            unpack8(Ap + (size_t)r1 * 128 + kb, a1h, a1l);
            const u16* wp = sW + phase * 16384 + c * 4096 + lane * 8;
#pragma unroll
            for (int n = 0; n < 8; ++n) {
                bf16x8 b = *(const bf16x8*)(wp + n * 512);
                acc[0][n] = __builtin_amdgcn_mfma_f32_16x16x32_bf16(a0h, b, acc[0][n], 0, 0, 0);
                acc[0][n] = __builtin_amdgcn_mfma_f32_16x16x32_bf16(a0l, b, acc[0][n], 0, 0, 0);
                acc[1][n] = __builtin_amdgcn_mfma_f32_16x16x32_bf16(a1h, b, acc[1][n], 0, 0, 0);
                acc[1][n] = __builtin_amdgcn_mfma_f32_16x16x32_bf16(a1l, b, acc[1][n], 0, 0, 0);
            }
        }
    }

#pragma unroll
    for (int mt = 0; mt < 2; ++mt) {
#pragma unroll
        for (int n = 0; n < 8; ++n) {
            const int col = n * 16 + lr;
            const float b = bias[col];
#pragma unroll
            for (int r = 0; r < 4; ++r) {
                int row = m0 + mt * 16 + quad * 4 + r;
                if (row >= N) continue;
                Cout[(size_t)row * 128 + col] = packf(fmaxf(acc[mt][n][r] + b, 0.f));
            }
        }
    }
}

// ---------------- MFMA final lin: packed A, OC=64, LDS frag weights ---------
__global__ __launch_bounds__(256)
void lin_mfma(const u32* __restrict__ A, const u16* __restrict__ Wf,
              const float* __restrict__ bias, float* __restrict__ out, int N)
{
    __shared__ u16 sW[8192];   // 16 KB = 1024 uint4: [c*2048 + n*512 + lane*8]
    const int tid = threadIdx.x;
    for (int i = tid; i < 1024; i += 256)          // FIXED: was 512 (half slot)
        ((uint4*)sW)[i] = ((const uint4*)Wf)[i];
    __syncthreads();

    const int lane = tid & 63;
    const int m0   = (blockIdx.x * 4 + (tid >> 6)) * 32;
    if (m0 >= N) return;
    const int lr   = lane & 15;
    const int quad = lane >> 4;

    f32x4 acc[2][4];
#pragma unroll
    for (int mt = 0; mt < 2; ++mt)
#pragma unroll
        for (int n = 0; n < 4; ++n) acc[mt][n] = (f32x4){0.f, 0.f, 0.f, 0.f};

    int r0 = m0 + lr;      if (r0 >= N) r0 = N - 1;
    int r1 = m0 + 16 + lr; if (r1 >= N) r1 = N - 1;

#pragma unroll
    for (int c = 0; c < 4; ++c) {
        const int kb = c * 32 + quad * 8;
        bf16x8 a0h, a0l, a1h, a1l;
        unpack8(A + (size_t)r0 * 128 + kb, a0h, a0l);
        unpack8(A + (size_t)r1 * 128 + kb, a1h, a1l);
        const u16* wp = sW + c * 2048 + lane * 8;
#pragma unroll
        for (int n = 0; n < 4; ++n) {
            bf16x8 b = *(const bf16x8*)(wp + n * 512);
            acc[0][n] = __builtin_amdgcn_mfma_f32_16x16x32_bf16(a0h, b, acc[0][n], 0, 0, 0);
            acc[0][n] = __builtin_amdgcn_mfma_f32_16x16x32_bf16(a0l, b, acc[0][n], 0, 0, 0);
            acc[1][n] = __builtin_amdgcn_mfma_f32_16x16x32_bf16(a1h, b, acc[1][n], 0, 0, 0);
            acc[1][n] = __builtin_amdgcn_mfma_f32_16x16x32_bf16(a1l, b, acc[1][n], 0, 0, 0);
        }
    }

#pragma unroll
    for (int mt = 0; mt < 2; ++mt) {
#pragma unroll
        for (int n = 0; n < 4; ++n) {
            const int col = n * 16 + lr;
            const float b = bias[col];
#pragma unroll
            for (int r = 0; r < 4; ++r) {
                int row = m0 + mt * 16 + quad * 4 + r;
                if (row >= N) continue;
                out[(size_t)row * 64 + col] = acc[mt][n][r] + b;
            }
        }
    }
}

extern "C" void kernel_launch(void* const* d_in, const int* in_sizes, int n_in,
                              void* d_out, int out_size, void* d_ws, size_t ws_size,
                              hipStream_t stream)
{
    const float* x_meas  = (const float*)d_in[0];
    const float* x_dem   = (const float*)d_in[1];
    const int*   src_m   = (const int*)d_in[2];
    const int*   dst_m   = (const int*)d_in[3];
    const int*   src_b   = (const int*)d_in[4];
    const int*   dst_b   = (const int*)d_in[5];
    const float* edge_w  = (const float*)d_in[6];
    const float* W_rel1  = (const float*)d_in[7];
    const float* b_rel1  = (const float*)d_in[8];
    const float* W_root1 = (const float*)d_in[9];
    const float* W_rel2  = (const float*)d_in[10];
    const float* b_rel2  = (const float*)d_in[11];
    const float* W_root2 = (const float*)d_in[12];
    const float* W_rel3  = (const float*)d_in[13];
    const float* b_rel3  = (const float*)d_in[14];
    const float* W_root3 = (const float*)d_in[15];
    const float* W_lin   = (const float*)d_in[16];
    const float* b_lin   = (const float*)d_in[17];
    float* out = (float*)d_out;

    const int NM = 50000, ND = 20000, E = 600000;

    char* p = (char*)d_ws;
    auto alloc = [&](size_t bytes) { char* r = p; p += (bytes + 511) & ~(size_t)511; return r; };
    int*   deg_m   = (int*)alloc((size_t)NM * 4);
    int*   deg_b   = (int*)alloc((size_t)ND * 4);
    int*   rp_m    = (int*)alloc((size_t)(NM + 1) * 4);
    int*   rp_b    = (int*)alloc((size_t)(ND + 1) * 4);
    int*   srcs_m  = (int*)alloc((size_t)E * 4);
    int2*  edges_b = (int2*)alloc((size_t)E * 8);
    u32*   agg1    = (u32*)alloc((size_t)NM * 128 * 4);
    u32*   agg2    = (u32*)alloc((size_t)ND * 128 * 4);
    u32*   movie   = (u32*)alloc((size_t)NM * 128 * 4);
    u32*   t2      = (u32*)alloc((size_t)ND * 128 * 4);
    u16*   wbuf    = (u16*)alloc(7 * 16384 * 2);
    int* rank_m = (int*)agg1;
    int* rank_b = rank_m + E;
    u16* xm_bf  = (u16*)movie;
    u32* agg3 = agg1;
    u32* t3   = agg2;
    u16* w1r = wbuf + 0 * 16384;
    u16* w1o = wbuf + 1 * 16384;
    u16* w2r = wbuf + 2 * 16384;
    u16* w2o = wbuf + 3 * 16384;
    u16* w3r = wbuf + 4 * 16384;
    u16* w3o = wbuf + 5 * 16384;
    u16* wl  = wbuf + 6 * 16384;

    size_t deg_span = (size_t)((char*)deg_b - (char*)deg_m) + (size_t)ND * 4;
    hipMemsetAsync(deg_m, 0, deg_span, stream);

    tobf16_kernel<<<(NM * 16 + 255) / 256, 256, 0, stream>>>(x_meas, xm_bf, NM * 16);

    const int eb2 = (2 * E + 255) / 256;
    hist_kernel<<<eb2, 256, 0, stream>>>(dst_m, dst_b, deg_m, deg_b, rank_m, rank_b, E);
    scan2_kernel<<<2, 1024, 0, stream>>>(deg_m, rp_m, NM, deg_b, rp_b, ND);
    fill_kernel<<<eb2, 256, 0, stream>>>(src_m, dst_m, src_b, dst_b, edge_w,
                                         rp_m, rp_b, rank_m, rank_b, srcs_m, edges_b, E);

    wfrag_all<<<448, 256, 0, stream>>>(W_rel1, W_root1, W_rel2, W_root2,
                                       W_rel3, W_root3, W_lin, wbuf);

    gather12<<<(NM + ND + 7) / 8, 256, 0, stream>>>(xm_bf, srcs_m, edges_b,
                                                    rp_m, rp_b, agg1, agg2, NM, ND);

    const int cb1 = (NM + 127) / 128;
    const int cb2 = (ND + 127) / 128;
    conv12_mfma<<<cb1 + cb2, 256, 0, stream>>>(agg1, w1r, b_rel1, x_meas, w1o, movie, NM, cb1,
                                               agg2, w2r, b_rel2, x_dem,  w2o, t2,    ND);

    gather3_kernel<<<(ND + 7) / 8, 256, 0, stream>>>(movie, edges_b, rp_b, agg3, ND);

    conv3_mfma<<<cb2, 256, 0, stream>>>(agg3, w3r, b_rel3, t2, w3o, t3, ND);

    lin_mfma<<<cb2, 256, 0, stream>>>(t3, wl, b_lin, out, ND);
}

// Round 11
// 321.966 us; speedup vs baseline: 20.4328x; 1.1803x over previous
//
#include <hip/hip_runtime.h>

// Round 11: (1) prep megakernel (hist + tobf16 + wfrag in one launch — hist's
// waves idle on atomics, merged blocks fill the CUs), (2) movie stored bf16
// (halves gather3's scattered row bytes), (3) lin fused into conv3 via in-LDS
// bf16 tile transpose (kills t3 entirely), (4) scan vectorized 4 elems/thread.

typedef unsigned short u16;
typedef unsigned int u32;
typedef __attribute__((ext_vector_type(8))) short bf16x8;
typedef __attribute__((ext_vector_type(4))) float f32x4;

__device__ __forceinline__ float bf2f(u16 h) {
    union { u32 u; float f; } v; v.u = ((u32)h) << 16; return v.f;
}
__device__ __forceinline__ u16 f2bf(float f) {
    union { float f; u32 u; } v; v.f = f;
    u32 lsb = (v.u >> 16) & 1u;
    v.u += 0x7fffu + lsb;           // RNE
    return (u16)(v.u >> 16);
}
__device__ __forceinline__ u32 packf(float v) {
    u32 b = __float_as_uint(v);
    float hf = __uint_as_float(b & 0xffff0000u);
    u16 l = f2bf(v - hf);
    return (b >> 16) | ((u32)l << 16);
}
__device__ __forceinline__ void split2(float v, u16& h, u16& l) {
    u16 hb = f2bf(v);
    h = hb; l = f2bf(v - bf2f(hb));
}
__device__ __forceinline__ void split8(const float* __restrict__ p, bf16x8& h, bf16x8& l) {
    float4 u = *(const float4*)p;
    float4 w = *(const float4*)(p + 4);
    float a[8] = {u.x, u.y, u.z, u.w, w.x, w.y, w.z, w.w};
#pragma unroll
    for (int j = 0; j < 8; ++j) {
        u16 hh, ll; split2(a[j], hh, ll);
        h[j] = (short)hh; l[j] = (short)ll;
    }
}
__device__ __forceinline__ void unpack8(const u32* __restrict__ p, bf16x8& h, bf16x8& l) {
    uint4 a = *(const uint4*)p;
    uint4 b = *(const uint4*)(p + 4);
    h[0] = (short)a.x; l[0] = (short)(a.x >> 16);
    h[1] = (short)a.y; l[1] = (short)(a.y >> 16);
    h[2] = (short)a.z; l[2] = (short)(a.z >> 16);
    h[3] = (short)a.w; l[3] = (short)(a.w >> 16);
    h[4] = (short)b.x; l[4] = (short)(b.x >> 16);
    h[5] = (short)b.y; l[5] = (short)(b.y >> 16);
    h[6] = (short)b.z; l[6] = (short)(b.z >> 16);
    h[7] = (short)b.w; l[7] = (short)(b.w >> 16);
}

// ---------------- prep megakernel: hist | tobf16 | wfrag ----------------
// blocks [0,HB): hist (atomic-latency-bound, idle VALU);
// blocks [HB,HB+TB): x_meas -> bf16 rows; blocks [HB+TB,..+WB): weight frags.
__global__ __launch_bounds__(256)
void prep_kernel(const int* __restrict__ dst_m, const int* __restrict__ dst_b,
                 int* __restrict__ deg_m, int* __restrict__ deg_b,
                 int* __restrict__ rank_m, int* __restrict__ rank_b, int E,
                 const float* __restrict__ xm, u16* __restrict__ xm_bf, int n8,
                 const float* __restrict__ w0, const float* __restrict__ w1,
                 const float* __restrict__ w2, const float* __restrict__ w3,
                 const float* __restrict__ w4, const float* __restrict__ w5,
                 const float* __restrict__ w6, u16* __restrict__ wbuf,
                 int HB, int TB)
{
    const int b = blockIdx.x;
    if (b < HB) {
        int t = b * 256 + threadIdx.x;
        if (t < E) {
            rank_m[t] = atomicAdd(&deg_m[dst_m[t]], 1);
        } else if (t < 2 * E) {
            int e = t - E;
            rank_b[e] = atomicAdd(&deg_b[dst_b[e]], 1);
        }
    } else if (b < HB + TB) {
        int i = (b - HB) * 256 + threadIdx.x;
        if (i >= n8) return;
        float4 a = ((const float4*)xm)[2 * i];
        float4 c = ((const float4*)xm)[2 * i + 1];
        ushort4 h0; h0.x = f2bf(a.x); h0.y = f2bf(a.y); h0.z = f2bf(a.z); h0.w = f2bf(a.w);
        ushort4 h1; h1.x = f2bf(c.x); h1.y = f2bf(c.y); h1.z = f2bf(c.z); h1.w = f2bf(c.w);
        ((ushort4*)xm_bf)[2 * i]     = h0;
        ((ushort4*)xm_bf)[2 * i + 1] = h1;
    } else {
        int bb = b - HB - TB;
        const int widx = bb >> 6;
        const int o    = ((bb & 63) << 8) + threadIdx.x;
        const int OC   = (widx == 6) ? 64 : 128;
        if (o >= OC * 128) return;
        const float* W;
        switch (widx) {
            case 0: W = w0; break; case 1: W = w1; break; case 2: W = w2; break;
            case 3: W = w3; break; case 4: W = w4; break; case 5: W = w5; break;
            default: W = w6;
        }
        int j = o & 7;
        int lane = (o >> 3) & 63;
        int n, c;
        if (OC == 128) { n = (o >> 9) & 7; c = o >> 12; }
        else           { n = (o >> 9) & 3; c = o >> 11; }
        int col = n * 16 + (lane & 15);
        int k   = c * 32 + (lane >> 4) * 8 + j;
        wbuf[widx * 16384 + o] = f2bf(W[k * OC + col]);
    }
}

__device__ __forceinline__ int wave_incl_scan(int v, int lane) {
#pragma unroll
    for (int off = 1; off < 64; off <<= 1) {
        int t = __shfl_up(v, off, 64);
        if (lane >= off) v += t;
    }
    return v;
}

// exclusive scan + sentinel, 4 elems/thread (4096/chunk)
__global__ __launch_bounds__(1024)
void scan2_kernel(const int* __restrict__ degA, int* __restrict__ rpA, int nA,
                  const int* __restrict__ degB, int* __restrict__ rpB, int nB)
{
    const int* deg = blockIdx.x ? degB : degA;
    int* rp = blockIdx.x ? rpB : rpA;
    int n = blockIdx.x ? nB : nA;

    __shared__ int wsum[16];
    __shared__ int carry;
    const int tid = threadIdx.x, lane = tid & 63, wid = tid >> 6;
    if (tid == 0) carry = 0;
    __syncthreads();

    for (int base = 0; base < n; base += 4096) {
        int idx = base + tid * 4;
        int4 v = make_int4(0, 0, 0, 0);
        if (idx + 3 < n) v = *(const int4*)(deg + idx);
        else {
            if (idx + 0 < n) v.x = deg[idx + 0];
            if (idx + 1 < n) v.y = deg[idx + 1];
            if (idx + 2 < n) v.z = deg[idx + 2];
            if (idx + 3 < n) v.w = deg[idx + 3];
        }
        int s = v.x + v.y + v.z + v.w;
        int incl = wave_incl_scan(s, lane);
        if (lane == 63) wsum[wid] = incl;
        __syncthreads();
        if (wid == 0) {
            int t = (lane < 16) ? wsum[lane] : 0;
            int ti = wave_incl_scan(t, lane);
            if (lane < 16) wsum[lane] = ti - t;
        }
        __syncthreads();
        int base_t = carry + wsum[wid] + incl - s;
        if (idx + 3 < n) {
            int4 st;
            st.x = base_t;
            st.y = base_t + v.x;
            st.z = base_t + v.x + v.y;
            st.w = base_t + v.x + v.y + v.z;
            *(int4*)(rp + idx) = st;
        } else {
            if (idx + 0 < n) rp[idx + 0] = base_t;
            if (idx + 1 < n) rp[idx + 1] = base_t + v.x;
            if (idx + 2 < n) rp[idx + 2] = base_t + v.x + v.y;
            if (idx + 3 < n) rp[idx + 3] = base_t + v.x + v.y + v.z;
        }
        __syncthreads();
        if (tid == 1023) carry += wsum[15] + incl;
        __syncthreads();
    }
    if (tid == 0) rp[n] = carry;
}

// ---------------- atomic-free fill (pos = rp[dst] + rank) ----------------
__global__ __launch_bounds__(256)
void fill_kernel(const int* __restrict__ src_m, const int* __restrict__ dst_m,
                 const int* __restrict__ src_b, const int* __restrict__ dst_b,
                 const float* __restrict__ edge_w,
                 const int* __restrict__ rp_m, const int* __restrict__ rp_b,
                 const int* __restrict__ rank_m, const int* __restrict__ rank_b,
                 int* __restrict__ srcs_m, int2* __restrict__ edges_b, int E)
{
    int t = blockIdx.x * 256 + threadIdx.x;
    if (t < E) {
        int pos = rp_m[dst_m[t]] + rank_m[t];
        srcs_m[pos] = src_m[t];
    } else if (t < 2 * E) {
        int e = t - E;
        int pos = rp_b[dst_b[e]] + rank_b[e];
        float x = edge_w[e];
        int2 pk;
        pk.x = src_b[e];
        pk.y = __float_as_int(1.0f / (1.0f + __expf(-x)));
        edges_b[pos] = pk;
    }
}

// ---------------- merged gather1+2 from bf16 rows -> packed agg ----------------
__global__ __launch_bounds__(256)
void gather12(const u16* __restrict__ Xb,
              const int* __restrict__ srcs_m, const int2* __restrict__ edges_b,
              const int* __restrict__ rp_m, const int* __restrict__ rp_b,
              u32* __restrict__ agg1, u32* __restrict__ agg2, int NM, int ND)
{
    const int h  = blockIdx.x * 8 + (threadIdx.x >> 5);
    const int cl = threadIdx.x & 31;
    float4 acc = make_float4(0.f, 0.f, 0.f, 0.f);

    if (h < NM) {
        int i   = rp_m[h];
        int end = rp_m[h + 1];
        for (; i + 4 <= end; i += 4) {
            int s0 = srcs_m[i], s1 = srcs_m[i + 1], s2 = srcs_m[i + 2], s3 = srcs_m[i + 3];
            ushort4 v0 = *(const ushort4*)(Xb + (size_t)s0 * 128 + cl * 4);
            ushort4 v1 = *(const ushort4*)(Xb + (size_t)s1 * 128 + cl * 4);
            ushort4 v2 = *(const ushort4*)(Xb + (size_t)s2 * 128 + cl * 4);
            ushort4 v3 = *(const ushort4*)(Xb + (size_t)s3 * 128 + cl * 4);
            acc.x += (bf2f(v0.x) + bf2f(v1.x)) + (bf2f(v2.x) + bf2f(v3.x));
            acc.y += (bf2f(v0.y) + bf2f(v1.y)) + (bf2f(v2.y) + bf2f(v3.y));
            acc.z += (bf2f(v0.z) + bf2f(v1.z)) + (bf2f(v2.z) + bf2f(v3.z));
            acc.w += (bf2f(v0.w) + bf2f(v1.w)) + (bf2f(v2.w) + bf2f(v3.w));
        }
        for (; i < end; ++i) {
            int s = srcs_m[i];
            ushort4 v = *(const ushort4*)(Xb + (size_t)s * 128 + cl * 4);
            acc.x += bf2f(v.x); acc.y += bf2f(v.y);
            acc.z += bf2f(v.z); acc.w += bf2f(v.w);
        }
        uint4 st;
        st.x = packf(acc.x); st.y = packf(acc.y);
        st.z = packf(acc.z); st.w = packf(acc.w);
        *(uint4*)(agg1 + (size_t)h * 128 + cl * 4) = st;
    } else if (h < NM + ND) {
        int node = h - NM;
        int i   = rp_b[node];
        int end = rp_b[node + 1];
        for (; i + 4 <= end; i += 4) {
            int2 p0 = edges_b[i],     p1 = edges_b[i + 1];
            int2 p2 = edges_b[i + 2], p3 = edges_b[i + 3];
            float w0 = __int_as_float(p0.y), w1 = __int_as_float(p1.y);
            float w2 = __int_as_float(p2.y), w3 = __int_as_float(p3.y);
            ushort4 v0 = *(const ushort4*)(Xb + (size_t)p0.x * 128 + cl * 4);
            ushort4 v1 = *(const ushort4*)(Xb + (size_t)p1.x * 128 + cl * 4);
            ushort4 v2 = *(const ushort4*)(Xb + (size_t)p2.x * 128 + cl * 4);
            ushort4 v3 = *(const ushort4*)(Xb + (size_t)p3.x * 128 + cl * 4);
            acc.x = fmaf(w0, bf2f(v0.x), acc.x); acc.y = fmaf(w0, bf2f(v0.y), acc.y);
            acc.z = fmaf(w0, bf2f(v0.z), acc.z); acc.w = fmaf(w0, bf2f(v0.w), acc.w);
            acc.x = fmaf(w1, bf2f(v1.x), acc.x); acc.y = fmaf(w1, bf2f(v1.y), acc.y);
            acc.z = fmaf(w1, bf2f(v1.z), acc.z); acc.w = fmaf(w1, bf2f(v1.w), acc.w);
            acc.x = fmaf(w2, bf2f(v2.x), acc.x); acc.y = fmaf(w2, bf2f(v2.y), acc.y);
            acc.z = fmaf(w2, bf2f(v2.z), acc.z); acc.w = fmaf(w2, bf2f(v2.w), acc.w);
            acc.x = fmaf(w3, bf2f(v3.x), acc.x); acc.y = fmaf(w3, bf2f(v3.y), acc.y);
            acc.z = fmaf(w3, bf2f(v3.z), acc.z); acc.w = fmaf(w3, bf2f(v3.w), acc.w);
        }
        for (; i < end; ++i) {
            int2 pk = edges_b[i];
            float w = __int_as_float(pk.y);
            ushort4 v = *(const ushort4*)(Xb + (size_t)pk.x * 128 + cl * 4);
            acc.x = fmaf(w, bf2f(v.x), acc.x); acc.y = fmaf(w, bf2f(v.y), acc.y);
            acc.z = fmaf(w, bf2f(v.z), acc.z); acc.w = fmaf(w, bf2f(v.w), acc.w);
        }
        uint4 st;
        st.x = packf(acc.x); st.y = packf(acc.y);
        st.z = packf(acc.z); st.w = packf(acc.w);
        *(uint4*)(agg2 + (size_t)node * 128 + cl * 4) = st;
    }
}

// ---------------- gather3: bf16 movie rows -> packed agg3, weighted ----------
__global__ __launch_bounds__(256)
void gather3_kernel(const u16* __restrict__ Mv, const int2* __restrict__ edges_b,
                    const int* __restrict__ rp_b, u32* __restrict__ agg3, int ND)
{
    const int node = blockIdx.x * 8 + (threadIdx.x >> 5);
    if (node >= ND) return;
    const int cl = threadIdx.x & 31;
    int i   = rp_b[node];
    int end = rp_b[node + 1];

    float4 acc = make_float4(0.f, 0.f, 0.f, 0.f);
    for (; i + 4 <= end; i += 4) {
        int2 p0 = edges_b[i],     p1 = edges_b[i + 1];
        int2 p2 = edges_b[i + 2], p3 = edges_b[i + 3];
        float w0 = __int_as_float(p0.y), w1 = __int_as_float(p1.y);
        float w2 = __int_as_float(p2.y), w3 = __int_as_float(p3.y);
        ushort4 v0 = *(const ushort4*)(Mv + (size_t)p0.x * 128 + cl * 4);
        ushort4 v1 = *(const ushort4*)(Mv + (size_t)p1.x * 128 + cl * 4);
        ushort4 v2 = *(const ushort4*)(Mv + (size_t)p2.x * 128 + cl * 4);
        ushort4 v3 = *(const ushort4*)(Mv + (size_t)p3.x * 128 + cl * 4);
        acc.x = fmaf(w0, bf2f(v0.x), acc.x); acc.y = fmaf(w0, bf2f(v0.y), acc.y);
        acc.z = fmaf(w0, bf2f(v0.z), acc.z); acc.w = fmaf(w0, bf2f(v0.w), acc.w);
        acc.x = fmaf(w1, bf2f(v1.x), acc.x); acc.y = fmaf(w1, bf2f(v1.y), acc.y);
        acc.z = fmaf(w1, bf2f(v1.z), acc.z); acc.w = fmaf(w1, bf2f(v1.w), acc.w);
        acc.x = fmaf(w2, bf2f(v2.x), acc.x); acc.y = fmaf(w2, bf2f(v2.y), acc.y);
        acc.z = fmaf(w2, bf2f(v2.z), acc.z); acc.w = fmaf(w2, bf2f(v2.w), acc.w);
        acc.x = fmaf(w3, bf2f(v3.x), acc.x); acc.y = fmaf(w3, bf2f(v3.y), acc.y);
        acc.z = fmaf(w3, bf2f(v3.z), acc.z); acc.w = fmaf(w3, bf2f(v3.w), acc.w);
    }
    for (; i < end; ++i) {
        int2 pk = edges_b[i];
        float w = __int_as_float(pk.y);
        ushort4 v = *(const ushort4*)(Mv + (size_t)pk.x * 128 + cl * 4);
        acc.x = fmaf(w, bf2f(v.x), acc.x); acc.y = fmaf(w, bf2f(v.y), acc.y);
        acc.z = fmaf(w, bf2f(v.z), acc.z); acc.w = fmaf(w, bf2f(v.w), acc.w);
    }
    uint4 st;
    st.x = packf(acc.x); st.y = packf(acc.y);
    st.z = packf(acc.z); st.w = packf(acc.w);
    *(uint4*)(agg3 + (size_t)node * 128 + cl * 4) = st;
}

// ---------------- merged MFMA conv1+conv2, LDS-staged frag weights ----------
// conv1 segment writes movie as bf16; conv2 segment writes t2 packed.
__global__ __launch_bounds__(256)
void conv12_mfma(const u32* __restrict__ agg1, const u16* __restrict__ w1r,
                 const float* __restrict__ b1, const float* __restrict__ x1,
                 const u16* __restrict__ w1o, u16* __restrict__ C1bf, int N1, int cb1,
                 const u32* __restrict__ agg2, const u16* __restrict__ w2r,
                 const float* __restrict__ b2, const float* __restrict__ x2,
                 const u16* __restrict__ w2o, u32* __restrict__ C2pk, int N2)
{
    __shared__ u16 sW[32768];   // 64 KB: [phase*16384 + c*4096 + n*512 + lane*8]

    const bool seg1 = (int)blockIdx.x < cb1;
    const u32* Ap; const u16 *Wr, *Wo; const float *bias, *Xf; int N, base;
    if (seg1) { Ap = agg1; Wr = w1r; Wo = w1o; bias = b1; Xf = x1; N = N1; base = blockIdx.x; }
    else      { Ap = agg2; Wr = w2r; Wo = w2o; bias = b2; Xf = x2; N = N2; base = blockIdx.x - cb1; }

    const int tid = threadIdx.x;
    for (int i = tid; i < 2048; i += 256) {
        ((uint4*)sW)[i]        = ((const uint4*)Wr)[i];
        ((uint4*)sW)[2048 + i] = ((const uint4*)Wo)[i];
    }
    __syncthreads();

    const int lane = tid & 63;
    const int m0   = (base * 4 + (tid >> 6)) * 32;
    if (m0 >= N) return;
    const int lr   = lane & 15;
    const int quad = lane >> 4;

    f32x4 acc[2][8];
#pragma unroll
    for (int mt = 0; mt < 2; ++mt)
#pragma unroll
        for (int n = 0; n < 8; ++n) acc[mt][n] = (f32x4){0.f, 0.f, 0.f, 0.f};

    int r0 = m0 + lr;      if (r0 >= N) r0 = N - 1;
    int r1 = m0 + 16 + lr; if (r1 >= N) r1 = N - 1;

#pragma unroll
    for (int phase = 0; phase < 2; ++phase) {
#pragma unroll
        for (int c = 0; c < 4; ++c) {
            const int kb = c * 32 + quad * 8;
            bf16x8 a0h, a0l, a1h, a1l;
            if (phase == 0) {
                unpack8(Ap + (size_t)r0 * 128 + kb, a0h, a0l);
                unpack8(Ap + (size_t)r1 * 128 + kb, a1h, a1l);
            } else {
                split8(Xf + (size_t)r0 * 128 + kb, a0h, a0l);
                split8(Xf + (size_t)r1 * 128 + kb, a1h, a1l);
            }
            const u16* wp = sW + phase * 16384 + c * 4096 + lane * 8;
#pragma unroll
            for (int n = 0; n < 8; ++n) {
                bf16x8 b = *(const bf16x8*)(wp + n * 512);
                acc[0][n] = __builtin_amdgcn_mfma_f32_16x16x32_bf16(a0h, b, acc[0][n], 0, 0, 0);
                acc[0][n] = __builtin_amdgcn_mfma_f32_16x16x32_bf16(a0l, b, acc[0][n], 0, 0, 0);
                acc[1][n] = __builtin_amdgcn_mfma_f32_16x16x32_bf16(a1h, b, acc[1][n], 0, 0, 0);
                acc[1][n] = __builtin_amdgcn_mfma_f32_16x16x32_bf16(a1l, b, acc[1][n], 0, 0, 0);
            }
        }
    }

#pragma unroll
    for (int mt = 0; mt < 2; ++mt) {
#pragma unroll
        for (int n = 0; n < 8; ++n) {
            const int col = n * 16 + lr;
            const float b = bias[col];
#pragma unroll
            for (int r = 0; r < 4; ++r) {
                int row = m0 + mt * 16 + quad * 4 + r;
                if (row >= N) continue;
                float v = fmaxf(acc[mt][n][r] + b, 0.f);
                if (seg1) C1bf[(size_t)row * 128 + col] = f2bf(v);
                else      C2pk[(size_t)row * 128 + col] = packf(v);
            }
        }
    }
}

// ---------------- conv3 + lin fused: out = (relu(agg3@W3r+b3+t2@W3o)) @ Wl + bl
// Tile round-trips through LDS as bf16 (C-layout -> A-layout), row pitch 136
// to break the 16-way transpose bank conflict. NO early returns (sync safety).
__global__ __launch_bounds__(256)
void conv3_lin(const u32* __restrict__ A1, const u16* __restrict__ Wr,
               const float* __restrict__ bias3,
               const u32* __restrict__ A2, const u16* __restrict__ Wo,
               const u16* __restrict__ Wl, const float* __restrict__ bias_l,
               float* __restrict__ out, int N)
{
    __shared__ u16 sW[40960];          // 64 KB conv W + 16 KB lin W = 80 KB
    u16* tile = sW;                    // overlays conv W after K-loop (needs 17408 u16)
    const u16* sWl = sW + 32768;

    const int tid = threadIdx.x;
    for (int i = tid; i < 2048; i += 256) {
        ((uint4*)sW)[i]        = ((const uint4*)Wr)[i];
        ((uint4*)sW)[2048 + i] = ((const uint4*)Wo)[i];
    }
    for (int i = tid; i < 1024; i += 256)
        ((uint4*)sW)[4096 + i] = ((const uint4*)Wl)[i];
    __syncthreads();

    const int lane  = tid & 63;
    const int wv    = tid >> 6;
    const int wbase = wv * 32;                 // local tile rows
    const int m0    = (blockIdx.x * 4 + wv) * 32;
    const int lr    = lane & 15;
    const int quad  = lane >> 4;

    f32x4 acc[2][8];
#pragma unroll
    for (int mt = 0; mt < 2; ++mt)
#pragma unroll
        for (int n = 0; n < 8; ++n) acc[mt][n] = (f32x4){0.f, 0.f, 0.f, 0.f};

    int r0 = m0 + lr;      if (r0 >= N) r0 = N - 1; if (r0 < 0) r0 = 0;
    int r1 = m0 + 16 + lr; if (r1 >= N) r1 = N - 1;

#pragma unroll
    for (int phase = 0; phase < 2; ++phase) {
        const u32* Ap = phase ? A2 : A1;
#pragma unroll
        for (int c = 0; c < 4; ++c) {
            const int kb = c * 32 + quad * 8;
            bf16x8 a0h, a0l, a1h, a1l;
            unpack8(Ap + (size_t)r0 * 128 + kb, a0h, a0l);
            unpack8(Ap + (size_t)r1 * 128 + kb, a1h, a1l);
            const u16* wp = sW + phase * 16384 + c * 4096 + lane * 8;
#pragma unroll
            for (int n = 0; n < 8; ++n) {
                bf16x8 b = *(const bf16x8*)(wp + n * 512);
                acc[0][n] = __builtin_amdgcn_mfma_f32_16x16x32_bf16(a0h, b, acc[0][n], 0, 0, 0);
                acc[0][n] = __builtin_amdgcn_mfma_f32_16x16x32_bf16(a0l, b, acc[0][n], 0, 0, 0);
                acc[1][n] = __builtin_amdgcn_mfma_f32_16x16x32_bf16(a1h, b, acc[1][n], 0, 0, 0);
                acc[1][n] = __builtin_amdgcn_mfma_f32_16x16x32_bf16(a1l, b, acc[1][n], 0, 0, 0);
            }
        }
    }
    __syncthreads();   // all waves done reading conv weights; tile overlays them

    // write relu'd bf16 tile (C-layout scatter into padded rows)
#pragma unroll
    for (int mt = 0; mt < 2; ++mt) {
#pragma unroll
        for (int n = 0; n < 8; ++n) {
            const int col = n * 16 + lr;
            const float b = bias3[col];
#pragma unroll
            for (int r = 0; r < 4; ++r) {
                int row = wbase + mt * 16 + quad * 4 + r;
                tile[row * 136 + col] = f2bf(fmaxf(acc[mt][n][r] + b, 0.f));
            }
        }
    }
    __syncthreads();

    // lin: A-frags from tile (bf16), B-frags from sWl
    f32x4 acc2[2][4];
#pragma unroll
    for (int mt = 0; mt < 2; ++mt)
#pragma unroll
        for (int n = 0; n < 4; ++n) acc2[mt][n] = (f32x4){0.f, 0.f, 0.f, 0.f};

#pragma unroll
    for (int c = 0; c < 4; ++c) {
        const int kb = c * 32 + quad * 8;
        bf16x8 a0 = *(const bf16x8*)(tile + (wbase + lr) * 136 + kb);
        bf16x8 a1 = *(const bf16x8*)(tile + (wbase + 16 + lr) * 136 + kb);
#pragma unroll
        for (int n = 0; n < 4; ++n) {
            bf16x8 b = *(const bf16x8*)(sWl + c * 2048 + n * 512 + lane * 8);
            acc2[0][n] = __builtin_amdgcn_mfma_f32_16x16x32_bf16(a0, b, acc2[0][n], 0, 0, 0);
            acc2[1][n] = __builtin_amdgcn_mfma_f32_16x16x32_bf16(a1, b, acc2[1][n], 0, 0, 0);
        }
    }

#pragma unroll
    for (int mt = 0; mt < 2; ++mt) {
#pragma unroll
        for (int n = 0; n < 4; ++n) {
            const int col = n * 16 + lr;
            const float b = bias_l[col];
#pragma unroll
            for (int r = 0; r < 4; ++r) {
                int row = m0 + mt * 16 + quad * 4 + r;
                if (row >= N) continue;
                out[(size_t)row * 64 + col] = acc2[mt][n][r] + b;
            }
        }
    }
}

extern "C" void kernel_launch(void* const* d_in, const int* in_sizes, int n_in,
                              void* d_out, int out_size, void* d_ws, size_t ws_size,
                              hipStream_t stream)
{
    const float* x_meas  = (const float*)d_in[0];
    const float* x_dem   = (const float*)d_in[1];
    const int*   src_m   = (const int*)d_in[2];
    const int*   dst_m   = (const int*)d_in[3];
    const int*   src_b   = (const int*)d_in[4];
    const int*   dst_b   = (const int*)d_in[5];
    const float* edge_w  = (const float*)d_in[6];
    const float* W_rel1  = (const float*)d_in[7];
    const float* b_rel1  = (const float*)d_in[8];
    const float* W_root1 = (const float*)d_in[9];
    const float* W_rel2  = (const float*)d_in[10];
    const float* b_rel2  = (const float*)d_in[11];
    const float* W_root2 = (const float*)d_in[12];
    const float* W_rel3  = (const float*)d_in[13];
    const float* b_rel3  = (const float*)d_in[14];
    const float* W_root3 = (const float*)d_in[15];
    const float* W_lin   = (const float*)d_in[16];
    const float* b_lin   = (const float*)d_in[17];
    float* out = (float*)d_out;

    const int NM = 50000, ND = 20000, E = 600000;

    char* p = (char*)d_ws;
    auto alloc = [&](size_t bytes) { char* r = p; p += (bytes + 511) & ~(size_t)511; return r; };
    int*   deg_m   = (int*)alloc((size_t)NM * 4);
    int*   deg_b   = (int*)alloc((size_t)ND * 4);
    int*   rp_m    = (int*)alloc((size_t)(NM + 1) * 4);
    int*   rp_b    = (int*)alloc((size_t)(ND + 1) * 4);
    int*   srcs_m  = (int*)alloc((size_t)E * 4);
    int2*  edges_b = (int2*)alloc((size_t)E * 8);
    u32*   agg1    = (u32*)alloc((size_t)NM * 128 * 4);   // 25.6 MB
    u32*   agg2    = (u32*)alloc((size_t)ND * 128 * 4);   // 10.24 MB
    u16*   movie   = (u16*)alloc((size_t)NM * 128 * 2);   // 12.8 MB (bf16)
    u32*   t2      = (u32*)alloc((size_t)ND * 128 * 4);   // 10.24 MB
    u16*   wbuf    = (u16*)alloc(7 * 16384 * 2);          // 224 KB
    // aliases (lifetimes serial on the stream):
    int* rank_m = (int*)agg1;          // dies at fill; agg1 written by gather12
    int* rank_b = rank_m + E;
    u16* xm_bf  = movie;               // dies at gather12; movie written by conv12
    u32* agg3   = agg1;                // agg1 dead after conv12

    size_t deg_span = (size_t)((char*)deg_b - (char*)deg_m) + (size_t)ND * 4;
    hipMemsetAsync(deg_m, 0, deg_span, stream);

    const int HB = (2 * E + 255) / 256;       // 4688 hist blocks
    const int TB = (NM * 16 + 255) / 256;     // 3125 tobf16 blocks
    const int WB = 448;                       // wfrag blocks
    prep_kernel<<<HB + TB + WB, 256, 0, stream>>>(
        dst_m, dst_b, deg_m, deg_b, rank_m, rank_b, E,
        x_meas, xm_bf, NM * 16,
        W_rel1, W_root1, W_rel2, W_root2, W_rel3, W_root3, W_lin, wbuf,
        HB, TB);

    scan2_kernel<<<2, 1024, 0, stream>>>(deg_m, rp_m, NM, deg_b, rp_b, ND);
    fill_kernel<<<HB, 256, 0, stream>>>(src_m, dst_m, src_b, dst_b, edge_w,
                                        rp_m, rp_b, rank_m, rank_b, srcs_m, edges_b, E);

    gather12<<<(NM + ND + 7) / 8, 256, 0, stream>>>(xm_bf, srcs_m, edges_b,
                                                    rp_m, rp_b, agg1, agg2, NM, ND);

    const int cb1 = (NM + 127) / 128;
    const int cb2 = (ND + 127) / 128;
    u16* w1r = wbuf + 0 * 16384; u16* w1o = wbuf + 1 * 16384;
    u16* w2r = wbuf + 2 * 16384; u16* w2o = wbuf + 3 * 16384;
    u16* w3r = wbuf + 4 * 16384; u16* w3o = wbuf + 5 * 16384;
    u16* wl  = wbuf + 6 * 16384;
    conv12_mfma<<<cb1 + cb2, 256, 0, stream>>>(agg1, w1r, b_rel1, x_meas, w1o, movie, NM, cb1,
                                               agg2, w2r, b_rel2, x_dem,  w2o, t2,    ND);

    gather3_kernel<<<(ND + 7) / 8, 256, 0, stream>>>(movie, edges_b, rp_b, agg3, ND);

    conv3_lin<<<cb2, 256, 0, stream>>>(agg3, w3r, b_rel3, t2, w3o, wl, b_lin, out, ND);
}

// Round 12
// 305.390 us; speedup vs baseline: 21.5419x; 1.0543x over previous
//
#include <hip/hip_runtime.h>

// Round 12: pure-bf16 activations (fp32 MFMA accum). conv A-op = single 16B
// bf16x8 load + 1 MFMA (was 2 loads + unpack + 2 MFMA); roots from bf16
// copies (no fp32 input streams in convs); 32KB two-stage W staging -> 5
// blocks/CU (was 2). All intermediates bf16 (half L3 traffic). No early
// returns around barriers. Revert path if absmax>1.36: packed agg + split-2.

typedef unsigned short u16;
typedef unsigned int u32;
typedef __attribute__((ext_vector_type(8))) short bf16x8;
typedef __attribute__((ext_vector_type(4))) float f32x4;

__device__ __forceinline__ float bf2f(u16 h) {
    union { u32 u; float f; } v; v.u = ((u32)h) << 16; return v.f;
}
__device__ __forceinline__ u16 f2bf(float f) {
    union { float f; u32 u; } v; v.f = f;
    u32 lsb = (v.u >> 16) & 1u;
    v.u += 0x7fffu + lsb;           // RNE
    return (u16)(v.u >> 16);
}

// ---------------- prep megakernel: hist | xm->bf16 | xd->bf16 | wfrag --------
__global__ __launch_bounds__(256)
void prep_kernel(const int* __restrict__ dst_m, const int* __restrict__ dst_b,
                 int* __restrict__ deg_m, int* __restrict__ deg_b,
                 int* __restrict__ rank_m, int* __restrict__ rank_b, int E,
                 const float* __restrict__ xm, u16* __restrict__ xm_bf, int n8m,
                 const float* __restrict__ xd, u16* __restrict__ xd_bf, int n8d,
                 const float* __restrict__ w0, const float* __restrict__ w1,
                 const float* __restrict__ w2, const float* __restrict__ w3,
                 const float* __restrict__ w4, const float* __restrict__ w5,
                 const float* __restrict__ w6, u16* __restrict__ wbuf,
                 int HB, int TB, int TB2)
{
    const int b = blockIdx.x;
    if (b < HB) {
        int t = b * 256 + threadIdx.x;
        if (t < E) {
            rank_m[t] = atomicAdd(&deg_m[dst_m[t]], 1);
        } else if (t < 2 * E) {
            int e = t - E;
            rank_b[e] = atomicAdd(&deg_b[dst_b[e]], 1);
        }
    } else if (b < HB + TB + TB2) {
        const bool isM = b < HB + TB;
        const float* src = isM ? xm : xd;
        u16* dst = isM ? xm_bf : xd_bf;
        int n8 = isM ? n8m : n8d;
        int i = (b - (isM ? HB : HB + TB)) * 256 + threadIdx.x;
        if (i >= n8) return;
        float4 a = ((const float4*)src)[2 * i];
        float4 c = ((const float4*)src)[2 * i + 1];
        ushort4 h0; h0.x = f2bf(a.x); h0.y = f2bf(a.y); h0.z = f2bf(a.z); h0.w = f2bf(a.w);
        ushort4 h1; h1.x = f2bf(c.x); h1.y = f2bf(c.y); h1.z = f2bf(c.z); h1.w = f2bf(c.w);
        ((ushort4*)dst)[2 * i]     = h0;
        ((ushort4*)dst)[2 * i + 1] = h1;
    } else {
        int bb = b - HB - TB - TB2;
        const int widx = bb >> 6;
        const int o    = ((bb & 63) << 8) + threadIdx.x;
        const int OC   = (widx == 6) ? 64 : 128;
        if (o >= OC * 128) return;
        const float* W;
        switch (widx) {
            case 0: W = w0; break; case 1: W = w1; break; case 2: W = w2; break;
            case 3: W = w3; break; case 4: W = w4; break; case 5: W = w5; break;
            default: W = w6;
        }
        int j = o & 7;
        int lane = (o >> 3) & 63;
        int n, c;
        if (OC == 128) { n = (o >> 9) & 7; c = o >> 12; }
        else           { n = (o >> 9) & 3; c = o >> 11; }
        int col = n * 16 + (lane & 15);
        int k   = c * 32 + (lane >> 4) * 8 + j;
        wbuf[widx * 16384 + o] = f2bf(W[k * OC + col]);
    }
}

__device__ __forceinline__ int wave_incl_scan(int v, int lane) {
#pragma unroll
    for (int off = 1; off < 64; off <<= 1) {
        int t = __shfl_up(v, off, 64);
        if (lane >= off) v += t;
    }
    return v;
}

// exclusive scan + sentinel, 4 elems/thread
__global__ __launch_bounds__(1024)
void scan2_kernel(const int* __restrict__ degA, int* __restrict__ rpA, int nA,
                  const int* __restrict__ degB, int* __restrict__ rpB, int nB)
{
    const int* deg = blockIdx.x ? degB : degA;
    int* rp = blockIdx.x ? rpB : rpA;
    int n = blockIdx.x ? nB : nA;

    __shared__ int wsum[16];
    __shared__ int carry;
    const int tid = threadIdx.x, lane = tid & 63, wid = tid >> 6;
    if (tid == 0) carry = 0;
    __syncthreads();

    for (int base = 0; base < n; base += 4096) {
        int idx = base + tid * 4;
        int4 v = make_int4(0, 0, 0, 0);
        if (idx + 3 < n) v = *(const int4*)(deg + idx);
        else {
            if (idx + 0 < n) v.x = deg[idx + 0];
            if (idx + 1 < n) v.y = deg[idx + 1];
            if (idx + 2 < n) v.z = deg[idx + 2];
            if (idx + 3 < n) v.w = deg[idx + 3];
        }
        int s = v.x + v.y + v.z + v.w;
        int incl = wave_incl_scan(s, lane);
        if (lane == 63) wsum[wid] = incl;
        __syncthreads();
        if (wid == 0) {
            int t = (lane < 16) ? wsum[lane] : 0;
            int ti = wave_incl_scan(t, lane);
            if (lane < 16) wsum[lane] = ti - t;
        }
        __syncthreads();
        int base_t = carry + wsum[wid] + incl - s;
        if (idx + 3 < n) {
            int4 st;
            st.x = base_t;
            st.y = base_t + v.x;
            st.z = base_t + v.x + v.y;
            st.w = base_t + v.x + v.y + v.z;
            *(int4*)(rp + idx) = st;
        } else {
            if (idx + 0 < n) rp[idx + 0] = base_t;
            if (idx + 1 < n) rp[idx + 1] = base_t + v.x;
            if (idx + 2 < n) rp[idx + 2] = base_t + v.x + v.y;
            if (idx + 3 < n) rp[idx + 3] = base_t + v.x + v.y + v.z;
        }
        __syncthreads();
        if (tid == 1023) carry += wsum[15] + incl;
        __syncthreads();
    }
    if (tid == 0) rp[n] = carry;
}

// ---------------- atomic-free fill ----------------
__global__ __launch_bounds__(256)
void fill_kernel(const int* __restrict__ src_m, const int* __restrict__ dst_m,
                 const int* __restrict__ src_b, const int* __restrict__ dst_b,
                 const float* __restrict__ edge_w,
                 const int* __restrict__ rp_m, const int* __restrict__ rp_b,
                 const int* __restrict__ rank_m, const int* __restrict__ rank_b,
                 int* __restrict__ srcs_m, int2* __restrict__ edges_b, int E)
{
    int t = blockIdx.x * 256 + threadIdx.x;
    if (t < E) {
        int pos = rp_m[dst_m[t]] + rank_m[t];
        srcs_m[pos] = src_m[t];
    } else if (t < 2 * E) {
        int e = t - E;
        int pos = rp_b[dst_b[e]] + rank_b[e];
        float x = edge_w[e];
        int2 pk;
        pk.x = src_b[e];
        pk.y = __float_as_int(1.0f / (1.0f + __expf(-x)));
        edges_b[pos] = pk;
    }
}

// ---------------- merged gather1+2 from bf16 rows -> bf16 agg ----------------
__global__ __launch_bounds__(256)
void gather12(const u16* __restrict__ Xb,
              const int* __restrict__ srcs_m, const int2* __restrict__ edges_b,
              const int* __restrict__ rp_m, const int* __restrict__ rp_b,
              u16* __restrict__ agg1, u16* __restrict__ agg2, int NM, int ND)
{
    const int h  = blockIdx.x * 8 + (threadIdx.x >> 5);
    const int cl = threadIdx.x & 31;
    float4 acc = make_float4(0.f, 0.f, 0.f, 0.f);

    if (h < NM) {
        int i   = rp_m[h];
        int end = rp_m[h + 1];
        for (; i + 4 <= end; i += 4) {
            int s0 = srcs_m[i], s1 = srcs_m[i + 1], s2 = srcs_m[i + 2], s3 = srcs_m[i + 3];
            ushort4 v0 = *(const ushort4*)(Xb + (size_t)s0 * 128 + cl * 4);
            ushort4 v1 = *(const ushort4*)(Xb + (size_t)s1 * 128 + cl * 4);
            ushort4 v2 = *(const ushort4*)(Xb + (size_t)s2 * 128 + cl * 4);
            ushort4 v3 = *(const ushort4*)(Xb + (size_t)s3 * 128 + cl * 4);
            acc.x += (bf2f(v0.x) + bf2f(v1.x)) + (bf2f(v2.x) + bf2f(v3.x));
            acc.y += (bf2f(v0.y) + bf2f(v1.y)) + (bf2f(v2.y) + bf2f(v3.y));
            acc.z += (bf2f(v0.z) + bf2f(v1.z)) + (bf2f(v2.z) + bf2f(v3.z));
            acc.w += (bf2f(v0.w) + bf2f(v1.w)) + (bf2f(v2.w) + bf2f(v3.w));
        }
        for (; i < end; ++i) {
            int s = srcs_m[i];
            ushort4 v = *(const ushort4*)(Xb + (size_t)s * 128 + cl * 4);
            acc.x += bf2f(v.x); acc.y += bf2f(v.y);
            acc.z += bf2f(v.z); acc.w += bf2f(v.w);
        }
        ushort4 st;
        st.x = f2bf(acc.x); st.y = f2bf(acc.y);
        st.z = f2bf(acc.z); st.w = f2bf(acc.w);
        *(ushort4*)(agg1 + (size_t)h * 128 + cl * 4) = st;
    } else if (h < NM + ND) {
        int node = h - NM;
        int i   = rp_b[node];
        int end = rp_b[node + 1];
        for (; i + 4 <= end; i += 4) {
            int2 p0 = edges_b[i],     p1 = edges_b[i + 1];
            int2 p2 = edges_b[i + 2], p3 = edges_b[i + 3];
            float w0 = __int_as_float(p0.y), w1 = __int_as_float(p1.y);
            float w2 = __int_as_float(p2.y), w3 = __int_as_float(p3.y);
            ushort4 v0 = *(const ushort4*)(Xb + (size_t)p0.x * 128 + cl * 4);
            ushort4 v1 = *(const ushort4*)(Xb + (size_t)p1.x * 128 + cl * 4);
            ushort4 v2 = *(const ushort4*)(Xb + (size_t)p2.x * 128 + cl * 4);
            ushort4 v3 = *(const ushort4*)(Xb + (size_t)p3.x * 128 + cl * 4);
            acc.x = fmaf(w0, bf2f(v0.x), acc.x); acc.y = fmaf(w0, bf2f(v0.y), acc.y);
            acc.z = fmaf(w0, bf2f(v0.z), acc.z); acc.w = fmaf(w0, bf2f(v0.w), acc.w);
            acc.x = fmaf(w1, bf2f(v1.x), acc.x); acc.y = fmaf(w1, bf2f(v1.y), acc.y);
            acc.z = fmaf(w1, bf2f(v1.z), acc.z); acc.w = fmaf(w1, bf2f(v1.w), acc.w);
            acc.x = fmaf(w2, bf2f(v2.x), acc.x); acc.y = fmaf(w2, bf2f(v2.y), acc.y);
            acc.z = fmaf(w2, bf2f(v2.z), acc.z); acc.w = fmaf(w2, bf2f(v2.w), acc.w);
            acc.x = fmaf(w3, bf2f(v3.x), acc.x); acc.y = fmaf(w3, bf2f(v3.y), acc.y);
            acc.z = fmaf(w3, bf2f(v3.z), acc.z); acc.w = fmaf(w3, bf2f(v3.w), acc.w);
        }
        for (; i < end; ++i) {
            int2 pk = edges_b[i];
            float w = __int_as_float(pk.y);
            ushort4 v = *(const ushort4*)(Xb + (size_t)pk.x * 128 + cl * 4);
            acc.x = fmaf(w, bf2f(v.x), acc.x); acc.y = fmaf(w, bf2f(v.y), acc.y);
            acc.z = fmaf(w, bf2f(v.z), acc.z); acc.w = fmaf(w, bf2f(v.w), acc.w);
        }
        ushort4 st;
        st.x = f2bf(acc.x); st.y = f2bf(acc.y);
        st.z = f2bf(acc.z); st.w = f2bf(acc.w);
        *(ushort4*)(agg2 + (size_t)node * 128 + cl * 4) = st;
    }
}

// ---------------- gather3: bf16 movie rows -> bf16 agg3, weighted ----------
__global__ __launch_bounds__(256)
void gather3_kernel(const u16* __restrict__ Mv, const int2* __restrict__ edges_b,
                    const int* __restrict__ rp_b, u16* __restrict__ agg3, int ND)
{
    const int node = blockIdx.x * 8 + (threadIdx.x >> 5);
    if (node >= ND) return;
    const int cl = threadIdx.x & 31;
    int i   = rp_b[node];
    int end = rp_b[node + 1];

    float4 acc = make_float4(0.f, 0.f, 0.f, 0.f);
    for (; i + 4 <= end; i += 4) {
        int2 p0 = edges_b[i],     p1 = edges_b[i + 1];
        int2 p2 = edges_b[i + 2], p3 = edges_b[i + 3];
        float w0 = __int_as_float(p0.y), w1 = __int_as_float(p1.y);
        float w2 = __int_as_float(p2.y), w3 = __int_as_float(p3.y);
        ushort4 v0 = *(const ushort4*)(Mv + (size_t)p0.x * 128 + cl * 4);
        ushort4 v1 = *(const ushort4*)(Mv + (size_t)p1.x * 128 + cl * 4);
        ushort4 v2 = *(const ushort4*)(Mv + (size_t)p2.x * 128 + cl * 4);
        ushort4 v3 = *(const ushort4*)(Mv + (size_t)p3.x * 128 + cl * 4);
        acc.x = fmaf(w0, bf2f(v0.x), acc.x); acc.y = fmaf(w0, bf2f(v0.y), acc.y);
        acc.z = fmaf(w0, bf2f(v0.z), acc.z); acc.w = fmaf(w0, bf2f(v0.w), acc.w);
        acc.x = fmaf(w1, bf2f(v1.x), acc.x); acc.y = fmaf(w1, bf2f(v1.y), acc.y);
        acc.z = fmaf(w1, bf2f(v1.z), acc.z); acc.w = fmaf(w1, bf2f(v1.w), acc.w);
        acc.x = fmaf(w2, bf2f(v2.x), acc.x); acc.y = fmaf(w2, bf2f(v2.y), acc.y);
        acc.z = fmaf(w2, bf2f(v2.z), acc.z); acc.w = fmaf(w2, bf2f(v2.w), acc.w);
        acc.x = fmaf(w3, bf2f(v3.x), acc.x); acc.y = fmaf(w3, bf2f(v3.y), acc.y);
        acc.z = fmaf(w3, bf2f(v3.z), acc.z); acc.w = fmaf(w3, bf2f(v3.w), acc.w);
    }
    for (; i < end; ++i) {
        int2 pk = edges_b[i];
        float w = __int_as_float(pk.y);
        ushort4 v = *(const ushort4*)(Mv + (size_t)pk.x * 128 + cl * 4);
        acc.x = fmaf(w, bf2f(v.x), acc.x); acc.y = fmaf(w, bf2f(v.y), acc.y);
        acc.z = fmaf(w, bf2f(v.z), acc.z); acc.w = fmaf(w, bf2f(v.w), acc.w);
    }
    ushort4 st;
    st.x = f2bf(acc.x); st.y = f2bf(acc.y);
    st.z = f2bf(acc.z); st.w = f2bf(acc.w);
    *(ushort4*)(agg3 + (size_t)node * 128 + cl * 4) = st;
}

// ---------------- merged MFMA conv1+conv2 (bf16 A, two-stage 32KB W) --------
// No early returns: barriers mid-kernel; rows clamped, stores guarded.
__global__ __launch_bounds__(256)
void conv12_mfma(const u16* __restrict__ agg1, const u16* __restrict__ w1r,
                 const float* __restrict__ b1, const u16* __restrict__ xm_bf,
                 const u16* __restrict__ w1o, u16* __restrict__ C1, int N1, int cb1,
                 const u16* __restrict__ agg2, const u16* __restrict__ w2r,
                 const float* __restrict__ b2, const u16* __restrict__ xd_bf,
                 const u16* __restrict__ w2o, u16* __restrict__ C2, int N2)
{
    __shared__ u16 sW[16384];   // 32 KB, one phase at a time

    const bool seg1 = (int)blockIdx.x < cb1;
    const u16 *A0, *A1p, *Wr, *Wo; const float* bias; u16* C; int N, base;
    if (seg1) { A0 = agg1; A1p = xm_bf; Wr = w1r; Wo = w1o; bias = b1; C = C1; N = N1; base = blockIdx.x; }
    else      { A0 = agg2; A1p = xd_bf; Wr = w2r; Wo = w2o; bias = b2; C = C2; N = N2; base = blockIdx.x - cb1; }

    const int tid  = threadIdx.x;
    const int lane = tid & 63;
    const int m0   = (base * 4 + (tid >> 6)) * 32;
    const int lr   = lane & 15;
    const int quad = lane >> 4;

    int r0 = m0 + lr;      if (r0 >= N) r0 = N - 1;
    int r1 = m0 + 16 + lr; if (r1 >= N) r1 = N - 1;

    f32x4 acc[2][8];
#pragma unroll
    for (int mt = 0; mt < 2; ++mt)
#pragma unroll
        for (int n = 0; n < 8; ++n) acc[mt][n] = (f32x4){0.f, 0.f, 0.f, 0.f};

    // phase 0: aggregate term
    for (int i = tid; i < 2048; i += 256)
        ((uint4*)sW)[i] = ((const uint4*)Wr)[i];
    __syncthreads();
#pragma unroll
    for (int c = 0; c < 4; ++c) {
        const int kb = c * 32 + quad * 8;
        bf16x8 a0 = *(const bf16x8*)(A0 + (size_t)r0 * 128 + kb);
        bf16x8 a1 = *(const bf16x8*)(A0 + (size_t)r1 * 128 + kb);
        const u16* wp = sW + c * 4096 + lane * 8;
#pragma unroll
        for (int n = 0; n < 8; ++n) {
            bf16x8 b = *(const bf16x8*)(wp + n * 512);
            acc[0][n] = __builtin_amdgcn_mfma_f32_16x16x32_bf16(a0, b, acc[0][n], 0, 0, 0);
            acc[1][n] = __builtin_amdgcn_mfma_f32_16x16x32_bf16(a1, b, acc[1][n], 0, 0, 0);
        }
    }
    __syncthreads();

    // phase 1: root term
    for (int i = tid; i < 2048; i += 256)
        ((uint4*)sW)[i] = ((const uint4*)Wo)[i];
    __syncthreads();
#pragma unroll
    for (int c = 0; c < 4; ++c) {
        const int kb = c * 32 + quad * 8;
        bf16x8 a0 = *(const bf16x8*)(A1p + (size_t)r0 * 128 + kb);
        bf16x8 a1 = *(const bf16x8*)(A1p + (size_t)r1 * 128 + kb);
        const u16* wp = sW + c * 4096 + lane * 8;
#pragma unroll
        for (int n = 0; n < 8; ++n) {
            bf16x8 b = *(const bf16x8*)(wp + n * 512);
            acc[0][n] = __builtin_amdgcn_mfma_f32_16x16x32_bf16(a0, b, acc[0][n], 0, 0, 0);
            acc[1][n] = __builtin_amdgcn_mfma_f32_16x16x32_bf16(a1, b, acc[1][n], 0, 0, 0);
        }
    }

#pragma unroll
    for (int mt = 0; mt < 2; ++mt) {
#pragma unroll
        for (int n = 0; n < 8; ++n) {
            const int col = n * 16 + lr;
            const float b = bias[col];
#pragma unroll
            for (int r = 0; r < 4; ++r) {
                int row = m0 + mt * 16 + quad * 4 + r;
                if (row >= N) continue;
                C[(size_t)row * 128 + col] = f2bf(fmaxf(acc[mt][n][r] + b, 0.f));
            }
        }
    }
}

// ---------------- conv3 + lin fused (bf16 A), 50 KB LDS ----------------
__global__ __launch_bounds__(256)
void conv3_lin(const u16* __restrict__ A1, const u16* __restrict__ Wr,
               const float* __restrict__ bias3,
               const u16* __restrict__ A2, const u16* __restrict__ Wo,
               const u16* __restrict__ Wl, const float* __restrict__ bias_l,
               float* __restrict__ out, int N)
{
    __shared__ u16 lds[17408 + 8192];   // 34 KB tile region (overlays conv W) + 16 KB lin W
    u16* tile = lds;
    u16* sWl  = lds + 17408;

    const int tid  = threadIdx.x;
    const int lane = tid & 63;
    const int wv   = tid >> 6;
    const int wbase = wv * 32;
    const int m0   = (blockIdx.x * 4 + wv) * 32;
    const int lr   = lane & 15;
    const int quad = lane >> 4;

    int r0 = m0 + lr;      if (r0 >= N) r0 = N - 1;
    int r1 = m0 + 16 + lr; if (r1 >= N) r1 = N - 1;

    f32x4 acc[2][8];
#pragma unroll
    for (int mt = 0; mt < 2; ++mt)
#pragma unroll
        for (int n = 0; n < 8; ++n) acc[mt][n] = (f32x4){0.f, 0.f, 0.f, 0.f};

    // stage lin W once + conv phase-0 W
    for (int i = tid; i < 1024; i += 256)
        ((uint4*)sWl)[i] = ((const uint4*)Wl)[i];
    for (int i = tid; i < 2048; i += 256)
        ((uint4*)lds)[i] = ((const uint4*)Wr)[i];
    __syncthreads();
#pragma unroll
    for (int c = 0; c < 4; ++c) {
        const int kb = c * 32 + quad * 8;
        bf16x8 a0 = *(const bf16x8*)(A1 + (size_t)r0 * 128 + kb);
        bf16x8 a1 = *(const bf16x8*)(A1 + (size_t)r1 * 128 + kb);
        const u16* wp = lds + c * 4096 + lane * 8;
#pragma unroll
        for (int n = 0; n < 8; ++n) {
            bf16x8 b = *(const bf16x8*)(wp + n * 512);
            acc[0][n] = __builtin_amdgcn_mfma_f32_16x16x32_bf16(a0, b, acc[0][n], 0, 0, 0);
            acc[1][n] = __builtin_amdgcn_mfma_f32_16x16x32_bf16(a1, b, acc[1][n], 0, 0, 0);
        }
    }
    __syncthreads();
    for (int i = tid; i < 2048; i += 256)
        ((uint4*)lds)[i] = ((const uint4*)Wo)[i];
    __syncthreads();
#pragma unroll
    for (int c = 0; c < 4; ++c) {
        const int kb = c * 32 + quad * 8;
        bf16x8 a0 = *(const bf16x8*)(A2 + (size_t)r0 * 128 + kb);
        bf16x8 a1 = *(const bf16x8*)(A2 + (size_t)r1 * 128 + kb);
        const u16* wp = lds + c * 4096 + lane * 8;
#pragma unroll
        for (int n = 0; n < 8; ++n) {
            bf16x8 b = *(const bf16x8*)(wp + n * 512);
            acc[0][n] = __builtin_amdgcn_mfma_f32_16x16x32_bf16(a0, b, acc[0][n], 0, 0, 0);
            acc[1][n] = __builtin_amdgcn_mfma_f32_16x16x32_bf16(a1, b, acc[1][n], 0, 0, 0);
        }
    }
    __syncthreads();   // done reading conv W; tile overlays it

    // relu'd bf16 tile, C-layout -> padded rows (pitch 136)
#pragma unroll
    for (int mt = 0; mt < 2; ++mt) {
#pragma unroll
        for (int n = 0; n < 8; ++n) {
            const int col = n * 16 + lr;
            const float b = bias3[col];
#pragma unroll
            for (int r = 0; r < 4; ++r) {
                int row = wbase + mt * 16 + quad * 4 + r;
                tile[row * 136 + col] = f2bf(fmaxf(acc[mt][n][r] + b, 0.f));
            }
        }
    }
    __syncthreads();

    f32x4 acc2[2][4];
#pragma unroll
    for (int mt = 0; mt < 2; ++mt)
#pragma unroll
        for (int n = 0; n < 4; ++n) acc2[mt][n] = (f32x4){0.f, 0.f, 0.f, 0.f};

#pragma unroll
    for (int c = 0; c < 4; ++c) {
        const int kb = c * 32 + quad * 8;
        bf16x8 a0 = *(const bf16x8*)(tile + (wbase + lr) * 136 + kb);
        bf16x8 a1 = *(const bf16x8*)(tile + (wbase + 16 + lr) * 136 + kb);
#pragma unroll
        for (int n = 0; n < 4; ++n) {
            bf16x8 b = *(const bf16x8*)(sWl + c * 2048 + n * 512 + lane * 8);
            acc2[0][n] = __builtin_amdgcn_mfma_f32_16x16x32_bf16(a0, b, acc2[0][n], 0, 0, 0);
            acc2[1][n] = __builtin_amdgcn_mfma_f32_16x16x32_bf16(a1, b, acc2[1][n], 0, 0, 0);
        }
    }

#pragma unroll
    for (int mt = 0; mt < 2; ++mt) {
#pragma unroll
        for (int n = 0; n < 4; ++n) {
            const int col = n * 16 + lr;
            const float b = bias_l[col];
#pragma unroll
            for (int r = 0; r < 4; ++r) {
                int row = m0 + mt * 16 + quad * 4 + r;
                if (row >= N) continue;
                out[(size_t)row * 64 + col] = acc2[mt][n][r] + b;
            }
        }
    }
}

extern "C" void kernel_launch(void* const* d_in, const int* in_sizes, int n_in,
                              void* d_out, int out_size, void* d_ws, size_t ws_size,
                              hipStream_t stream)
{
    const float* x_meas  = (const float*)d_in[0];
    const float* x_dem   = (const float*)d_in[1];
    const int*   src_m   = (const int*)d_in[2];
    const int*   dst_m   = (const int*)d_in[3];
    const int*   src_b   = (const int*)d_in[4];
    const int*   dst_b   = (const int*)d_in[5];
    const float* edge_w  = (const float*)d_in[6];
    const float* W_rel1  = (const float*)d_in[7];
    const float* b_rel1  = (const float*)d_in[8];
    const float* W_root1 = (const float*)d_in[9];
    const float* W_rel2  = (const float*)d_in[10];
    const float* b_rel2  = (const float*)d_in[11];
    const float* W_root2 = (const float*)d_in[12];
    const float* W_rel3  = (const float*)d_in[13];
    const float* b_rel3  = (const float*)d_in[14];
    const float* W_root3 = (const float*)d_in[15];
    const float* W_lin   = (const float*)d_in[16];
    const float* b_lin   = (const float*)d_in[17];
    float* out = (float*)d_out;

    const int NM = 50000, ND = 20000, E = 600000;

    char* p = (char*)d_ws;
    auto alloc = [&](size_t bytes) { char* r = p; p += (bytes + 511) & ~(size_t)511; return r; };
    int*   deg_m   = (int*)alloc((size_t)NM * 4);
    int*   deg_b   = (int*)alloc((size_t)ND * 4);
    int*   rp_m    = (int*)alloc((size_t)(NM + 1) * 4);
    int*   rp_b    = (int*)alloc((size_t)(ND + 1) * 4);
    int*   srcs_m  = (int*)alloc((size_t)E * 4);
    int2*  edges_b = (int2*)alloc((size_t)E * 8);
    u16*   agg1    = (u16*)alloc((size_t)NM * 128 * 2);   // 12.8 MB bf16
    u16*   agg2    = (u16*)alloc((size_t)ND * 128 * 2);   // 5.12 MB
    u16*   movie   = (u16*)alloc((size_t)NM * 128 * 2);   // 12.8 MB (= xm_bf alias)
    u16*   t2      = (u16*)alloc((size_t)ND * 128 * 2);   // 5.12 MB
    u16*   xd_bf   = (u16*)alloc((size_t)ND * 128 * 2);   // 5.12 MB
    u16*   wbuf    = (u16*)alloc(7 * 16384 * 2);          // 224 KB
    // aliases (stream-serial lifetimes):
    int* rank_m = (int*)agg1;          // dies at fill; agg1 written by gather12
    int* rank_b = rank_m + E;          // 4.8 MB total <= 12.8 MB
    u16* xm_bf  = movie;               // conv1 reads own rows, writes own rows (safe)
    u16* agg3   = agg1;                // agg1 dead after conv12

    size_t deg_span = (size_t)((char*)deg_b - (char*)deg_m) + (size_t)ND * 4;
    hipMemsetAsync(deg_m, 0, deg_span, stream);

    const int HB  = (2 * E + 255) / 256;       // 4688
    const int TB  = (NM * 16 + 255) / 256;     // 3125
    const int TB2 = (ND * 16 + 255) / 256;     // 1250
    const int WB  = 448;
    prep_kernel<<<HB + TB + TB2 + WB, 256, 0, stream>>>(
        dst_m, dst_b, deg_m, deg_b, rank_m, rank_b, E,
        x_meas, xm_bf, NM * 16, x_dem, xd_bf, ND * 16,
        W_rel1, W_root1, W_rel2, W_root2, W_rel3, W_root3, W_lin, wbuf,
        HB, TB, TB2);

    scan2_kernel<<<2, 1024, 0, stream>>>(deg_m, rp_m, NM, deg_b, rp_b, ND);
    fill_kernel<<<HB, 256, 0, stream>>>(src_m, dst_m, src_b, dst_b, edge_w,
                                        rp_m, rp_b, rank_m, rank_b, srcs_m, edges_b, E);

    gather12<<<(NM + ND + 7) / 8, 256, 0, stream>>>(xm_bf, srcs_m, edges_b,
                                                    rp_m, rp_b, agg1, agg2, NM, ND);

    const int cb1 = (NM + 127) / 128;
    const int cb2 = (ND + 127) / 128;
    u16* w1r = wbuf + 0 * 16384; u16* w1o = wbuf + 1 * 16384;
    u16* w2r = wbuf + 2 * 16384; u16* w2o = wbuf + 3 * 16384;
    u16* w3r = wbuf + 4 * 16384; u16* w3o = wbuf + 5 * 16384;
    u16* wl  = wbuf + 6 * 16384;
    conv12_mfma<<<cb1 + cb2, 256, 0, stream>>>(agg1, w1r, b_rel1, xm_bf, w1o, movie, NM, cb1,
                                               agg2, w2r, b_rel2, xd_bf, w2o, t2,    ND);

    gather3_kernel<<<(ND + 7) / 8, 256, 0, stream>>>(movie, edges_b, rp_b, agg3, ND);

    conv3_lin<<<cb2, 256, 0, stream>>>(agg3, w3r, b_rel3, t2, w3o, wl, b_lin, out, ND);
}